// Round 1
// baseline (888.101 us; speedup 1.0000x reference)
//
#include <hip/hip_runtime.h>
#include <stdint.h>

typedef __bf16 bf16;
typedef __bf16 bf16x8 __attribute__((ext_vector_type(8)));
typedef float f32x4 __attribute__((ext_vector_type(4)));

#define SEQ 2048
#define NHEAD 16
#define HDIM 64
#define DMODEL 1024
#define NBATCH 4
#define ATT_SCALE 0.125f
#define SEQHD (SEQ * HDIM)          // 131072
#define BHSTRIDE (2 * SEQHD)        // per-(b,h): K tile then V^T tile

// LDS slot invariant: L[row*64 + ((blk ^ (row&7))*8) + off] = SRC[row][blk*8+off]

__device__ __forceinline__ void stage64_block(const float* __restrict__ src, bf16* lds, int t) {
#pragma unroll
  for (int i = 0; i < 2; ++i) {
    int row = i * 32 + (t >> 3);
    int gb = t & 7;
    const float* p = src + (size_t)row * DMODEL + gb * 8;
    float4 f0 = *(const float4*)p;
    float4 f1 = *(const float4*)(p + 4);
    bf16x8 v;
    v[0] = (bf16)f0.x; v[1] = (bf16)f0.y; v[2] = (bf16)f0.z; v[3] = (bf16)f0.w;
    v[4] = (bf16)f1.x; v[5] = (bf16)f1.y; v[6] = (bf16)f1.z; v[7] = (bf16)f1.w;
    *(bf16x8*)(lds + row * 64 + ((gb ^ (row & 7)) * 8)) = v;
  }
}

__device__ __forceinline__ void stage64_wave(const float* __restrict__ src, bf16* lds, int lane) {
#pragma unroll
  for (int i = 0; i < 8; ++i) {
    int row = i * 8 + (lane >> 3);
    int gb = lane & 7;
    const float* p = src + (size_t)row * DMODEL + gb * 8;
    float4 f0 = *(const float4*)p;
    float4 f1 = *(const float4*)(p + 4);
    bf16x8 v;
    v[0] = (bf16)f0.x; v[1] = (bf16)f0.y; v[2] = (bf16)f0.z; v[3] = (bf16)f0.w;
    v[4] = (bf16)f1.x; v[5] = (bf16)f1.y; v[6] = (bf16)f1.z; v[7] = (bf16)f1.w;
    *(bf16x8*)(lds + row * 64 + ((gb ^ (row & 7)) * 8)) = v;
  }
}

__device__ __forceinline__ void stage64_wave_bf16(const bf16* __restrict__ src, bf16* lds, int lane) {
#pragma unroll
  for (int i = 0; i < 8; ++i) {
    int row = i * 8 + (lane >> 3);
    int gb = lane & 7;
    bf16x8 v = *(const bf16x8*)(src + (size_t)row * DMODEL + gb * 8);
    *(bf16x8*)(lds + row * 64 + ((gb ^ (row & 7)) * 8)) = v;
  }
}

// ---- Q projection for ALL batches: Qall[bh][s][hd] = (x*Wq_h^T + bq)*SCALE ----
__global__ __launch_bounds__(256) void qproj_kernel(
    const float* __restrict__ x, const float* __restrict__ Wq,
    const float* __restrict__ bq, bf16* __restrict__ Qall) {
  __shared__ __align__(16) bf16 lW[64 * 64];
  __shared__ __align__(16) bf16 lXw[4][64 * 64];
  const int t = threadIdx.x, wave = t >> 6, lane = t & 63;
  const int quad = lane >> 4, c = lane & 15;
  const int m0 = blockIdx.x * 256;           // token rows (0..8191)
  const int h = blockIdx.y;
  const float* W = Wq + (size_t)(h * HDIM) * DMODEL;
  bf16* pw = lXw[wave];
  f32x4 acc[4][4] = {};
  for (int k0 = 0; k0 < DMODEL; k0 += 64) {
    __syncthreads();
    stage64_block(W + k0, lW, t);
    stage64_wave(x + (size_t)(m0 + wave * 64) * DMODEL + k0, pw, lane);
    __syncthreads();
#pragma unroll
    for (int kk = 0; kk < 2; ++kk) {
      bf16x8 af[4], bfr[4];
#pragma unroll
      for (int mi = 0; mi < 4; ++mi) {
        int row = mi * 16 + c;
        af[mi] = *(const bf16x8*)(pw + row * 64 + (((kk * 4 + quad) ^ (row & 7)) * 8));
      }
#pragma unroll
      for (int ni = 0; ni < 4; ++ni) {
        int row = ni * 16 + c;
        bfr[ni] = *(const bf16x8*)(lW + row * 64 + (((kk * 4 + quad) ^ (row & 7)) * 8));
      }
#pragma unroll
      for (int mi = 0; mi < 4; ++mi)
#pragma unroll
        for (int ni = 0; ni < 4; ++ni)
          acc[mi][ni] = __builtin_amdgcn_mfma_f32_16x16x32_bf16(af[mi], bfr[ni], acc[mi][ni], 0, 0, 0);
    }
  }
#pragma unroll
  for (int ni = 0; ni < 4; ++ni) {
    int hd = ni * 16 + c;
    float bqv = bq[h * HDIM + hd];
#pragma unroll
    for (int mi = 0; mi < 4; ++mi)
#pragma unroll
      for (int r = 0; r < 4; ++r) {
        int tok = m0 + wave * 64 + mi * 16 + quad * 4 + r;
        int b = tok >> 11, s = tok & 2047;
        Qall[((size_t)(b * NHEAD + h) * SEQ + s) * HDIM + hd] = (bf16)((acc[mi][ni][r] + bqv) * ATT_SCALE);
      }
  }
}

// ---- K/V projection for one 2-batch chunk (4096 rows) ----
__global__ __launch_bounds__(256) void kvproj_kernel(
    const float* __restrict__ xc,
    const float* __restrict__ Wk, const float* __restrict__ bk,
    const float* __restrict__ Wv, const float* __restrict__ bv,
    bf16* __restrict__ scr) {
  __shared__ __align__(16) bf16 lW[64 * 64];
  __shared__ __align__(16) bf16 lXw[4][64 * 64];
  const int t = threadIdx.x, wave = t >> 6, lane = t & 63;
  const int quad = lane >> 4, c = lane & 15;
  const int m0 = blockIdx.x * 256;
  const int nt = blockIdx.y;
  const int h = nt >> 1, isV = nt & 1;
  const float* W = (isV ? Wv : Wk) + (size_t)(h * HDIM) * DMODEL;
  const float* bias = (isV ? bv : bk) + h * HDIM;
  bf16* pw = lXw[wave];
  f32x4 acc[4][4] = {};
  for (int k0 = 0; k0 < DMODEL; k0 += 64) {
    __syncthreads();
    stage64_block(W + k0, lW, t);
    stage64_wave(xc + (size_t)(m0 + wave * 64) * DMODEL + k0, pw, lane);
    __syncthreads();
#pragma unroll
    for (int kk = 0; kk < 2; ++kk) {
      bf16x8 af[4], bfr[4];
#pragma unroll
      for (int mi = 0; mi < 4; ++mi) {
        int row = mi * 16 + c;
        af[mi] = *(const bf16x8*)(pw + row * 64 + (((kk * 4 + quad) ^ (row & 7)) * 8));
      }
#pragma unroll
      for (int ni = 0; ni < 4; ++ni) {
        int row = ni * 16 + c;
        bfr[ni] = *(const bf16x8*)(lW + row * 64 + (((kk * 4 + quad) ^ (row & 7)) * 8));
      }
#pragma unroll
      for (int mi = 0; mi < 4; ++mi)
#pragma unroll
        for (int ni = 0; ni < 4; ++ni)
          acc[mi][ni] = __builtin_amdgcn_mfma_f32_16x16x32_bf16(af[mi], bfr[ni], acc[mi][ni], 0, 0, 0);
    }
  }
#pragma unroll
  for (int ni = 0; ni < 4; ++ni) {
    int hd = ni * 16 + c;
    float bv_ = bias[hd];
#pragma unroll
    for (int mi = 0; mi < 4; ++mi)
#pragma unroll
      for (int r = 0; r < 4; ++r) {
        int key = m0 + wave * 64 + mi * 16 + quad * 4 + r;
        int b_loc = key >> 11, s = key & 2047;
        bf16* base = scr + (size_t)(b_loc * NHEAD + h) * BHSTRIDE;
        float val = acc[mi][ni][r] + bv_;
        if (isV) base[SEQHD + (size_t)hd * SEQ + s] = (bf16)val;
        else     base[(size_t)s * HDIM + hd] = (bf16)val;
      }
  }
}

// ---- attention: ALL 4 batches in one launch; 2048 blocks of 128 threads.
//      XCD-aware swizzle: each bh's 32 q-tile blocks land on ONE XCD so its
//      512 KB K/V working set stays L2-resident (8 bh/XCD = 4 MB = one L2). ----
__global__ __launch_bounds__(128, 4) void attn4_kernel(
    const bf16* __restrict__ Qall, const bf16* __restrict__ KV0,
    const bf16* __restrict__ KV1, const int* __restrict__ mask,
    bf16* __restrict__ O) {
  __shared__ __align__(16) bf16 lPw[2][32 * 64];
  const int t = threadIdx.x, wave = t >> 6, lane = t & 63;
  const int quad = lane >> 4, c = lane & 15;
  // swizzle: i = slot*8 + xcd  (HW round-robins linear id across 8 XCDs)
  const int i = blockIdx.x;                  // 0..2047
  const int xcd = i & 7, slot = i >> 3;      // slot 0..255
  const int bh = xcd * 8 + (slot >> 5);      // 0..63, 8 bh per XCD
  const int qt = slot & 31;                  // 32 tiles of 64 q rows
  const int b = bh >> 4, h = bh & 15;
  const int q0 = qt * 64 + wave * 32;
  const bf16* Qh = Qall + (size_t)bh * SEQHD;
  const bf16* Kb = (b < 2 ? KV0 : KV1) + (size_t)((b & 1) * NHEAD + h) * BHSTRIDE;
  const bf16* Vtb = Kb + SEQHD;
  const int* maskG = mask + b * SEQ;
  bf16* pw = lPw[wave];

  // Q fragments (scale pre-folded at qproj)
  bf16x8 qf[2][2];
#pragma unroll
  for (int mi = 0; mi < 2; ++mi)
#pragma unroll
    for (int kk = 0; kk < 2; ++kk)
      qf[mi][kk] = *(const bf16x8*)(Qh + (size_t)(q0 + mi * 16 + c) * HDIM + kk * 32 + quad * 8);

  f32x4 oacc[2][4] = {};
  float mrun[2][4], lrun[2][4];
#pragma unroll
  for (int mi = 0; mi < 2; ++mi)
#pragma unroll
    for (int r = 0; r < 4; ++r) { mrun[mi][r] = -1e30f; lrun[mi][r] = 0.0f; }

  for (int kt = 0; kt < SEQ; kt += 64) {
    f32x4 sacc[2][4] = {};
    bf16x8 vf[2][4];
#pragma unroll
    for (int kk = 0; kk < 2; ++kk) {
      bf16x8 kf[4];
#pragma unroll
      for (int ni = 0; ni < 4; ++ni)
        kf[ni] = *(const bf16x8*)(Kb + (size_t)(kt + ni * 16 + c) * HDIM + kk * 32 + quad * 8);
#pragma unroll
      for (int ni = 0; ni < 4; ++ni)
        vf[kk][ni] = *(const bf16x8*)(Vtb + (size_t)(ni * 16 + c) * SEQ + kt + kk * 32 + quad * 8);
#pragma unroll
      for (int mi = 0; mi < 2; ++mi)
#pragma unroll
        for (int ni = 0; ni < 4; ++ni)
          sacc[mi][ni] = __builtin_amdgcn_mfma_f32_16x16x32_bf16(qf[mi][kk], kf[ni], sacc[mi][ni], 0, 0, 0);
    }

    float sm[4];
#pragma unroll
    for (int ni = 0; ni < 4; ++ni) sm[ni] = maskG[kt + ni * 16 + c] ? -3e38f : 0.0f;

#pragma unroll
    for (int mi = 0; mi < 2; ++mi) {
#pragma unroll
      for (int r = 0; r < 4; ++r) {
        float sv[4];
#pragma unroll
        for (int ni = 0; ni < 4; ++ni) sv[ni] = sacc[mi][ni][r] + sm[ni];
        float mx = fmaxf(fmaxf(sv[0], sv[1]), fmaxf(sv[2], sv[3]));
        mx = fmaxf(mx, __shfl_xor(mx, 1));
        mx = fmaxf(mx, __shfl_xor(mx, 2));
        mx = fmaxf(mx, __shfl_xor(mx, 4));
        mx = fmaxf(mx, __shfl_xor(mx, 8));
        float mo = mrun[mi][r];
        float mn = fmaxf(mo, mx);
        float al = __expf(mo - mn);
        mrun[mi][r] = mn;
        float rs = 0.0f, p[4];
#pragma unroll
        for (int ni = 0; ni < 4; ++ni) { p[ni] = __expf(sv[ni] - mn); rs += p[ni]; }
        rs += __shfl_xor(rs, 1);
        rs += __shfl_xor(rs, 2);
        rs += __shfl_xor(rs, 4);
        rs += __shfl_xor(rs, 8);
        lrun[mi][r] = lrun[mi][r] * al + rs;
        int row = mi * 16 + quad * 4 + r;
#pragma unroll
        for (int ni = 0; ni < 4; ++ni) {
          oacc[mi][ni][r] *= al;
          int colT = ni * 16 + c;
          pw[row * 64 + (((colT >> 3) ^ (row & 7)) * 8) + (colT & 7)] = (bf16)p[ni];
        }
      }
    }

#pragma unroll
    for (int kk = 0; kk < 2; ++kk) {
      bf16x8 pf[2];
#pragma unroll
      for (int mi = 0; mi < 2; ++mi) {
        int row = mi * 16 + c;
        pf[mi] = *(const bf16x8*)(pw + row * 64 + (((kk * 4 + quad) ^ (row & 7)) * 8));
      }
#pragma unroll
      for (int mi = 0; mi < 2; ++mi)
#pragma unroll
        for (int ni = 0; ni < 4; ++ni)
          oacc[mi][ni] = __builtin_amdgcn_mfma_f32_16x16x32_bf16(pf[mi], vf[kk][ni], oacc[mi][ni], 0, 0, 0);
    }
  }

  // epilogue: O[tok][h*64+hd] bf16, plain stores
#pragma unroll
  for (int mi = 0; mi < 2; ++mi)
#pragma unroll
    for (int r = 0; r < 4; ++r) {
      float lv = lrun[mi][r];
      float inv = lv > 0.0f ? 1.0f / lv : 0.0f;
      size_t tok = (size_t)b * SEQ + q0 + mi * 16 + quad * 4 + r;
#pragma unroll
      for (int ni = 0; ni < 4; ++ni)
        O[tok * DMODEL + h * HDIM + ni * 16 + c] = (bf16)(oacc[mi][ni][r] * inv);
    }
}

// ---- output projection: out = O*Wo^T + bo (fp32), deterministic ----
__global__ __launch_bounds__(256) void outproj_kernel(
    const bf16* __restrict__ O, const float* __restrict__ Wo,
    const float* __restrict__ bo, float* __restrict__ out) {
  __shared__ __align__(16) bf16 lW[64 * 64];
  __shared__ __align__(16) bf16 lXw[4][64 * 64];
  const int t = threadIdx.x, wave = t >> 6, lane = t & 63;
  const int quad = lane >> 4, c = lane & 15;
  const int m0 = blockIdx.x * 256;           // token rows
  const int n0 = blockIdx.y * 64;            // output cols
  bf16* pw = lXw[wave];
  f32x4 acc[4][4] = {};
  for (int k0 = 0; k0 < DMODEL; k0 += 64) {
    __syncthreads();
    stage64_block(Wo + (size_t)n0 * DMODEL + k0, lW, t);
    stage64_wave_bf16(O + (size_t)(m0 + wave * 64) * DMODEL + k0, pw, lane);
    __syncthreads();
#pragma unroll
    for (int kk = 0; kk < 2; ++kk) {
      bf16x8 af[4], bfr[4];
#pragma unroll
      for (int mi = 0; mi < 4; ++mi) {
        int row = mi * 16 + c;
        af[mi] = *(const bf16x8*)(pw + row * 64 + (((kk * 4 + quad) ^ (row & 7)) * 8));
      }
#pragma unroll
      for (int ni = 0; ni < 4; ++ni) {
        int row = ni * 16 + c;
        bfr[ni] = *(const bf16x8*)(lW + row * 64 + (((kk * 4 + quad) ^ (row & 7)) * 8));
      }
#pragma unroll
      for (int mi = 0; mi < 4; ++mi)
#pragma unroll
        for (int ni = 0; ni < 4; ++ni)
          acc[mi][ni] = __builtin_amdgcn_mfma_f32_16x16x32_bf16(af[mi], bfr[ni], acc[mi][ni], 0, 0, 0);
    }
  }
#pragma unroll
  for (int ni = 0; ni < 4; ++ni) {
    int gn = n0 + ni * 16 + c;
    float bv_ = bo[gn];
#pragma unroll
    for (int mi = 0; mi < 4; ++mi)
#pragma unroll
      for (int r = 0; r < 4; ++r) {
        int gm = m0 + wave * 64 + mi * 16 + quad * 4 + r;
        out[(size_t)gm * DMODEL + gn] = acc[mi][ni][r] + bv_;
      }
  }
}

extern "C" void kernel_launch(void* const* d_in, const int* in_sizes, int n_in,
                              void* d_out, int out_size, void* d_ws, size_t ws_size,
                              hipStream_t stream) {
  const float* x  = (const float*)d_in[0];
  const int*   mask = (const int*)d_in[1];
  const float* Wq = (const float*)d_in[2]; const float* bq = (const float*)d_in[3];
  const float* Wk = (const float*)d_in[4]; const float* bk = (const float*)d_in[5];
  const float* Wv = (const float*)d_in[6]; const float* bv = (const float*)d_in[7];
  const float* Wo = (const float*)d_in[8]; const float* bo = (const float*)d_in[9];
  float* out = (float*)d_out;
  char* outc = (char*)d_out;
  char* xc   = (char*)d_in[0];
  const size_t mat = (size_t)NBATCH * SEQ * DMODEL;  // 8,388,608 elems
  const size_t half = mat * 2;                        // 16.78 MB bytes

  // Buffer plan (d_ws unusable; d_in[0] restored by harness each launch):
  //   Qall (bf16, 16.78 MB)          -> d_out.lo
  //   KV0  (batches 0,1; 16.78 MB)   -> d_out.hi
  //   KV1  (batches 2,3; 16.78 MB)   -> x.lo   (kvproj1 reads x.hi only)
  //   O (bf16, 16.78 MB)             -> x.hi   (attn reads KV1=x.lo, writes x.hi)
  //   final fp32 out (33.55 MB)      -> d_out  (overwrites Qall+KV0, reads only O)
  bf16* Qall = (bf16*)d_out;
  bf16* KV0  = (bf16*)(outc + half);
  bf16* KV1  = (bf16*)xc;
  bf16* O    = (bf16*)(xc + half);

  qproj_kernel<<<dim3(32, 16), 256, 0, stream>>>(x, Wq, bq, Qall);
  kvproj_kernel<<<dim3(16, 32), 256, 0, stream>>>(x, Wk, bk, Wv, bv, KV0);
  kvproj_kernel<<<dim3(16, 32), 256, 0, stream>>>(x + (size_t)2 * SEQ * DMODEL, Wk, bk, Wv, bv, KV1);
  attn4_kernel<<<dim3(2048), 128, 0, stream>>>(Qall, KV0, KV1, mask, O);
  outproj_kernel<<<dim3(32, 16), 256, 0, stream>>>(O, Wo, bo, out);
}

// Round 2
// 638.958 us; speedup vs baseline: 1.3899x; 1.3899x over previous
//
#include <hip/hip_runtime.h>
#include <stdint.h>

typedef __bf16 bf16;
typedef __bf16 bf16x8 __attribute__((ext_vector_type(8)));
typedef float f32x4 __attribute__((ext_vector_type(4)));

#define SEQ 2048
#define NHEAD 16
#define HDIM 64
#define DMODEL 1024
#define NBATCH 4
#define ATT_SCALE 0.125f
#define SEQHD (SEQ * HDIM)          // 131072
#define BHSTRIDE (2 * SEQHD)        // per-(b,h): K tile then V^T tile

// LDS slot invariant: L[row*64 + ((blk ^ (row&7))*8) + off] = SRC[row][blk*8+off]

__device__ __forceinline__ void stage64_block(const float* __restrict__ src, bf16* lds, int t) {
#pragma unroll
  for (int i = 0; i < 2; ++i) {
    int row = i * 32 + (t >> 3);
    int gb = t & 7;
    const float* p = src + (size_t)row * DMODEL + gb * 8;
    float4 f0 = *(const float4*)p;
    float4 f1 = *(const float4*)(p + 4);
    bf16x8 v;
    v[0] = (bf16)f0.x; v[1] = (bf16)f0.y; v[2] = (bf16)f0.z; v[3] = (bf16)f0.w;
    v[4] = (bf16)f1.x; v[5] = (bf16)f1.y; v[6] = (bf16)f1.z; v[7] = (bf16)f1.w;
    *(bf16x8*)(lds + row * 64 + ((gb ^ (row & 7)) * 8)) = v;
  }
}

__device__ __forceinline__ void stage64_wave(const float* __restrict__ src, bf16* lds, int lane) {
#pragma unroll
  for (int i = 0; i < 8; ++i) {
    int row = i * 8 + (lane >> 3);
    int gb = lane & 7;
    const float* p = src + (size_t)row * DMODEL + gb * 8;
    float4 f0 = *(const float4*)p;
    float4 f1 = *(const float4*)(p + 4);
    bf16x8 v;
    v[0] = (bf16)f0.x; v[1] = (bf16)f0.y; v[2] = (bf16)f0.z; v[3] = (bf16)f0.w;
    v[4] = (bf16)f1.x; v[5] = (bf16)f1.y; v[6] = (bf16)f1.z; v[7] = (bf16)f1.w;
    *(bf16x8*)(lds + row * 64 + ((gb ^ (row & 7)) * 8)) = v;
  }
}

__device__ __forceinline__ void stage64_wave_bf16(const bf16* __restrict__ src, bf16* lds, int lane) {
#pragma unroll
  for (int i = 0; i < 8; ++i) {
    int row = i * 8 + (lane >> 3);
    int gb = lane & 7;
    bf16x8 v = *(const bf16x8*)(src + (size_t)row * DMODEL + gb * 8);
    *(bf16x8*)(lds + row * 64 + ((gb ^ (row & 7)) * 8)) = v;
  }
}

// ---- Q projection for ALL batches: Qall[bh][s][hd] = (x*Wq_h^T + bq)*SCALE ----
__global__ __launch_bounds__(256) void qproj_kernel(
    const float* __restrict__ x, const float* __restrict__ Wq,
    const float* __restrict__ bq, bf16* __restrict__ Qall) {
  __shared__ __align__(16) bf16 lW[64 * 64];
  __shared__ __align__(16) bf16 lXw[4][64 * 64];
  const int t = threadIdx.x, wave = t >> 6, lane = t & 63;
  const int quad = lane >> 4, c = lane & 15;
  const int m0 = blockIdx.x * 256;           // token rows (0..8191)
  const int h = blockIdx.y;
  const float* W = Wq + (size_t)(h * HDIM) * DMODEL;
  bf16* pw = lXw[wave];
  f32x4 acc[4][4] = {};
  for (int k0 = 0; k0 < DMODEL; k0 += 64) {
    __syncthreads();
    stage64_block(W + k0, lW, t);
    stage64_wave(x + (size_t)(m0 + wave * 64) * DMODEL + k0, pw, lane);
    __syncthreads();
#pragma unroll
    for (int kk = 0; kk < 2; ++kk) {
      bf16x8 af[4], bfr[4];
#pragma unroll
      for (int mi = 0; mi < 4; ++mi) {
        int row = mi * 16 + c;
        af[mi] = *(const bf16x8*)(pw + row * 64 + (((kk * 4 + quad) ^ (row & 7)) * 8));
      }
#pragma unroll
      for (int ni = 0; ni < 4; ++ni) {
        int row = ni * 16 + c;
        bfr[ni] = *(const bf16x8*)(lW + row * 64 + (((kk * 4 + quad) ^ (row & 7)) * 8));
      }
#pragma unroll
      for (int mi = 0; mi < 4; ++mi)
#pragma unroll
        for (int ni = 0; ni < 4; ++ni)
          acc[mi][ni] = __builtin_amdgcn_mfma_f32_16x16x32_bf16(af[mi], bfr[ni], acc[mi][ni], 0, 0, 0);
    }
  }
#pragma unroll
  for (int ni = 0; ni < 4; ++ni) {
    int hd = ni * 16 + c;
    float bqv = bq[h * HDIM + hd];
#pragma unroll
    for (int mi = 0; mi < 4; ++mi)
#pragma unroll
      for (int r = 0; r < 4; ++r) {
        int tok = m0 + wave * 64 + mi * 16 + quad * 4 + r;
        int b = tok >> 11, s = tok & 2047;
        Qall[((size_t)(b * NHEAD + h) * SEQ + s) * HDIM + hd] = (bf16)((acc[mi][ni][r] + bqv) * ATT_SCALE);
      }
  }
}

// ---- K/V projection for one 2-batch chunk (4096 rows) ----
__global__ __launch_bounds__(256) void kvproj_kernel(
    const float* __restrict__ xc,
    const float* __restrict__ Wk, const float* __restrict__ bk,
    const float* __restrict__ Wv, const float* __restrict__ bv,
    bf16* __restrict__ scr) {
  __shared__ __align__(16) bf16 lW[64 * 64];
  __shared__ __align__(16) bf16 lXw[4][64 * 64];
  const int t = threadIdx.x, wave = t >> 6, lane = t & 63;
  const int quad = lane >> 4, c = lane & 15;
  const int m0 = blockIdx.x * 256;
  const int nt = blockIdx.y;
  const int h = nt >> 1, isV = nt & 1;
  const float* W = (isV ? Wv : Wk) + (size_t)(h * HDIM) * DMODEL;
  const float* bias = (isV ? bv : bk) + h * HDIM;
  bf16* pw = lXw[wave];
  f32x4 acc[4][4] = {};
  for (int k0 = 0; k0 < DMODEL; k0 += 64) {
    __syncthreads();
    stage64_block(W + k0, lW, t);
    stage64_wave(xc + (size_t)(m0 + wave * 64) * DMODEL + k0, pw, lane);
    __syncthreads();
#pragma unroll
    for (int kk = 0; kk < 2; ++kk) {
      bf16x8 af[4], bfr[4];
#pragma unroll
      for (int mi = 0; mi < 4; ++mi) {
        int row = mi * 16 + c;
        af[mi] = *(const bf16x8*)(pw + row * 64 + (((kk * 4 + quad) ^ (row & 7)) * 8));
      }
#pragma unroll
      for (int ni = 0; ni < 4; ++ni) {
        int row = ni * 16 + c;
        bfr[ni] = *(const bf16x8*)(lW + row * 64 + (((kk * 4 + quad) ^ (row & 7)) * 8));
      }
#pragma unroll
      for (int mi = 0; mi < 4; ++mi)
#pragma unroll
        for (int ni = 0; ni < 4; ++ni)
          acc[mi][ni] = __builtin_amdgcn_mfma_f32_16x16x32_bf16(af[mi], bfr[ni], acc[mi][ni], 0, 0, 0);
    }
  }
#pragma unroll
  for (int ni = 0; ni < 4; ++ni) {
    int hd = ni * 16 + c;
    float bv_ = bias[hd];
#pragma unroll
    for (int mi = 0; mi < 4; ++mi)
#pragma unroll
      for (int r = 0; r < 4; ++r) {
        int key = m0 + wave * 64 + mi * 16 + quad * 4 + r;
        int b_loc = key >> 11, s = key & 2047;
        bf16* base = scr + (size_t)(b_loc * NHEAD + h) * BHSTRIDE;
        float val = acc[mi][ni][r] + bv_;
        if (isV) base[SEQHD + (size_t)hd * SEQ + s] = (bf16)val;
        else     base[(size_t)s * HDIM + hd] = (bf16)val;
      }
  }
}

// ---- attention: ALL 4 batches in one launch; 2048 blocks of 128 threads.
//      XCD-aware swizzle: each bh's 32 q-tile blocks land on ONE XCD so its
//      512 KB K/V working set stays L2-resident (8 bh/XCD = 4 MB = one L2).
//      launch_bounds(128,3): (128,4) capped VGPR at 64 -> scratch spills,
//      466 MB WRITE_SIZE, 637 us. At (,3) this body compiles to 84 VGPR, 0 spill. ----
__global__ __launch_bounds__(128, 3) void attn4_kernel(
    const bf16* __restrict__ Qall, const bf16* __restrict__ KV0,
    const bf16* __restrict__ KV1, const int* __restrict__ mask,
    bf16* __restrict__ O) {
  __shared__ __align__(16) bf16 lPw[2][32 * 64];
  const int t = threadIdx.x, wave = t >> 6, lane = t & 63;
  const int quad = lane >> 4, c = lane & 15;
  // swizzle: i = slot*8 + xcd  (HW round-robins linear id across 8 XCDs)
  const int i = blockIdx.x;                  // 0..2047
  const int xcd = i & 7, slot = i >> 3;      // slot 0..255
  const int bh = xcd * 8 + (slot >> 5);      // 0..63, 8 bh per XCD
  const int qt = slot & 31;                  // 32 tiles of 64 q rows
  const int b = bh >> 4, h = bh & 15;
  const int q0 = qt * 64 + wave * 32;
  const bf16* Qh = Qall + (size_t)bh * SEQHD;
  const bf16* Kb = (b < 2 ? KV0 : KV1) + (size_t)((b & 1) * NHEAD + h) * BHSTRIDE;
  const bf16* Vtb = Kb + SEQHD;
  const int* maskG = mask + b * SEQ;
  bf16* pw = lPw[wave];

  // Q fragments (scale pre-folded at qproj)
  bf16x8 qf[2][2];
#pragma unroll
  for (int mi = 0; mi < 2; ++mi)
#pragma unroll
    for (int kk = 0; kk < 2; ++kk)
      qf[mi][kk] = *(const bf16x8*)(Qh + (size_t)(q0 + mi * 16 + c) * HDIM + kk * 32 + quad * 8);

  f32x4 oacc[2][4] = {};
  float mrun[2][4], lrun[2][4];
#pragma unroll
  for (int mi = 0; mi < 2; ++mi)
#pragma unroll
    for (int r = 0; r < 4; ++r) { mrun[mi][r] = -1e30f; lrun[mi][r] = 0.0f; }

  for (int kt = 0; kt < SEQ; kt += 64) {
    f32x4 sacc[2][4] = {};
    bf16x8 vf[2][4];
#pragma unroll
    for (int kk = 0; kk < 2; ++kk) {
      bf16x8 kf[4];
#pragma unroll
      for (int ni = 0; ni < 4; ++ni)
        kf[ni] = *(const bf16x8*)(Kb + (size_t)(kt + ni * 16 + c) * HDIM + kk * 32 + quad * 8);
#pragma unroll
      for (int ni = 0; ni < 4; ++ni)
        vf[kk][ni] = *(const bf16x8*)(Vtb + (size_t)(ni * 16 + c) * SEQ + kt + kk * 32 + quad * 8);
#pragma unroll
      for (int mi = 0; mi < 2; ++mi)
#pragma unroll
        for (int ni = 0; ni < 4; ++ni)
          sacc[mi][ni] = __builtin_amdgcn_mfma_f32_16x16x32_bf16(qf[mi][kk], kf[ni], sacc[mi][ni], 0, 0, 0);
    }

    float sm[4];
#pragma unroll
    for (int ni = 0; ni < 4; ++ni) sm[ni] = maskG[kt + ni * 16 + c] ? -3e38f : 0.0f;

#pragma unroll
    for (int mi = 0; mi < 2; ++mi) {
#pragma unroll
      for (int r = 0; r < 4; ++r) {
        float sv[4];
#pragma unroll
        for (int ni = 0; ni < 4; ++ni) sv[ni] = sacc[mi][ni][r] + sm[ni];
        float mx = fmaxf(fmaxf(sv[0], sv[1]), fmaxf(sv[2], sv[3]));
        mx = fmaxf(mx, __shfl_xor(mx, 1));
        mx = fmaxf(mx, __shfl_xor(mx, 2));
        mx = fmaxf(mx, __shfl_xor(mx, 4));
        mx = fmaxf(mx, __shfl_xor(mx, 8));
        float mo = mrun[mi][r];
        float mn = fmaxf(mo, mx);
        float al = __expf(mo - mn);
        mrun[mi][r] = mn;
        float rs = 0.0f, p[4];
#pragma unroll
        for (int ni = 0; ni < 4; ++ni) { p[ni] = __expf(sv[ni] - mn); rs += p[ni]; }
        rs += __shfl_xor(rs, 1);
        rs += __shfl_xor(rs, 2);
        rs += __shfl_xor(rs, 4);
        rs += __shfl_xor(rs, 8);
        lrun[mi][r] = lrun[mi][r] * al + rs;
        int row = mi * 16 + quad * 4 + r;
#pragma unroll
        for (int ni = 0; ni < 4; ++ni) {
          oacc[mi][ni][r] *= al;
          int colT = ni * 16 + c;
          pw[row * 64 + (((colT >> 3) ^ (row & 7)) * 8) + (colT & 7)] = (bf16)p[ni];
        }
      }
    }

#pragma unroll
    for (int kk = 0; kk < 2; ++kk) {
      bf16x8 pf[2];
#pragma unroll
      for (int mi = 0; mi < 2; ++mi) {
        int row = mi * 16 + c;
        pf[mi] = *(const bf16x8*)(pw + row * 64 + (((kk * 4 + quad) ^ (row & 7)) * 8));
      }
#pragma unroll
      for (int mi = 0; mi < 2; ++mi)
#pragma unroll
        for (int ni = 0; ni < 4; ++ni)
          oacc[mi][ni] = __builtin_amdgcn_mfma_f32_16x16x32_bf16(pf[mi], vf[kk][ni], oacc[mi][ni], 0, 0, 0);
    }
  }

  // epilogue: O[tok][h*64+hd] bf16, plain stores
#pragma unroll
  for (int mi = 0; mi < 2; ++mi)
#pragma unroll
    for (int r = 0; r < 4; ++r) {
      float lv = lrun[mi][r];
      float inv = lv > 0.0f ? 1.0f / lv : 0.0f;
      size_t tok = (size_t)b * SEQ + q0 + mi * 16 + quad * 4 + r;
#pragma unroll
      for (int ni = 0; ni < 4; ++ni)
        O[tok * DMODEL + h * HDIM + ni * 16 + c] = (bf16)(oacc[mi][ni][r] * inv);
    }
}

// ---- output projection: out = O*Wo^T + bo (fp32), deterministic ----
__global__ __launch_bounds__(256) void outproj_kernel(
    const bf16* __restrict__ O, const float* __restrict__ Wo,
    const float* __restrict__ bo, float* __restrict__ out) {
  __shared__ __align__(16) bf16 lW[64 * 64];
  __shared__ __align__(16) bf16 lXw[4][64 * 64];
  const int t = threadIdx.x, wave = t >> 6, lane = t & 63;
  const int quad = lane >> 4, c = lane & 15;
  const int m0 = blockIdx.x * 256;           // token rows
  const int n0 = blockIdx.y * 64;            // output cols
  bf16* pw = lXw[wave];
  f32x4 acc[4][4] = {};
  for (int k0 = 0; k0 < DMODEL; k0 += 64) {
    __syncthreads();
    stage64_block(Wo + (size_t)n0 * DMODEL + k0, lW, t);
    stage64_wave_bf16(O + (size_t)(m0 + wave * 64) * DMODEL + k0, pw, lane);
    __syncthreads();
#pragma unroll
    for (int kk = 0; kk < 2; ++kk) {
      bf16x8 af[4], bfr[4];
#pragma unroll
      for (int mi = 0; mi < 4; ++mi) {
        int row = mi * 16 + c;
        af[mi] = *(const bf16x8*)(pw + row * 64 + (((kk * 4 + quad) ^ (row & 7)) * 8));
      }
#pragma unroll
      for (int ni = 0; ni < 4; ++ni) {
        int row = ni * 16 + c;
        bfr[ni] = *(const bf16x8*)(lW + row * 64 + (((kk * 4 + quad) ^ (row & 7)) * 8));
      }
#pragma unroll
      for (int mi = 0; mi < 4; ++mi)
#pragma unroll
        for (int ni = 0; ni < 4; ++ni)
          acc[mi][ni] = __builtin_amdgcn_mfma_f32_16x16x32_bf16(af[mi], bfr[ni], acc[mi][ni], 0, 0, 0);
    }
  }
#pragma unroll
  for (int ni = 0; ni < 4; ++ni) {
    int gn = n0 + ni * 16 + c;
    float bv_ = bo[gn];
#pragma unroll
    for (int mi = 0; mi < 4; ++mi)
#pragma unroll
      for (int r = 0; r < 4; ++r) {
        int gm = m0 + wave * 64 + mi * 16 + quad * 4 + r;
        out[(size_t)gm * DMODEL + gn] = acc[mi][ni][r] + bv_;
      }
  }
}

extern "C" void kernel_launch(void* const* d_in, const int* in_sizes, int n_in,
                              void* d_out, int out_size, void* d_ws, size_t ws_size,
                              hipStream_t stream) {
  const float* x  = (const float*)d_in[0];
  const int*   mask = (const int*)d_in[1];
  const float* Wq = (const float*)d_in[2]; const float* bq = (const float*)d_in[3];
  const float* Wk = (const float*)d_in[4]; const float* bk = (const float*)d_in[5];
  const float* Wv = (const float*)d_in[6]; const float* bv = (const float*)d_in[7];
  const float* Wo = (const float*)d_in[8]; const float* bo = (const float*)d_in[9];
  float* out = (float*)d_out;
  char* outc = (char*)d_out;
  char* xc   = (char*)d_in[0];
  const size_t mat = (size_t)NBATCH * SEQ * DMODEL;  // 8,388,608 elems
  const size_t half = mat * 2;                        // 16.78 MB bytes

  // Buffer plan (d_ws unusable; d_in[0] restored by harness each launch):
  //   Qall (bf16, 16.78 MB)          -> d_out.lo
  //   KV0  (batches 0,1; 16.78 MB)   -> d_out.hi
  //   KV1  (batches 2,3; 16.78 MB)   -> x.lo   (kvproj1 reads x.hi only)
  //   O (bf16, 16.78 MB)             -> x.hi   (attn reads KV1=x.lo, writes x.hi)
  //   final fp32 out (33.55 MB)      -> d_out  (overwrites Qall+KV0, reads only O)
  bf16* Qall = (bf16*)d_out;
  bf16* KV0  = (bf16*)(outc + half);
  bf16* KV1  = (bf16*)xc;
  bf16* O    = (bf16*)(xc + half);

  qproj_kernel<<<dim3(32, 16), 256, 0, stream>>>(x, Wq, bq, Qall);
  kvproj_kernel<<<dim3(16, 32), 256, 0, stream>>>(x, Wk, bk, Wv, bv, KV0);
  kvproj_kernel<<<dim3(16, 32), 256, 0, stream>>>(x + (size_t)2 * SEQ * DMODEL, Wk, bk, Wv, bv, KV1);
  attn4_kernel<<<dim3(2048), 128, 0, stream>>>(Qall, KV0, KV1, mask, O);
  outproj_kernel<<<dim3(32, 16), 256, 0, stream>>>(O, Wo, bo, out);
}

// Round 3
// 589.303 us; speedup vs baseline: 1.5070x; 1.0843x over previous
//
#include <hip/hip_runtime.h>
#include <stdint.h>

typedef __bf16 bf16;
typedef __bf16 bf16x8 __attribute__((ext_vector_type(8)));
typedef float f32x4 __attribute__((ext_vector_type(4)));

#define SEQ 2048
#define NHEAD 16
#define HDIM 64
#define DMODEL 1024
#define NBATCH 4
// 0.125 * log2(e): softmax runs in exp2 domain (saves the 1.4427 mul per exp)
#define ATT_SCALE 0.18033688011112042f
#define SEQHD (SEQ * HDIM)          // 131072
#define BHSTRIDE (2 * SEQHD)        // per-(b,h): K tile then V^T tile

// LDS slot invariant: L[row*64 + ((blk ^ (row&7))*8) + off] = SRC[row][blk*8+off]

__device__ __forceinline__ void gload_lds16(const bf16* g, bf16* l) {
  __builtin_amdgcn_global_load_lds(
      (const __attribute__((address_space(1))) uint32_t*)g,
      (__attribute__((address_space(3))) uint32_t*)l, 16, 0, 0);
}

__device__ __forceinline__ void stage64_block(const float* __restrict__ src, bf16* lds, int t) {
#pragma unroll
  for (int i = 0; i < 2; ++i) {
    int row = i * 32 + (t >> 3);
    int gb = t & 7;
    const float* p = src + (size_t)row * DMODEL + gb * 8;
    float4 f0 = *(const float4*)p;
    float4 f1 = *(const float4*)(p + 4);
    bf16x8 v;
    v[0] = (bf16)f0.x; v[1] = (bf16)f0.y; v[2] = (bf16)f0.z; v[3] = (bf16)f0.w;
    v[4] = (bf16)f1.x; v[5] = (bf16)f1.y; v[6] = (bf16)f1.z; v[7] = (bf16)f1.w;
    *(bf16x8*)(lds + row * 64 + ((gb ^ (row & 7)) * 8)) = v;
  }
}

__device__ __forceinline__ void stage64_wave(const float* __restrict__ src, bf16* lds, int lane) {
#pragma unroll
  for (int i = 0; i < 8; ++i) {
    int row = i * 8 + (lane >> 3);
    int gb = lane & 7;
    const float* p = src + (size_t)row * DMODEL + gb * 8;
    float4 f0 = *(const float4*)p;
    float4 f1 = *(const float4*)(p + 4);
    bf16x8 v;
    v[0] = (bf16)f0.x; v[1] = (bf16)f0.y; v[2] = (bf16)f0.z; v[3] = (bf16)f0.w;
    v[4] = (bf16)f1.x; v[5] = (bf16)f1.y; v[6] = (bf16)f1.z; v[7] = (bf16)f1.w;
    *(bf16x8*)(lds + row * 64 + ((gb ^ (row & 7)) * 8)) = v;
  }
}

__device__ __forceinline__ void stage64_wave_bf16(const bf16* __restrict__ src, bf16* lds, int lane) {
#pragma unroll
  for (int i = 0; i < 8; ++i) {
    int row = i * 8 + (lane >> 3);
    int gb = lane & 7;
    bf16x8 v = *(const bf16x8*)(src + (size_t)row * DMODEL + gb * 8);
    *(bf16x8*)(lds + row * 64 + ((gb ^ (row & 7)) * 8)) = v;
  }
}

// ---- Q projection for ALL batches: Qall[bh][s][hd] = (x*Wq_h^T + bq)*SCALE ----
__global__ __launch_bounds__(256) void qproj_kernel(
    const float* __restrict__ x, const float* __restrict__ Wq,
    const float* __restrict__ bq, bf16* __restrict__ Qall) {
  __shared__ __align__(16) bf16 lW[64 * 64];
  __shared__ __align__(16) bf16 lXw[4][64 * 64];
  const int t = threadIdx.x, wave = t >> 6, lane = t & 63;
  const int quad = lane >> 4, c = lane & 15;
  const int m0 = blockIdx.x * 256;           // token rows (0..8191)
  const int h = blockIdx.y;
  const float* W = Wq + (size_t)(h * HDIM) * DMODEL;
  bf16* pw = lXw[wave];
  f32x4 acc[4][4] = {};
  for (int k0 = 0; k0 < DMODEL; k0 += 64) {
    __syncthreads();
    stage64_block(W + k0, lW, t);
    stage64_wave(x + (size_t)(m0 + wave * 64) * DMODEL + k0, pw, lane);
    __syncthreads();
#pragma unroll
    for (int kk = 0; kk < 2; ++kk) {
      bf16x8 af[4], bfr[4];
#pragma unroll
      for (int mi = 0; mi < 4; ++mi) {
        int row = mi * 16 + c;
        af[mi] = *(const bf16x8*)(pw + row * 64 + (((kk * 4 + quad) ^ (row & 7)) * 8));
      }
#pragma unroll
      for (int ni = 0; ni < 4; ++ni) {
        int row = ni * 16 + c;
        bfr[ni] = *(const bf16x8*)(lW + row * 64 + (((kk * 4 + quad) ^ (row & 7)) * 8));
      }
#pragma unroll
      for (int mi = 0; mi < 4; ++mi)
#pragma unroll
        for (int ni = 0; ni < 4; ++ni)
          acc[mi][ni] = __builtin_amdgcn_mfma_f32_16x16x32_bf16(af[mi], bfr[ni], acc[mi][ni], 0, 0, 0);
    }
  }
#pragma unroll
  for (int ni = 0; ni < 4; ++ni) {
    int hd = ni * 16 + c;
    float bqv = bq[h * HDIM + hd];
#pragma unroll
    for (int mi = 0; mi < 4; ++mi)
#pragma unroll
      for (int r = 0; r < 4; ++r) {
        int tok = m0 + wave * 64 + mi * 16 + quad * 4 + r;
        int b = tok >> 11, s = tok & 2047;
        Qall[((size_t)(b * NHEAD + h) * SEQ + s) * HDIM + hd] = (bf16)((acc[mi][ni][r] + bqv) * ATT_SCALE);
      }
  }
}

// ---- K/V projection for one 2-batch chunk (4096 rows) ----
__global__ __launch_bounds__(256) void kvproj_kernel(
    const float* __restrict__ xc,
    const float* __restrict__ Wk, const float* __restrict__ bk,
    const float* __restrict__ Wv, const float* __restrict__ bv,
    bf16* __restrict__ scr) {
  __shared__ __align__(16) bf16 lW[64 * 64];
  __shared__ __align__(16) bf16 lXw[4][64 * 64];
  const int t = threadIdx.x, wave = t >> 6, lane = t & 63;
  const int quad = lane >> 4, c = lane & 15;
  const int m0 = blockIdx.x * 256;
  const int nt = blockIdx.y;
  const int h = nt >> 1, isV = nt & 1;
  const float* W = (isV ? Wv : Wk) + (size_t)(h * HDIM) * DMODEL;
  const float* bias = (isV ? bv : bk) + h * HDIM;
  bf16* pw = lXw[wave];
  f32x4 acc[4][4] = {};
  for (int k0 = 0; k0 < DMODEL; k0 += 64) {
    __syncthreads();
    stage64_block(W + k0, lW, t);
    stage64_wave(xc + (size_t)(m0 + wave * 64) * DMODEL + k0, pw, lane);
    __syncthreads();
#pragma unroll
    for (int kk = 0; kk < 2; ++kk) {
      bf16x8 af[4], bfr[4];
#pragma unroll
      for (int mi = 0; mi < 4; ++mi) {
        int row = mi * 16 + c;
        af[mi] = *(const bf16x8*)(pw + row * 64 + (((kk * 4 + quad) ^ (row & 7)) * 8));
      }
#pragma unroll
      for (int ni = 0; ni < 4; ++ni) {
        int row = ni * 16 + c;
        bfr[ni] = *(const bf16x8*)(lW + row * 64 + (((kk * 4 + quad) ^ (row & 7)) * 8));
      }
#pragma unroll
      for (int mi = 0; mi < 4; ++mi)
#pragma unroll
        for (int ni = 0; ni < 4; ++ni)
          acc[mi][ni] = __builtin_amdgcn_mfma_f32_16x16x32_bf16(af[mi], bfr[ni], acc[mi][ni], 0, 0, 0);
    }
  }
#pragma unroll
  for (int ni = 0; ni < 4; ++ni) {
    int hd = ni * 16 + c;
    float bv_ = bias[hd];
#pragma unroll
    for (int mi = 0; mi < 4; ++mi)
#pragma unroll
      for (int r = 0; r < 4; ++r) {
        int key = m0 + wave * 64 + mi * 16 + quad * 4 + r;
        int b_loc = key >> 11, s = key & 2047;
        bf16* base = scr + (size_t)(b_loc * NHEAD + h) * BHSTRIDE;
        float val = acc[mi][ni][r] + bv_;
        if (isV) base[SEQHD + (size_t)hd * SEQ + s] = (bf16)val;
        else     base[(size_t)s * HDIM + hd] = (bf16)val;
      }
  }
}

// ---- attention: ALL 4 batches in one launch; 2048 blocks of 128 threads.
//      XCD-aware swizzle (8 bh per XCD -> 4 MB K/V per L2).
//      K and V tiles cooperatively staged in LDS via global_load_lds (16B),
//      single-buffered each, pipelined one phase ahead:
//        stage V[kt] at top -> QK(lK[kt]) -> barrier A -> stage K[kt+1]
//        -> softmax+PV(lV[kt]) -> barrier B -> stage V[kt+1]
//      LDS layout keeps the XOR-swizzle invariant by pre-swizzling the
//      GLOBAL source address (linear LDS dest, global_load_lds constraint).
//      VGPR budget: keep <=80 for 3 waves/SIMD (84->88 alloc gave 2/SIMD, R2). ----
__global__ __launch_bounds__(128, 3) void attn4_kernel(
    const bf16* __restrict__ Qall, const bf16* __restrict__ KV0,
    const bf16* __restrict__ KV1, const int* __restrict__ mask,
    bf16* __restrict__ O) {
  __shared__ __align__(16) bf16 lK[64 * 64];
  __shared__ __align__(16) bf16 lV[64 * 64];
  __shared__ __align__(16) bf16 lPw[2][32 * 64];
  const int t = threadIdx.x, wave = t >> 6, lane = t & 63;
  const int quad = lane >> 4, c = lane & 15;
  // swizzle: i = slot*8 + xcd  (HW round-robins linear id across 8 XCDs)
  const int i = blockIdx.x;                  // 0..2047
  const int xcd = i & 7, slot = i >> 3;      // slot 0..255
  const int bh = xcd * 8 + (slot >> 5);      // 0..63, 8 bh per XCD
  const int qt = slot & 31;                  // 32 tiles of 64 q rows
  const int b = bh >> 4, h = bh & 15;
  const int q0 = qt * 64 + wave * 32;
  const bf16* Qh = Qall + (size_t)bh * SEQHD;
  const bf16* Kb = (b < 2 ? KV0 : KV1) + (size_t)((b & 1) * NHEAD + h) * BHSTRIDE;
  const bf16* Vtb = Kb + SEQHD;
  const int* maskG = mask + b * SEQ;
  bf16* pw = lPw[wave];

  // per-thread staging constants: thread t covers row (i2*16 + t/8), source
  // col-block ((t&7) ^ (row&7)) -- row&7 == (t>>3)&7 for all i2 (i2*16 % 8 == 0)
  const int srow = t >> 3;                              // 0..15
  const int sswz = (t & 7) ^ (srow & 7);
  const bf16* kSrc = Kb + (size_t)srow * HDIM + sswz * 8;   // + kt*HDIM + i2*16*HDIM
  const bf16* vSrc = Vtb + (size_t)srow * SEQ + sswz * 8;   // + kt       + i2*16*SEQ
  bf16* kDst = lK + wave * 512;                             // + i2*1024 (HW adds lane*16B)
  bf16* vDst = lV + wave * 512;

  // Q fragments (scale+log2e pre-folded at qproj)
  bf16x8 qf[2][2];
#pragma unroll
  for (int mi = 0; mi < 2; ++mi)
#pragma unroll
    for (int kk = 0; kk < 2; ++kk)
      qf[mi][kk] = *(const bf16x8*)(Qh + (size_t)(q0 + mi * 16 + c) * HDIM + kk * 32 + quad * 8);

  f32x4 oacc[2][4] = {};
  float mrun[2][4], lrun[2][4];
#pragma unroll
  for (int mi = 0; mi < 2; ++mi)
#pragma unroll
    for (int r = 0; r < 4; ++r) { mrun[mi][r] = -1e30f; lrun[mi][r] = 0.0f; }

  // prologue: stage tile 0 (K and V)
#pragma unroll
  for (int i2 = 0; i2 < 4; ++i2) {
    gload_lds16(kSrc + i2 * 16 * HDIM, kDst + i2 * 1024);
    gload_lds16(vSrc + (size_t)i2 * 16 * SEQ, vDst + i2 * 1024);
  }
  __syncthreads();

  for (int kt = 0; kt < SEQ; kt += 64) {
    // mask loads issued early; consumed after barrier A (latency hidden)
    float sm[4];
#pragma unroll
    for (int ni = 0; ni < 4; ++ni) sm[ni] = maskG[kt + ni * 16 + c] ? -3e38f : 0.0f;

    // QK^T from lK
    f32x4 sacc[2][4] = {};
#pragma unroll
    for (int kk = 0; kk < 2; ++kk) {
      bf16x8 kf[4];
#pragma unroll
      for (int ni = 0; ni < 4; ++ni) {
        int row = ni * 16 + c;
        kf[ni] = *(const bf16x8*)(lK + row * 64 + (((kk * 4 + quad) ^ (row & 7)) * 8));
      }
#pragma unroll
      for (int mi = 0; mi < 2; ++mi)
#pragma unroll
        for (int ni = 0; ni < 4; ++ni)
          sacc[mi][ni] = __builtin_amdgcn_mfma_f32_16x16x32_bf16(qf[mi][kk], kf[ni], sacc[mi][ni], 0, 0, 0);
    }

    __syncthreads();  // A: all waves done reading lK; V[kt] staging drained
    if (kt + 64 < SEQ) {
      const bf16* ks = kSrc + (size_t)(kt + 64) * HDIM;
#pragma unroll
      for (int i2 = 0; i2 < 4; ++i2) gload_lds16(ks + i2 * 16 * HDIM, kDst + i2 * 1024);
    }

    // online softmax (exp2 domain)
#pragma unroll
    for (int mi = 0; mi < 2; ++mi) {
#pragma unroll
      for (int r = 0; r < 4; ++r) {
        float sv[4];
#pragma unroll
        for (int ni = 0; ni < 4; ++ni) sv[ni] = sacc[mi][ni][r] + sm[ni];
        float mx = fmaxf(fmaxf(sv[0], sv[1]), fmaxf(sv[2], sv[3]));
        mx = fmaxf(mx, __shfl_xor(mx, 1));
        mx = fmaxf(mx, __shfl_xor(mx, 2));
        mx = fmaxf(mx, __shfl_xor(mx, 4));
        mx = fmaxf(mx, __shfl_xor(mx, 8));
        float mo = mrun[mi][r];
        float mn = fmaxf(mo, mx);
        float al = __builtin_amdgcn_exp2f(mo - mn);
        mrun[mi][r] = mn;
        float rs = 0.0f, p[4];
#pragma unroll
        for (int ni = 0; ni < 4; ++ni) { p[ni] = __builtin_amdgcn_exp2f(sv[ni] - mn); rs += p[ni]; }
        rs += __shfl_xor(rs, 1);
        rs += __shfl_xor(rs, 2);
        rs += __shfl_xor(rs, 4);
        rs += __shfl_xor(rs, 8);
        lrun[mi][r] = lrun[mi][r] * al + rs;
        int row = mi * 16 + quad * 4 + r;
#pragma unroll
        for (int ni = 0; ni < 4; ++ni) {
          oacc[mi][ni][r] *= al;
          int colT = ni * 16 + c;
          pw[row * 64 + (((colT >> 3) ^ (row & 7)) * 8) + (colT & 7)] = (bf16)p[ni];
        }
      }
    }

    // PV from lPw (own wave) and lV
#pragma unroll
    for (int kk = 0; kk < 2; ++kk) {
      bf16x8 pf[2], vfr[4];
#pragma unroll
      for (int mi = 0; mi < 2; ++mi) {
        int row = mi * 16 + c;
        pf[mi] = *(const bf16x8*)(pw + row * 64 + (((kk * 4 + quad) ^ (row & 7)) * 8));
      }
#pragma unroll
      for (int ni = 0; ni < 4; ++ni) {
        int row = ni * 16 + c;
        vfr[ni] = *(const bf16x8*)(lV + row * 64 + (((kk * 4 + quad) ^ (row & 7)) * 8));
      }
#pragma unroll
      for (int mi = 0; mi < 2; ++mi)
#pragma unroll
        for (int ni = 0; ni < 4; ++ni)
          oacc[mi][ni] = __builtin_amdgcn_mfma_f32_16x16x32_bf16(pf[mi], vfr[ni], oacc[mi][ni], 0, 0, 0);
    }

    __syncthreads();  // B: all waves done reading lV; K[kt+64] staging drained
    if (kt + 64 < SEQ) {
      const bf16* vs = vSrc + (kt + 64);
#pragma unroll
      for (int i2 = 0; i2 < 4; ++i2) gload_lds16(vs + (size_t)i2 * 16 * SEQ, vDst + i2 * 1024);
    }
  }

  // epilogue: O[tok][h*64+hd] bf16, plain stores
#pragma unroll
  for (int mi = 0; mi < 2; ++mi)
#pragma unroll
    for (int r = 0; r < 4; ++r) {
      float lv = lrun[mi][r];
      float inv = lv > 0.0f ? 1.0f / lv : 0.0f;
      size_t tok = (size_t)b * SEQ + q0 + mi * 16 + quad * 4 + r;
#pragma unroll
      for (int ni = 0; ni < 4; ++ni)
        O[tok * DMODEL + h * HDIM + ni * 16 + c] = (bf16)(oacc[mi][ni][r] * inv);
    }
}

// ---- output projection: out = O*Wo^T + bo (fp32), deterministic ----
__global__ __launch_bounds__(256) void outproj_kernel(
    const bf16* __restrict__ O, const float* __restrict__ Wo,
    const float* __restrict__ bo, float* __restrict__ out) {
  __shared__ __align__(16) bf16 lW[64 * 64];
  __shared__ __align__(16) bf16 lXw[4][64 * 64];
  const int t = threadIdx.x, wave = t >> 6, lane = t & 63;
  const int quad = lane >> 4, c = lane & 15;
  const int m0 = blockIdx.x * 256;           // token rows
  const int n0 = blockIdx.y * 64;            // output cols
  bf16* pw = lXw[wave];
  f32x4 acc[4][4] = {};
  for (int k0 = 0; k0 < DMODEL; k0 += 64) {
    __syncthreads();
    stage64_block(Wo + (size_t)n0 * DMODEL + k0, lW, t);
    stage64_wave_bf16(O + (size_t)(m0 + wave * 64) * DMODEL + k0, pw, lane);
    __syncthreads();
#pragma unroll
    for (int kk = 0; kk < 2; ++kk) {
      bf16x8 af[4], bfr[4];
#pragma unroll
      for (int mi = 0; mi < 4; ++mi) {
        int row = mi * 16 + c;
        af[mi] = *(const bf16x8*)(pw + row * 64 + (((kk * 4 + quad) ^ (row & 7)) * 8));
      }
#pragma unroll
      for (int ni = 0; ni < 4; ++ni) {
        int row = ni * 16 + c;
        bfr[ni] = *(const bf16x8*)(lW + row * 64 + (((kk * 4 + quad) ^ (row & 7)) * 8));
      }
#pragma unroll
      for (int mi = 0; mi < 4; ++mi)
#pragma unroll
        for (int ni = 0; ni < 4; ++ni)
          acc[mi][ni] = __builtin_amdgcn_mfma_f32_16x16x32_bf16(af[mi], bfr[ni], acc[mi][ni], 0, 0, 0);
    }
  }
#pragma unroll
  for (int ni = 0; ni < 4; ++ni) {
    int gn = n0 + ni * 16 + c;
    float bv_ = bo[gn];
#pragma unroll
    for (int mi = 0; mi < 4; ++mi)
#pragma unroll
      for (int r = 0; r < 4; ++r) {
        int gm = m0 + wave * 64 + mi * 16 + quad * 4 + r;
        out[(size_t)gm * DMODEL + gn] = acc[mi][ni][r] + bv_;
      }
  }
}

extern "C" void kernel_launch(void* const* d_in, const int* in_sizes, int n_in,
                              void* d_out, int out_size, void* d_ws, size_t ws_size,
                              hipStream_t stream) {
  const float* x  = (const float*)d_in[0];
  const int*   mask = (const int*)d_in[1];
  const float* Wq = (const float*)d_in[2]; const float* bq = (const float*)d_in[3];
  const float* Wk = (const float*)d_in[4]; const float* bk = (const float*)d_in[5];
  const float* Wv = (const float*)d_in[6]; const float* bv = (const float*)d_in[7];
  const float* Wo = (const float*)d_in[8]; const float* bo = (const float*)d_in[9];
  float* out = (float*)d_out;
  char* outc = (char*)d_out;
  char* xc   = (char*)d_in[0];
  const size_t mat = (size_t)NBATCH * SEQ * DMODEL;  // 8,388,608 elems
  const size_t half = mat * 2;                        // 16.78 MB bytes

  // Buffer plan (d_ws unusable; d_in[0] restored by harness each launch):
  //   Qall (bf16, 16.78 MB)          -> d_out.lo
  //   KV0  (batches 0,1; 16.78 MB)   -> d_out.hi
  //   KV1  (batches 2,3; 16.78 MB)   -> x.lo   (kvproj1 reads x.hi only)
  //   O (bf16, 16.78 MB)             -> x.hi   (attn reads KV1=x.lo, writes x.hi)
  //   final fp32 out (33.55 MB)      -> d_out  (overwrites Qall+KV0, reads only O)
  bf16* Qall = (bf16*)d_out;
  bf16* KV0  = (bf16*)(outc + half);
  bf16* KV1  = (bf16*)xc;
  bf16* O    = (bf16*)(xc + half);

  qproj_kernel<<<dim3(32, 16), 256, 0, stream>>>(x, Wq, bq, Qall);
  kvproj_kernel<<<dim3(16, 32), 256, 0, stream>>>(x, Wk, bk, Wv, bv, KV0);
  kvproj_kernel<<<dim3(16, 32), 256, 0, stream>>>(x + (size_t)2 * SEQ * DMODEL, Wk, bk, Wv, bv, KV1);
  attn4_kernel<<<dim3(2048), 128, 0, stream>>>(Qall, KV0, KV1, mask, O);
  outproj_kernel<<<dim3(32, 16), 256, 0, stream>>>(O, Wo, bo, out);
}

// Round 4
// 457.428 us; speedup vs baseline: 1.9415x; 1.2883x over previous
//
#include <hip/hip_runtime.h>
#include <stdint.h>

typedef __bf16 bf16;
typedef __bf16 bf16x8 __attribute__((ext_vector_type(8)));
typedef float f32x4 __attribute__((ext_vector_type(4)));

#define SEQ 2048
#define NHEAD 16
#define HDIM 64
#define DMODEL 1024
#define NBATCH 4
// 0.125 * log2(e): softmax runs in exp2 domain (saves the 1.4427 mul per exp)
#define ATT_SCALE 0.18033688011112042f
#define SEQHD (SEQ * HDIM)          // 131072
#define BHSTRIDE (2 * SEQHD)        // per-(b,h): K tile then V^T tile

// LDS slot invariant: L[row*64 + ((blk ^ (row&7))*8) + off] = SRC[row][blk*8+off]

__device__ __forceinline__ void gload_lds16(const bf16* g, bf16* l) {
  __builtin_amdgcn_global_load_lds(
      (const __attribute__((address_space(1))) uint32_t*)g,
      (__attribute__((address_space(3))) uint32_t*)l, 16, 0, 0);
}

__device__ __forceinline__ void stage64_block(const float* __restrict__ src, bf16* lds, int t) {
#pragma unroll
  for (int i = 0; i < 2; ++i) {
    int row = i * 32 + (t >> 3);
    int gb = t & 7;
    const float* p = src + (size_t)row * DMODEL + gb * 8;
    float4 f0 = *(const float4*)p;
    float4 f1 = *(const float4*)(p + 4);
    bf16x8 v;
    v[0] = (bf16)f0.x; v[1] = (bf16)f0.y; v[2] = (bf16)f0.z; v[3] = (bf16)f0.w;
    v[4] = (bf16)f1.x; v[5] = (bf16)f1.y; v[6] = (bf16)f1.z; v[7] = (bf16)f1.w;
    *(bf16x8*)(lds + row * 64 + ((gb ^ (row & 7)) * 8)) = v;
  }
}

__device__ __forceinline__ void stage64_wave(const float* __restrict__ src, bf16* lds, int lane) {
#pragma unroll
  for (int i = 0; i < 8; ++i) {
    int row = i * 8 + (lane >> 3);
    int gb = lane & 7;
    const float* p = src + (size_t)row * DMODEL + gb * 8;
    float4 f0 = *(const float4*)p;
    float4 f1 = *(const float4*)(p + 4);
    bf16x8 v;
    v[0] = (bf16)f0.x; v[1] = (bf16)f0.y; v[2] = (bf16)f0.z; v[3] = (bf16)f0.w;
    v[4] = (bf16)f1.x; v[5] = (bf16)f1.y; v[6] = (bf16)f1.z; v[7] = (bf16)f1.w;
    *(bf16x8*)(lds + row * 64 + ((gb ^ (row & 7)) * 8)) = v;
  }
}

__device__ __forceinline__ void stage64_wave_bf16(const bf16* __restrict__ src, bf16* lds, int lane) {
#pragma unroll
  for (int i = 0; i < 8; ++i) {
    int row = i * 8 + (lane >> 3);
    int gb = lane & 7;
    bf16x8 v = *(const bf16x8*)(src + (size_t)row * DMODEL + gb * 8);
    *(bf16x8*)(lds + row * 64 + ((gb ^ (row & 7)) * 8)) = v;
  }
}

// ---- Q projection for ALL batches: Qall[bh][s][hd] = (x*Wq_h^T + bq)*SCALE ----
__global__ __launch_bounds__(256) void qproj_kernel(
    const float* __restrict__ x, const float* __restrict__ Wq,
    const float* __restrict__ bq, bf16* __restrict__ Qall) {
  __shared__ __align__(16) bf16 lW[64 * 64];
  __shared__ __align__(16) bf16 lXw[4][64 * 64];
  const int t = threadIdx.x, wave = t >> 6, lane = t & 63;
  const int quad = lane >> 4, c = lane & 15;
  const int m0 = blockIdx.x * 256;           // token rows (0..8191)
  const int h = blockIdx.y;
  const float* W = Wq + (size_t)(h * HDIM) * DMODEL;
  bf16* pw = lXw[wave];
  f32x4 acc[4][4] = {};
  for (int k0 = 0; k0 < DMODEL; k0 += 64) {
    __syncthreads();
    stage64_block(W + k0, lW, t);
    stage64_wave(x + (size_t)(m0 + wave * 64) * DMODEL + k0, pw, lane);
    __syncthreads();
#pragma unroll
    for (int kk = 0; kk < 2; ++kk) {
      bf16x8 af[4], bfr[4];
#pragma unroll
      for (int mi = 0; mi < 4; ++mi) {
        int row = mi * 16 + c;
        af[mi] = *(const bf16x8*)(pw + row * 64 + (((kk * 4 + quad) ^ (row & 7)) * 8));
      }
#pragma unroll
      for (int ni = 0; ni < 4; ++ni) {
        int row = ni * 16 + c;
        bfr[ni] = *(const bf16x8*)(lW + row * 64 + (((kk * 4 + quad) ^ (row & 7)) * 8));
      }
#pragma unroll
      for (int mi = 0; mi < 4; ++mi)
#pragma unroll
        for (int ni = 0; ni < 4; ++ni)
          acc[mi][ni] = __builtin_amdgcn_mfma_f32_16x16x32_bf16(af[mi], bfr[ni], acc[mi][ni], 0, 0, 0);
    }
  }
#pragma unroll
  for (int ni = 0; ni < 4; ++ni) {
    int hd = ni * 16 + c;
    float bqv = bq[h * HDIM + hd];
#pragma unroll
    for (int mi = 0; mi < 4; ++mi)
#pragma unroll
      for (int r = 0; r < 4; ++r) {
        int tok = m0 + wave * 64 + mi * 16 + quad * 4 + r;
        int b = tok >> 11, s = tok & 2047;
        Qall[((size_t)(b * NHEAD + h) * SEQ + s) * HDIM + hd] = (bf16)((acc[mi][ni][r] + bqv) * ATT_SCALE);
      }
  }
}

// ---- K/V projection for one 2-batch chunk (4096 rows) ----
__global__ __launch_bounds__(256) void kvproj_kernel(
    const float* __restrict__ xc,
    const float* __restrict__ Wk, const float* __restrict__ bk,
    const float* __restrict__ Wv, const float* __restrict__ bv,
    bf16* __restrict__ scr) {
  __shared__ __align__(16) bf16 lW[64 * 64];
  __shared__ __align__(16) bf16 lXw[4][64 * 64];
  const int t = threadIdx.x, wave = t >> 6, lane = t & 63;
  const int quad = lane >> 4, c = lane & 15;
  const int m0 = blockIdx.x * 256;
  const int nt = blockIdx.y;
  const int h = nt >> 1, isV = nt & 1;
  const float* W = (isV ? Wv : Wk) + (size_t)(h * HDIM) * DMODEL;
  const float* bias = (isV ? bv : bk) + h * HDIM;
  bf16* pw = lXw[wave];
  f32x4 acc[4][4] = {};
  for (int k0 = 0; k0 < DMODEL; k0 += 64) {
    __syncthreads();
    stage64_block(W + k0, lW, t);
    stage64_wave(xc + (size_t)(m0 + wave * 64) * DMODEL + k0, pw, lane);
    __syncthreads();
#pragma unroll
    for (int kk = 0; kk < 2; ++kk) {
      bf16x8 af[4], bfr[4];
#pragma unroll
      for (int mi = 0; mi < 4; ++mi) {
        int row = mi * 16 + c;
        af[mi] = *(const bf16x8*)(pw + row * 64 + (((kk * 4 + quad) ^ (row & 7)) * 8));
      }
#pragma unroll
      for (int ni = 0; ni < 4; ++ni) {
        int row = ni * 16 + c;
        bfr[ni] = *(const bf16x8*)(lW + row * 64 + (((kk * 4 + quad) ^ (row & 7)) * 8));
      }
#pragma unroll
      for (int mi = 0; mi < 4; ++mi)
#pragma unroll
        for (int ni = 0; ni < 4; ++ni)
          acc[mi][ni] = __builtin_amdgcn_mfma_f32_16x16x32_bf16(af[mi], bfr[ni], acc[mi][ni], 0, 0, 0);
    }
  }
#pragma unroll
  for (int ni = 0; ni < 4; ++ni) {
    int hd = ni * 16 + c;
    float bv_ = bias[hd];
#pragma unroll
    for (int mi = 0; mi < 4; ++mi)
#pragma unroll
      for (int r = 0; r < 4; ++r) {
        int key = m0 + wave * 64 + mi * 16 + quad * 4 + r;
        int b_loc = key >> 11, s = key & 2047;
        bf16* base = scr + (size_t)(b_loc * NHEAD + h) * BHSTRIDE;
        float val = acc[mi][ni][r] + bv_;
        if (isV) base[SEQHD + (size_t)hd * SEQ + s] = (bf16)val;
        else     base[(size_t)s * HDIM + hd] = (bf16)val;
      }
  }
}

// ---- attention: ALL 4 batches, one launch; 2048 blocks x 256 threads.
//      4 waves x 16 q-rows each (same 64 q-rows/block as before).
//      Occupancy model (R1/R2/R3 reconciled vs m69 steps): waves/SIMD is set by
//      TOTAL regs (VGPR+AGPR). 32-row waves needed ~148 (84 VGPR + 64 AGPR acc)
//      -> 2 waves/SIMD. 16-row waves need ~90-100 -> 4 waves/SIMD under
//      __launch_bounds__(256,4) (128-reg cap) with no spill headroom risk.
//      K/V tiles cooperatively staged in LDS via global_load_lds (16B),
//      single-buffered each, pipelined one phase ahead (stage K after barrier A,
//      V after barrier B). Global source address pre-swizzled; LDS dest linear. ----
__global__ __launch_bounds__(256, 4) void attn4_kernel(
    const bf16* __restrict__ Qall, const bf16* __restrict__ KV0,
    const bf16* __restrict__ KV1, const int* __restrict__ mask,
    bf16* __restrict__ O) {
  __shared__ __align__(16) bf16 lK[64 * 64];
  __shared__ __align__(16) bf16 lV[64 * 64];
  __shared__ __align__(16) bf16 lPw[4][16 * 64];
  const int t = threadIdx.x, wave = t >> 6, lane = t & 63;
  const int quad = lane >> 4, c = lane & 15;
  // swizzle: i = slot*8 + xcd  (HW round-robins linear id across 8 XCDs)
  const int i = blockIdx.x;                  // 0..2047
  const int xcd = i & 7, slot = i >> 3;      // slot 0..255
  const int bh = xcd * 8 + (slot >> 5);      // 0..63, 8 bh per XCD
  const int qt = slot & 31;                  // 32 tiles of 64 q rows
  const int b = bh >> 4, h = bh & 15;
  const int q0 = qt * 64 + wave * 16;        // 16 q-rows per wave
  const bf16* Qh = Qall + (size_t)bh * SEQHD;
  const bf16* Kb = (b < 2 ? KV0 : KV1) + (size_t)((b & 1) * NHEAD + h) * BHSTRIDE;
  const bf16* Vtb = Kb + SEQHD;
  const int* maskG = mask + b * SEQ;
  bf16* pw = lPw[wave];

  // staging: thread t covers row (i2*32 + t/8), source col-block ((t&7)^(row&7));
  // row&7 == (t>>3)&7 for both i2 (i2*32 % 8 == 0)
  const int srow = t >> 3;                              // 0..31
  const int sswz = (t & 7) ^ (srow & 7);
  const bf16* kSrc = Kb + (size_t)srow * HDIM + sswz * 8;   // + kt*HDIM + i2*32*HDIM
  const bf16* vSrc = Vtb + (size_t)srow * SEQ + sswz * 8;   // + kt       + i2*32*SEQ
  bf16* kDst = lK + wave * 512;                             // + i2*2048 (HW adds lane*16B)
  bf16* vDst = lV + wave * 512;

  // Q fragments (scale+log2e pre-folded at qproj): rows q0 + c
  bf16x8 qf[2];
#pragma unroll
  for (int kk = 0; kk < 2; ++kk)
    qf[kk] = *(const bf16x8*)(Qh + (size_t)(q0 + c) * HDIM + kk * 32 + quad * 8);

  f32x4 oacc[4] = {};
  float mrun[4], lrun[4];
#pragma unroll
  for (int r = 0; r < 4; ++r) { mrun[r] = -1e30f; lrun[r] = 0.0f; }

  // prologue: stage tile 0 (K and V)
#pragma unroll
  for (int i2 = 0; i2 < 2; ++i2) {
    gload_lds16(kSrc + i2 * 32 * HDIM, kDst + i2 * 2048);
    gload_lds16(vSrc + (size_t)i2 * 32 * SEQ, vDst + i2 * 2048);
  }
  __syncthreads();

  for (int kt = 0; kt < SEQ; kt += 64) {
    // mask loads issued early; consumed after barrier A (latency hidden)
    float sm[4];
#pragma unroll
    for (int ni = 0; ni < 4; ++ni) sm[ni] = maskG[kt + ni * 16 + c] ? -3e38f : 0.0f;

    // QK^T from lK
    f32x4 sacc[4] = {};
#pragma unroll
    for (int kk = 0; kk < 2; ++kk) {
      bf16x8 kf[4];
#pragma unroll
      for (int ni = 0; ni < 4; ++ni) {
        int row = ni * 16 + c;
        kf[ni] = *(const bf16x8*)(lK + row * 64 + (((kk * 4 + quad) ^ (row & 7)) * 8));
      }
#pragma unroll
      for (int ni = 0; ni < 4; ++ni)
        sacc[ni] = __builtin_amdgcn_mfma_f32_16x16x32_bf16(qf[kk], kf[ni], sacc[ni], 0, 0, 0);
    }

    __syncthreads();  // A: all waves done reading lK; V[kt] staging drained
    if (kt + 64 < SEQ) {
      const bf16* ks = kSrc + (size_t)(kt + 64) * HDIM;
#pragma unroll
      for (int i2 = 0; i2 < 2; ++i2) gload_lds16(ks + i2 * 32 * HDIM, kDst + i2 * 2048);
    }

    // online softmax (exp2 domain), 4 rows/thread (quad*4 + r)
#pragma unroll
    for (int r = 0; r < 4; ++r) {
      float sv[4];
#pragma unroll
      for (int ni = 0; ni < 4; ++ni) sv[ni] = sacc[ni][r] + sm[ni];
      float mx = fmaxf(fmaxf(sv[0], sv[1]), fmaxf(sv[2], sv[3]));
      mx = fmaxf(mx, __shfl_xor(mx, 1));
      mx = fmaxf(mx, __shfl_xor(mx, 2));
      mx = fmaxf(mx, __shfl_xor(mx, 4));
      mx = fmaxf(mx, __shfl_xor(mx, 8));
      float mo = mrun[r];
      float mn = fmaxf(mo, mx);
      float al = __builtin_amdgcn_exp2f(mo - mn);
      mrun[r] = mn;
      float rs = 0.0f, p[4];
#pragma unroll
      for (int ni = 0; ni < 4; ++ni) { p[ni] = __builtin_amdgcn_exp2f(sv[ni] - mn); rs += p[ni]; }
      rs += __shfl_xor(rs, 1);
      rs += __shfl_xor(rs, 2);
      rs += __shfl_xor(rs, 4);
      rs += __shfl_xor(rs, 8);
      lrun[r] = lrun[r] * al + rs;
      int row = quad * 4 + r;
#pragma unroll
      for (int ni = 0; ni < 4; ++ni) {
        oacc[ni][r] *= al;
        int colT = ni * 16 + c;
        pw[row * 64 + (((colT >> 3) ^ (row & 7)) * 8) + (colT & 7)] = (bf16)p[ni];
      }
    }

    // PV from lPw (own wave) and lV
#pragma unroll
    for (int kk = 0; kk < 2; ++kk) {
      bf16x8 pf, vfr[4];
      pf = *(const bf16x8*)(pw + c * 64 + (((kk * 4 + quad) ^ (c & 7)) * 8));
#pragma unroll
      for (int ni = 0; ni < 4; ++ni) {
        int row = ni * 16 + c;
        vfr[ni] = *(const bf16x8*)(lV + row * 64 + (((kk * 4 + quad) ^ (row & 7)) * 8));
      }
#pragma unroll
      for (int ni = 0; ni < 4; ++ni)
        oacc[ni] = __builtin_amdgcn_mfma_f32_16x16x32_bf16(pf, vfr[ni], oacc[ni], 0, 0, 0);
    }

    __syncthreads();  // B: all waves done reading lV; K[kt+64] staging drained
    if (kt + 64 < SEQ) {
      const bf16* vs = vSrc + (kt + 64);
#pragma unroll
      for (int i2 = 0; i2 < 2; ++i2) gload_lds16(vs + (size_t)i2 * 32 * SEQ, vDst + i2 * 2048);
    }
  }

  // epilogue: O[tok][h*64+hd] bf16, plain stores
#pragma unroll
  for (int r = 0; r < 4; ++r) {
    float lv = lrun[r];
    float inv = lv > 0.0f ? 1.0f / lv : 0.0f;
    size_t tok = (size_t)b * SEQ + q0 + quad * 4 + r;
#pragma unroll
    for (int ni = 0; ni < 4; ++ni)
      O[tok * DMODEL + h * HDIM + ni * 16 + c] = (bf16)(oacc[ni][r] * inv);
  }
}

// ---- output projection: out = O*Wo^T + bo (fp32), deterministic ----
__global__ __launch_bounds__(256) void outproj_kernel(
    const bf16* __restrict__ O, const float* __restrict__ Wo,
    const float* __restrict__ bo, float* __restrict__ out) {
  __shared__ __align__(16) bf16 lW[64 * 64];
  __shared__ __align__(16) bf16 lXw[4][64 * 64];
  const int t = threadIdx.x, wave = t >> 6, lane = t & 63;
  const int quad = lane >> 4, c = lane & 15;
  const int m0 = blockIdx.x * 256;           // token rows
  const int n0 = blockIdx.y * 64;            // output cols
  bf16* pw = lXw[wave];
  f32x4 acc[4][4] = {};
  for (int k0 = 0; k0 < DMODEL; k0 += 64) {
    __syncthreads();
    stage64_block(Wo + (size_t)n0 * DMODEL + k0, lW, t);
    stage64_wave_bf16(O + (size_t)(m0 + wave * 64) * DMODEL + k0, pw, lane);
    __syncthreads();
#pragma unroll
    for (int kk = 0; kk < 2; ++kk) {
      bf16x8 af[4], bfr[4];
#pragma unroll
      for (int mi = 0; mi < 4; ++mi) {
        int row = mi * 16 + c;
        af[mi] = *(const bf16x8*)(pw + row * 64 + (((kk * 4 + quad) ^ (row & 7)) * 8));
      }
#pragma unroll
      for (int ni = 0; ni < 4; ++ni) {
        int row = ni * 16 + c;
        bfr[ni] = *(const bf16x8*)(lW + row * 64 + (((kk * 4 + quad) ^ (row & 7)) * 8));
      }
#pragma unroll
      for (int mi = 0; mi < 4; ++mi)
#pragma unroll
        for (int ni = 0; ni < 4; ++ni)
          acc[mi][ni] = __builtin_amdgcn_mfma_f32_16x16x32_bf16(af[mi], bfr[ni], acc[mi][ni], 0, 0, 0);
    }
  }
#pragma unroll
  for (int ni = 0; ni < 4; ++ni) {
    int gn = n0 + ni * 16 + c;
    float bv_ = bo[gn];
#pragma unroll
    for (int mi = 0; mi < 4; ++mi)
#pragma unroll
      for (int r = 0; r < 4; ++r) {
        int gm = m0 + wave * 64 + mi * 16 + quad * 4 + r;
        out[(size_t)gm * DMODEL + gn] = acc[mi][ni][r] + bv_;
      }
  }
}

extern "C" void kernel_launch(void* const* d_in, const int* in_sizes, int n_in,
                              void* d_out, int out_size, void* d_ws, size_t ws_size,
                              hipStream_t stream) {
  const float* x  = (const float*)d_in[0];
  const int*   mask = (const int*)d_in[1];
  const float* Wq = (const float*)d_in[2]; const float* bq = (const float*)d_in[3];
  const float* Wk = (const float*)d_in[4]; const float* bk = (const float*)d_in[5];
  const float* Wv = (const float*)d_in[6]; const float* bv = (const float*)d_in[7];
  const float* Wo = (const float*)d_in[8]; const float* bo = (const float*)d_in[9];
  float* out = (float*)d_out;
  char* outc = (char*)d_out;
  char* xc   = (char*)d_in[0];
  const size_t mat = (size_t)NBATCH * SEQ * DMODEL;  // 8,388,608 elems
  const size_t half = mat * 2;                        // 16.78 MB bytes

  // Buffer plan (d_ws unusable; d_in[0] restored by harness each launch):
  //   Qall (bf16, 16.78 MB)          -> d_out.lo
  //   KV0  (batches 0,1; 16.78 MB)   -> d_out.hi
  //   KV1  (batches 2,3; 16.78 MB)   -> x.lo   (kvproj1 reads x.hi only)
  //   O (bf16, 16.78 MB)             -> x.hi   (attn reads KV1=x.lo, writes x.hi)
  //   final fp32 out (33.55 MB)      -> d_out  (overwrites Qall+KV0, reads only O)
  bf16* Qall = (bf16*)d_out;
  bf16* KV0  = (bf16*)(outc + half);
  bf16* KV1  = (bf16*)xc;
  bf16* O    = (bf16*)(xc + half);

  qproj_kernel<<<dim3(32, 16), 256, 0, stream>>>(x, Wq, bq, Qall);
  kvproj_kernel<<<dim3(16, 32), 256, 0, stream>>>(x, Wk, bk, Wv, bv, KV0);
  kvproj_kernel<<<dim3(16, 32), 256, 0, stream>>>(x + (size_t)2 * SEQ * DMODEL, Wk, bk, Wv, bv, KV1);
  attn4_kernel<<<dim3(2048), 256, 0, stream>>>(Qall, KV0, KV1, mask, O);
  outproj_kernel<<<dim3(32, 16), 256, 0, stream>>>(O, Wo, bo, out);
}

// Round 5
// 387.892 us; speedup vs baseline: 2.2896x; 1.1793x over previous
//
#include <hip/hip_runtime.h>
#include <stdint.h>

typedef __bf16 bf16;
typedef __bf16 bf16x8 __attribute__((ext_vector_type(8)));
typedef float f32x4 __attribute__((ext_vector_type(4)));

#define SEQ 2048
#define NHEAD 16
#define HDIM 64
#define DMODEL 1024
#define NBATCH 4
// 0.125 * log2(e): softmax runs in exp2 domain (saves the 1.4427 mul per exp)
#define ATT_SCALE 0.18033688011112042f
#define SEQHD (SEQ * HDIM)          // 131072
#define BHSTRIDE (2 * SEQHD)        // per-(b,h): K tile then V^T tile

// LDS slot invariant: L[row*64 + ((blk ^ (row&7))*8) + off] = SRC[row][blk*8+off]

__device__ __forceinline__ void gload_lds16(const bf16* g, bf16* l) {
  __builtin_amdgcn_global_load_lds(
      (const __attribute__((address_space(1))) uint32_t*)g,
      (__attribute__((address_space(3))) uint32_t*)l, 16, 0, 0);
}

__device__ __forceinline__ void stage64_block(const float* __restrict__ src, bf16* lds, int t) {
#pragma unroll
  for (int i = 0; i < 2; ++i) {
    int row = i * 32 + (t >> 3);
    int gb = t & 7;
    const float* p = src + (size_t)row * DMODEL + gb * 8;
    float4 f0 = *(const float4*)p;
    float4 f1 = *(const float4*)(p + 4);
    bf16x8 v;
    v[0] = (bf16)f0.x; v[1] = (bf16)f0.y; v[2] = (bf16)f0.z; v[3] = (bf16)f0.w;
    v[4] = (bf16)f1.x; v[5] = (bf16)f1.y; v[6] = (bf16)f1.z; v[7] = (bf16)f1.w;
    *(bf16x8*)(lds + row * 64 + ((gb ^ (row & 7)) * 8)) = v;
  }
}

__device__ __forceinline__ void stage64_wave(const float* __restrict__ src, bf16* lds, int lane) {
#pragma unroll
  for (int i = 0; i < 8; ++i) {
    int row = i * 8 + (lane >> 3);
    int gb = lane & 7;
    const float* p = src + (size_t)row * DMODEL + gb * 8;
    float4 f0 = *(const float4*)p;
    float4 f1 = *(const float4*)(p + 4);
    bf16x8 v;
    v[0] = (bf16)f0.x; v[1] = (bf16)f0.y; v[2] = (bf16)f0.z; v[3] = (bf16)f0.w;
    v[4] = (bf16)f1.x; v[5] = (bf16)f1.y; v[6] = (bf16)f1.z; v[7] = (bf16)f1.w;
    *(bf16x8*)(lds + row * 64 + ((gb ^ (row & 7)) * 8)) = v;
  }
}

__device__ __forceinline__ void stage64_wave_bf16(const bf16* __restrict__ src, bf16* lds, int lane) {
#pragma unroll
  for (int i = 0; i < 8; ++i) {
    int row = i * 8 + (lane >> 3);
    int gb = lane & 7;
    bf16x8 v = *(const bf16x8*)(src + (size_t)row * DMODEL + gb * 8);
    *(bf16x8*)(lds + row * 64 + ((gb ^ (row & 7)) * 8)) = v;
  }
}

// ---- mask -> compacted-position scan, IN PLACE, idempotent.
//      For each (b,s): unmasked -> 0x40000000 | pos   (pos = # unmasked before s)
//                      masked   -> 0x80000000 | pos   (negative)
//      Idempotent flag decode so rocprof replays / repeated launches are safe:
//      x<0 -> masked; x&0x40000000 -> unmasked; else original 0/1 (0=unmasked). ----
__global__ __launch_bounds__(256) void scan_kernel(int* __restrict__ posv) {
  __shared__ int sums[256];
  const int b = blockIdx.x, t = threadIdx.x;
  int* m = posv + b * SEQ;
  int f[8], cnt = 0;
#pragma unroll
  for (int j = 0; j < 8; ++j) {
    int x = m[t * 8 + j];
    int unm = (x < 0) ? 0 : ((x & 0x40000000) ? 1 : (x == 0 ? 1 : 0));
    f[j] = unm; cnt += unm;
  }
  sums[t] = cnt;
  __syncthreads();
  if (t == 0) {
    int acc = 0;
#pragma unroll 8
    for (int i = 0; i < 256; ++i) { int s = sums[i]; sums[i] = acc; acc += s; }
  }
  __syncthreads();
  int p = sums[t];
#pragma unroll
  for (int j = 0; j < 8; ++j) {
    m[t * 8 + j] = (int)((f[j] ? 0x40000000u : 0x80000000u) | (unsigned)p);
    p += f[j];
  }
}

// ---- Q projection for ALL batches: Qall[bh][s][hd] = (x*Wq_h^T + bq)*SCALE ----
__global__ __launch_bounds__(256) void qproj_kernel(
    const float* __restrict__ x, const float* __restrict__ Wq,
    const float* __restrict__ bq, bf16* __restrict__ Qall) {
  __shared__ __align__(16) bf16 lW[64 * 64];
  __shared__ __align__(16) bf16 lXw[4][64 * 64];
  const int t = threadIdx.x, wave = t >> 6, lane = t & 63;
  const int quad = lane >> 4, c = lane & 15;
  const int m0 = blockIdx.x * 256;           // token rows (0..8191)
  const int h = blockIdx.y;
  const float* W = Wq + (size_t)(h * HDIM) * DMODEL;
  bf16* pw = lXw[wave];
  f32x4 acc[4][4] = {};
  for (int k0 = 0; k0 < DMODEL; k0 += 64) {
    __syncthreads();
    stage64_block(W + k0, lW, t);
    stage64_wave(x + (size_t)(m0 + wave * 64) * DMODEL + k0, pw, lane);
    __syncthreads();
#pragma unroll
    for (int kk = 0; kk < 2; ++kk) {
      bf16x8 af[4], bfr[4];
#pragma unroll
      for (int mi = 0; mi < 4; ++mi) {
        int row = mi * 16 + c;
        af[mi] = *(const bf16x8*)(pw + row * 64 + (((kk * 4 + quad) ^ (row & 7)) * 8));
      }
#pragma unroll
      for (int ni = 0; ni < 4; ++ni) {
        int row = ni * 16 + c;
        bfr[ni] = *(const bf16x8*)(lW + row * 64 + (((kk * 4 + quad) ^ (row & 7)) * 8));
      }
#pragma unroll
      for (int mi = 0; mi < 4; ++mi)
#pragma unroll
        for (int ni = 0; ni < 4; ++ni)
          acc[mi][ni] = __builtin_amdgcn_mfma_f32_16x16x32_bf16(af[mi], bfr[ni], acc[mi][ni], 0, 0, 0);
    }
  }
#pragma unroll
  for (int ni = 0; ni < 4; ++ni) {
    int hd = ni * 16 + c;
    float bqv = bq[h * HDIM + hd];
#pragma unroll
    for (int mi = 0; mi < 4; ++mi)
#pragma unroll
      for (int r = 0; r < 4; ++r) {
        int tok = m0 + wave * 64 + mi * 16 + quad * 4 + r;
        int b = tok >> 11, s = tok & 2047;
        Qall[((size_t)(b * NHEAD + h) * SEQ + s) * HDIM + hd] = (bf16)((acc[mi][ni][r] + bqv) * ATT_SCALE);
      }
  }
}

// ---- K/V projection for one 2-batch chunk (4096 rows), COMPACTED scatter.
//      posv already offset to this chunk. Unmasked key s -> slot pos;
//      masked key s -> pad slot nk + (s - pos) with exact-zero K/V
//      (bijection: all 2048 slots written; pad gives score 0, masked at tail). ----
__global__ __launch_bounds__(256) void kvproj_kernel(
    const float* __restrict__ xc,
    const float* __restrict__ Wk, const float* __restrict__ bk,
    const float* __restrict__ Wv, const float* __restrict__ bv,
    const int* __restrict__ posv,
    bf16* __restrict__ scr) {
  __shared__ __align__(16) bf16 lW[64 * 64];
  __shared__ __align__(16) bf16 lXw[4][64 * 64];
  const int t = threadIdx.x, wave = t >> 6, lane = t & 63;
  const int quad = lane >> 4, c = lane & 15;
  const int m0 = blockIdx.x * 256;
  const int nt = blockIdx.y;
  const int h = nt >> 1, isV = nt & 1;
  const int b_loc = m0 >> 11;                // block spans one batch
  const float* W = (isV ? Wv : Wk) + (size_t)(h * HDIM) * DMODEL;
  const float* bias = (isV ? bv : bk) + h * HDIM;
  bf16* pw = lXw[wave];
  f32x4 acc[4][4] = {};
  for (int k0 = 0; k0 < DMODEL; k0 += 64) {
    __syncthreads();
    stage64_block(W + k0, lW, t);
    stage64_wave(xc + (size_t)(m0 + wave * 64) * DMODEL + k0, pw, lane);
    __syncthreads();
#pragma unroll
    for (int kk = 0; kk < 2; ++kk) {
      bf16x8 af[4], bfr[4];
#pragma unroll
      for (int mi = 0; mi < 4; ++mi) {
        int row = mi * 16 + c;
        af[mi] = *(const bf16x8*)(pw + row * 64 + (((kk * 4 + quad) ^ (row & 7)) * 8));
      }
#pragma unroll
      for (int ni = 0; ni < 4; ++ni) {
        int row = ni * 16 + c;
        bfr[ni] = *(const bf16x8*)(lW + row * 64 + (((kk * 4 + quad) ^ (row & 7)) * 8));
      }
#pragma unroll
      for (int mi = 0; mi < 4; ++mi)
#pragma unroll
        for (int ni = 0; ni < 4; ++ni)
          acc[mi][ni] = __builtin_amdgcn_mfma_f32_16x16x32_bf16(af[mi], bfr[ni], acc[mi][ni], 0, 0, 0);
    }
  }
  // nk for this batch (block-uniform)
  int v2 = posv[b_loc * SEQ + SEQ - 1];
  int nk = (v2 & 0x3FFFFFFF) + (v2 >= 0 ? 1 : 0);
  bf16* base = scr + (size_t)(b_loc * NHEAD + h) * BHSTRIDE;
#pragma unroll
  for (int ni = 0; ni < 4; ++ni) {
    int hd = ni * 16 + c;
    float bv_ = bias[hd];
#pragma unroll
    for (int mi = 0; mi < 4; ++mi)
#pragma unroll
      for (int r = 0; r < 4; ++r) {
        int key = m0 + wave * 64 + mi * 16 + quad * 4 + r;
        int s = key & 2047;
        int pv = posv[b_loc * SEQ + s];
        int pos = pv & 0x3FFFFFFF;
        int dst = (pv >= 0) ? pos : (nk + (s - pos));
        float val = (pv >= 0) ? (acc[mi][ni][r] + bv_) : 0.0f;
        if (isV) base[SEQHD + (size_t)hd * SEQ + dst] = (bf16)val;
        else     base[(size_t)dst * HDIM + hd] = (bf16)val;
      }
  }
}

// ---- attention over COMPACTED keys: ~nk/2048 of the work, no mask loads.
//      2048 blocks x 256 threads, 4 waves x 16 q-rows. XCD-aware swizzle.
//      K/V tiles staged in LDS via global_load_lds, pipelined one phase ahead.
//      Tail tile masks by index (col >= nk -> -3e38); pad K is exact zero. ----
__global__ __launch_bounds__(256, 4) void attn4_kernel(
    const bf16* __restrict__ Qall, const bf16* __restrict__ KV0,
    const bf16* __restrict__ KV1, const int* __restrict__ posv,
    bf16* __restrict__ O) {
  __shared__ __align__(16) bf16 lK[64 * 64];
  __shared__ __align__(16) bf16 lV[64 * 64];
  __shared__ __align__(16) bf16 lPw[4][16 * 64];
  const int t = threadIdx.x, wave = t >> 6, lane = t & 63;
  const int quad = lane >> 4, c = lane & 15;
  const int i = blockIdx.x;                  // 0..2047
  const int xcd = i & 7, slot = i >> 3;      // slot 0..255
  const int bh = xcd * 8 + (slot >> 5);      // 0..63, 8 bh per XCD
  const int qt = slot & 31;                  // 32 tiles of 64 q rows
  const int b = bh >> 4, h = bh & 15;
  const int q0 = qt * 64 + wave * 16;        // 16 q-rows per wave
  const bf16* Qh = Qall + (size_t)bh * SEQHD;
  const bf16* Kb = (b < 2 ? KV0 : KV1) + (size_t)((b & 1) * NHEAD + h) * BHSTRIDE;
  const bf16* Vtb = Kb + SEQHD;
  bf16* pw = lPw[wave];

  // compacted key count for this batch
  int v2 = posv[b * SEQ + SEQ - 1];
  int nk = (v2 & 0x3FFFFFFF) + (v2 >= 0 ? 1 : 0);
  int NT = ((nk + 63) >> 6) << 6;            // tiles cover [0, NT)

  // staging addressing (pre-swizzled global source, linear LDS dest)
  const int srow = t >> 3;                              // 0..31
  const int sswz = (t & 7) ^ (srow & 7);
  const bf16* kSrc = Kb + (size_t)srow * HDIM + sswz * 8;
  const bf16* vSrc = Vtb + (size_t)srow * SEQ + sswz * 8;
  bf16* kDst = lK + wave * 512;
  bf16* vDst = lV + wave * 512;

  // Q fragments (scale+log2e pre-folded at qproj): rows q0 + c
  bf16x8 qf[2];
#pragma unroll
  for (int kk = 0; kk < 2; ++kk)
    qf[kk] = *(const bf16x8*)(Qh + (size_t)(q0 + c) * HDIM + kk * 32 + quad * 8);

  f32x4 oacc[4] = {};
  float mrun[4], lrun[4];
#pragma unroll
  for (int r = 0; r < 4; ++r) { mrun[r] = -1e30f; lrun[r] = 0.0f; }

  // prologue: stage tile 0 (K and V)
#pragma unroll
  for (int i2 = 0; i2 < 2; ++i2) {
    gload_lds16(kSrc + i2 * 32 * HDIM, kDst + i2 * 2048);
    gload_lds16(vSrc + (size_t)i2 * 32 * SEQ, vDst + i2 * 2048);
  }
  __syncthreads();

  for (int kt = 0; kt < NT; kt += 64) {
    // QK^T from lK
    f32x4 sacc[4] = {};
#pragma unroll
    for (int kk = 0; kk < 2; ++kk) {
      bf16x8 kf[4];
#pragma unroll
      for (int ni = 0; ni < 4; ++ni) {
        int row = ni * 16 + c;
        kf[ni] = *(const bf16x8*)(lK + row * 64 + (((kk * 4 + quad) ^ (row & 7)) * 8));
      }
#pragma unroll
      for (int ni = 0; ni < 4; ++ni)
        sacc[ni] = __builtin_amdgcn_mfma_f32_16x16x32_bf16(qf[kk], kf[ni], sacc[ni], 0, 0, 0);
    }

    __syncthreads();  // A: all waves done reading lK; V[kt] staging drained
    if (kt + 64 < NT) {
      const bf16* ks = kSrc + (size_t)(kt + 64) * HDIM;
#pragma unroll
      for (int i2 = 0; i2 < 2; ++i2) gload_lds16(ks + i2 * 32 * HDIM, kDst + i2 * 2048);
    }

    // tail-index masking (all tiles except the last are fully valid)
    float sm[4];
    if (kt + 64 <= nk) {
      sm[0] = sm[1] = sm[2] = sm[3] = 0.0f;
    } else {
#pragma unroll
      for (int ni = 0; ni < 4; ++ni) sm[ni] = (kt + ni * 16 + c < nk) ? 0.0f : -3e38f;
    }

    // online softmax (exp2 domain), 4 rows/thread (quad*4 + r)
#pragma unroll
    for (int r = 0; r < 4; ++r) {
      float sv[4];
#pragma unroll
      for (int ni = 0; ni < 4; ++ni) sv[ni] = sacc[ni][r] + sm[ni];
      float mx = fmaxf(fmaxf(sv[0], sv[1]), fmaxf(sv[2], sv[3]));
      mx = fmaxf(mx, __shfl_xor(mx, 1));
      mx = fmaxf(mx, __shfl_xor(mx, 2));
      mx = fmaxf(mx, __shfl_xor(mx, 4));
      mx = fmaxf(mx, __shfl_xor(mx, 8));
      float mo = mrun[r];
      float mn = fmaxf(mo, mx);
      float al = __builtin_amdgcn_exp2f(mo - mn);
      mrun[r] = mn;
      float rs = 0.0f, p[4];
#pragma unroll
      for (int ni = 0; ni < 4; ++ni) { p[ni] = __builtin_amdgcn_exp2f(sv[ni] - mn); rs += p[ni]; }
      rs += __shfl_xor(rs, 1);
      rs += __shfl_xor(rs, 2);
      rs += __shfl_xor(rs, 4);
      rs += __shfl_xor(rs, 8);
      lrun[r] = lrun[r] * al + rs;
      int row = quad * 4 + r;
#pragma unroll
      for (int ni = 0; ni < 4; ++ni) {
        oacc[ni][r] *= al;
        int colT = ni * 16 + c;
        pw[row * 64 + (((colT >> 3) ^ (row & 7)) * 8) + (colT & 7)] = (bf16)p[ni];
      }
    }

    // PV from lPw (own wave) and lV
#pragma unroll
    for (int kk = 0; kk < 2; ++kk) {
      bf16x8 pf, vfr[4];
      pf = *(const bf16x8*)(pw + c * 64 + (((kk * 4 + quad) ^ (c & 7)) * 8));
#pragma unroll
      for (int ni = 0; ni < 4; ++ni) {
        int row = ni * 16 + c;
        vfr[ni] = *(const bf16x8*)(lV + row * 64 + (((kk * 4 + quad) ^ (row & 7)) * 8));
      }
#pragma unroll
      for (int ni = 0; ni < 4; ++ni)
        oacc[ni] = __builtin_amdgcn_mfma_f32_16x16x32_bf16(pf, vfr[ni], oacc[ni], 0, 0, 0);
    }

    __syncthreads();  // B: all waves done reading lV; K[kt+64] staging drained
    if (kt + 64 < NT) {
      const bf16* vs = vSrc + (kt + 64);
#pragma unroll
      for (int i2 = 0; i2 < 2; ++i2) gload_lds16(vs + (size_t)i2 * 32 * SEQ, vDst + i2 * 2048);
    }
  }

  // epilogue: O[tok][h*64+hd] bf16, plain stores
#pragma unroll
  for (int r = 0; r < 4; ++r) {
    float lv = lrun[r];
    float inv = lv > 0.0f ? 1.0f / lv : 0.0f;
    size_t tok = (size_t)b * SEQ + q0 + quad * 4 + r;
#pragma unroll
    for (int ni = 0; ni < 4; ++ni)
      O[tok * DMODEL + h * HDIM + ni * 16 + c] = (bf16)(oacc[ni][r] * inv);
  }
}

// ---- output projection: out = O*Wo^T + bo (fp32), deterministic ----
__global__ __launch_bounds__(256) void outproj_kernel(
    const bf16* __restrict__ O, const float* __restrict__ Wo,
    const float* __restrict__ bo, float* __restrict__ out) {
  __shared__ __align__(16) bf16 lW[64 * 64];
  __shared__ __align__(16) bf16 lXw[4][64 * 64];
  const int t = threadIdx.x, wave = t >> 6, lane = t & 63;
  const int quad = lane >> 4, c = lane & 15;
  const int m0 = blockIdx.x * 256;           // token rows
  const int n0 = blockIdx.y * 64;            // output cols
  bf16* pw = lXw[wave];
  f32x4 acc[4][4] = {};
  for (int k0 = 0; k0 < DMODEL; k0 += 64) {
    __syncthreads();
    stage64_block(Wo + (size_t)n0 * DMODEL + k0, lW, t);
    stage64_wave_bf16(O + (size_t)(m0 + wave * 64) * DMODEL + k0, pw, lane);
    __syncthreads();
#pragma unroll
    for (int kk = 0; kk < 2; ++kk) {
      bf16x8 af[4], bfr[4];
#pragma unroll
      for (int mi = 0; mi < 4; ++mi) {
        int row = mi * 16 + c;
        af[mi] = *(const bf16x8*)(pw + row * 64 + (((kk * 4 + quad) ^ (row & 7)) * 8));
      }
#pragma unroll
      for (int ni = 0; ni < 4; ++ni) {
        int row = ni * 16 + c;
        bfr[ni] = *(const bf16x8*)(lW + row * 64 + (((kk * 4 + quad) ^ (row & 7)) * 8));
      }
#pragma unroll
      for (int mi = 0; mi < 4; ++mi)
#pragma unroll
        for (int ni = 0; ni < 4; ++ni)
          acc[mi][ni] = __builtin_amdgcn_mfma_f32_16x16x32_bf16(af[mi], bfr[ni], acc[mi][ni], 0, 0, 0);
    }
  }
#pragma unroll
  for (int ni = 0; ni < 4; ++ni) {
    int gn = n0 + ni * 16 + c;
    float bv_ = bo[gn];
#pragma unroll
    for (int mi = 0; mi < 4; ++mi)
#pragma unroll
      for (int r = 0; r < 4; ++r) {
        int gm = m0 + wave * 64 + mi * 16 + quad * 4 + r;
        out[(size_t)gm * DMODEL + gn] = acc[mi][ni][r] + bv_;
      }
  }
}

extern "C" void kernel_launch(void* const* d_in, const int* in_sizes, int n_in,
                              void* d_out, int out_size, void* d_ws, size_t ws_size,
                              hipStream_t stream) {
  const float* x  = (const float*)d_in[0];
  int*         posv = (int*)d_in[1];                 // mask -> compacted pos (in place)
  const float* Wq = (const float*)d_in[2]; const float* bq = (const float*)d_in[3];
  const float* Wk = (const float*)d_in[4]; const float* bk = (const float*)d_in[5];
  const float* Wv = (const float*)d_in[6]; const float* bv = (const float*)d_in[7];
  const float* Wo = (const float*)d_in[8]; const float* bo = (const float*)d_in[9];
  float* out = (float*)d_out;
  char* outc = (char*)d_out;
  char* xc   = (char*)d_in[0];
  const size_t mat = (size_t)NBATCH * SEQ * DMODEL;  // 8,388,608 elems
  const size_t half = mat * 2;                        // 16.78 MB bytes

  // Buffer plan (d_ws unusable; inputs restored by harness each launch):
  //   Qall (bf16, 16.78 MB)          -> d_out.lo
  //   KV0  (batches 0,1; 16.78 MB)   -> d_out.hi
  //   KV1  (batches 2,3; 16.78 MB)   -> x.lo   (kvproj1 reads x.hi only)
  //   O (bf16, 16.78 MB)             -> x.hi   (attn reads KV1=x.lo, writes x.hi)
  //   final fp32 out (33.55 MB)      -> d_out  (overwrites Qall+KV0, reads only O)
  //   posv                           -> mask buffer, in place (idempotent scan)
  bf16* Qall = (bf16*)d_out;
  bf16* KV0  = (bf16*)(outc + half);
  bf16* KV1  = (bf16*)xc;
  bf16* O    = (bf16*)(xc + half);

  scan_kernel<<<dim3(NBATCH), 256, 0, stream>>>(posv);
  qproj_kernel<<<dim3(32, 16), 256, 0, stream>>>(x, Wq, bq, Qall);
  kvproj_kernel<<<dim3(16, 32), 256, 0, stream>>>(x, Wk, bk, Wv, bv, posv, KV0);
  kvproj_kernel<<<dim3(16, 32), 256, 0, stream>>>(x + (size_t)2 * SEQ * DMODEL, Wk, bk, Wv, bv,
                                                  posv + 2 * SEQ, KV1);
  attn4_kernel<<<dim3(2048), 256, 0, stream>>>(Qall, KV0, KV1, posv, O);
  outproj_kernel<<<dim3(32, 16), 256, 0, stream>>>(O, Wo, bo, out);
}

// Round 6
// 361.129 us; speedup vs baseline: 2.4592x; 1.0741x over previous
//
#include <hip/hip_runtime.h>
#include <stdint.h>

typedef __bf16 bf16;
typedef __bf16 bf16x8 __attribute__((ext_vector_type(8)));
typedef float f32x4 __attribute__((ext_vector_type(4)));

#define SEQ 2048
#define NHEAD 16
#define HDIM 64
#define DMODEL 1024
#define NBATCH 4
// 0.125 * log2(e): softmax runs in exp2 domain
#define ATT_SCALE 0.18033688011112042f
#define SEQHD (SEQ * HDIM)          // 131072
#define BHSTRIDE (2 * SEQHD)        // per-(b,h): K tile then V^T tile

// LDS slot invariant: L[row*64 + ((blk ^ (row&7))*8) + off] = SRC[row][blk*8+off]
// All staging now via global_load_lds with PRE-SWIZZLED global source + linear
// LDS dest (m173 pattern); fragment reads use the same XOR and are unchanged.

__device__ __forceinline__ void gload_lds16(const bf16* g, bf16* l) {
  __builtin_amdgcn_global_load_lds(
      (const __attribute__((address_space(1))) uint32_t*)g,
      (__attribute__((address_space(3))) uint32_t*)l, 16, 0, 0);
}

// ---- fp32 -> bf16 conversion (memory-bound pre-pass), 16 elems/thread ----
__global__ __launch_bounds__(256) void cvt_kernel(const float* __restrict__ src,
                                                  bf16* __restrict__ dst) {
  size_t i = ((size_t)blockIdx.x * 256 + threadIdx.x) * 16;
#pragma unroll
  for (int j = 0; j < 2; ++j) {
    float4 f0 = *(const float4*)(src + i + j * 8);
    float4 f1 = *(const float4*)(src + i + j * 8 + 4);
    bf16x8 v;
    v[0] = (bf16)f0.x; v[1] = (bf16)f0.y; v[2] = (bf16)f0.z; v[3] = (bf16)f0.w;
    v[4] = (bf16)f1.x; v[5] = (bf16)f1.y; v[6] = (bf16)f1.z; v[7] = (bf16)f1.w;
    *(bf16x8*)(dst + i + j * 8) = v;
  }
}

// Wq/Wk/Wv -> packed bf16 [3][1024][1024]
__global__ __launch_bounds__(256) void cvt3_kernel(const float* __restrict__ a,
                                                   const float* __restrict__ b,
                                                   const float* __restrict__ c,
                                                   bf16* __restrict__ dst) {
  const float* s = blockIdx.y == 0 ? a : (blockIdx.y == 1 ? b : c);
  bf16* d = dst + (size_t)blockIdx.y * DMODEL * DMODEL;
  size_t i = ((size_t)blockIdx.x * 256 + threadIdx.x) * 16;
#pragma unroll
  for (int j = 0; j < 2; ++j) {
    float4 f0 = *(const float4*)(s + i + j * 8);
    float4 f1 = *(const float4*)(s + i + j * 8 + 4);
    bf16x8 v;
    v[0] = (bf16)f0.x; v[1] = (bf16)f0.y; v[2] = (bf16)f0.z; v[3] = (bf16)f0.w;
    v[4] = (bf16)f1.x; v[5] = (bf16)f1.y; v[6] = (bf16)f1.z; v[7] = (bf16)f1.w;
    *(bf16x8*)(d + i + j * 8) = v;
  }
}

// ---- mask -> compacted-position scan, IN PLACE, idempotent (see R5) ----
__global__ __launch_bounds__(256) void scan_kernel(int* __restrict__ posv) {
  __shared__ int sums[256];
  const int b = blockIdx.x, t = threadIdx.x;
  int* m = posv + b * SEQ;
  int f[8], cnt = 0;
#pragma unroll
  for (int j = 0; j < 8; ++j) {
    int x = m[t * 8 + j];
    int unm = (x < 0) ? 0 : ((x & 0x40000000) ? 1 : (x == 0 ? 1 : 0));
    f[j] = unm; cnt += unm;
  }
  sums[t] = cnt;
  __syncthreads();
  if (t == 0) {
    int acc = 0;
#pragma unroll 8
    for (int i = 0; i < 256; ++i) { int s = sums[i]; sums[i] = acc; acc += s; }
  }
  __syncthreads();
  int p = sums[t];
#pragma unroll
  for (int j = 0; j < 8; ++j) {
    m[t * 8 + j] = (int)((f[j] ? 0x40000000u : 0x80000000u) | (unsigned)p);
    p += f[j];
  }
}

// ---- merged Q/K/V projection for one 2-batch chunk (4096 tokens).
//      grid (16, 48): nt 0-15 Q heads, 16-31 K heads, 32-47 V heads.
//      A (xbf) and W (bf16) both staged via global_load_lds -> no staging VALU.
//      Q epilogue: scaled scatter to Qall. K/V: compacted scatter (R5). ----
__global__ __launch_bounds__(256) void proj_kernel(
    const bf16* __restrict__ xb, const bf16* __restrict__ Wall,
    const float* __restrict__ bq, const float* __restrict__ bk,
    const float* __restrict__ bv, const int* __restrict__ posv,
    bf16* __restrict__ Qall, bf16* __restrict__ kv, int b_base) {
  __shared__ __align__(16) bf16 lW[64 * 64];
  __shared__ __align__(16) bf16 lXw[4][64 * 64];
  const int t = threadIdx.x, wave = t >> 6, lane = t & 63;
  const int quad = lane >> 4, c = lane & 15;
  const int m0 = blockIdx.x * 256;           // local token rows (0..4095)
  const int nt = blockIdx.y;
  const int sel = nt >> 4, h = nt & 15;      // 0=Q 1=K 2=V
  const bf16* W = Wall + (size_t)sel * DMODEL * DMODEL + (size_t)(h * HDIM) * DMODEL;
  bf16* pw = lXw[wave];
  // pre-swizzled staging sources (row&7 == lane>>3 for all iters)
  const int sr = lane >> 3, sg = lane & 7;
  const bf16* aS = xb + (size_t)(m0 + wave * 64 + sr) * DMODEL + ((sg ^ sr) * 8);
  const bf16* wS = W + (size_t)(wave * 8 + sr) * DMODEL + ((sg ^ sr) * 8);
  f32x4 acc[4][4] = {};
  for (int k0 = 0; k0 < DMODEL; k0 += 64) {
    __syncthreads();
    gload_lds16(wS + k0, lW + wave * 512);
    gload_lds16(wS + 32 * DMODEL + k0, lW + wave * 512 + 2048);
#pragma unroll
    for (int ii = 0; ii < 8; ++ii)
      gload_lds16(aS + k0 + (size_t)ii * 8 * DMODEL, pw + ii * 512);
    __syncthreads();
#pragma unroll
    for (int kk = 0; kk < 2; ++kk) {
      bf16x8 af[4], bfr[4];
#pragma unroll
      for (int mi = 0; mi < 4; ++mi) {
        int row = mi * 16 + c;
        af[mi] = *(const bf16x8*)(pw + row * 64 + (((kk * 4 + quad) ^ (row & 7)) * 8));
      }
#pragma unroll
      for (int ni = 0; ni < 4; ++ni) {
        int row = ni * 16 + c;
        bfr[ni] = *(const bf16x8*)(lW + row * 64 + (((kk * 4 + quad) ^ (row & 7)) * 8));
      }
#pragma unroll
      for (int mi = 0; mi < 4; ++mi)
#pragma unroll
        for (int ni = 0; ni < 4; ++ni)
          acc[mi][ni] = __builtin_amdgcn_mfma_f32_16x16x32_bf16(af[mi], bfr[ni], acc[mi][ni], 0, 0, 0);
    }
  }

  if (sel == 0) {
    // Q: scaled scatter by token
#pragma unroll
    for (int ni = 0; ni < 4; ++ni) {
      int hd = ni * 16 + c;
      float bqv = bq[h * HDIM + hd];
#pragma unroll
      for (int mi = 0; mi < 4; ++mi)
#pragma unroll
        for (int r = 0; r < 4; ++r) {
          int tok = m0 + wave * 64 + mi * 16 + quad * 4 + r;
          int b_loc = tok >> 11, s = tok & 2047;
          Qall[((size_t)((b_base + b_loc) * NHEAD + h) * SEQ + s) * HDIM + hd] =
              (bf16)((acc[mi][ni][r] + bqv) * ATT_SCALE);
        }
    }
  } else {
    const float* bias = (sel == 1 ? bk : bv) + h * HDIM;
    const int isV = (sel == 2);
    const int b_loc0 = m0 >> 11;             // block spans one batch
    int v2 = posv[b_loc0 * SEQ + SEQ - 1];
    int nk = (v2 & 0x3FFFFFFF) + (v2 >= 0 ? 1 : 0);
    bf16* base = kv + (size_t)(b_loc0 * NHEAD + h) * BHSTRIDE;
#pragma unroll
    for (int ni = 0; ni < 4; ++ni) {
      int hd = ni * 16 + c;
      float bv_ = bias[hd];
#pragma unroll
      for (int mi = 0; mi < 4; ++mi)
#pragma unroll
        for (int r = 0; r < 4; ++r) {
          int tok = m0 + wave * 64 + mi * 16 + quad * 4 + r;
          int s = tok & 2047;
          int pv = posv[b_loc0 * SEQ + s];
          int pos = pv & 0x3FFFFFFF;
          int dst = (pv >= 0) ? pos : (nk + (s - pos));
          float val = (pv >= 0) ? (acc[mi][ni][r] + bv_) : 0.0f;
          if (isV) base[SEQHD + (size_t)hd * SEQ + dst] = (bf16)val;
          else     base[(size_t)dst * HDIM + hd] = (bf16)val;
        }
    }
  }
}

// ---- attention over COMPACTED keys, one 2-batch chunk per launch.
//      1024 blocks x 256 threads (4 waves x 16 q-rows) = 16 waves/CU: full
//      occupancy at the 4-waves/SIMD register cap, so chunking costs nothing.
//      XCD swizzle: 4 bh per XCD -> 2 MB K/V per L2. ----
__global__ __launch_bounds__(256, 4) void attn4_kernel(
    const bf16* __restrict__ Qall, const bf16* __restrict__ KV,
    const int* __restrict__ posv, bf16* __restrict__ O, int chunk) {
  __shared__ __align__(16) bf16 lK[64 * 64];
  __shared__ __align__(16) bf16 lV[64 * 64];
  __shared__ __align__(16) bf16 lPw[4][16 * 64];
  const int t = threadIdx.x, wave = t >> 6, lane = t & 63;
  const int quad = lane >> 4, c = lane & 15;
  const int i = blockIdx.x;                  // 0..1023
  const int xcd = i & 7, slot = i >> 3;      // slot 0..127
  const int bhl = xcd * 4 + (slot >> 5);     // 0..31, 4 bh per XCD
  const int qt = slot & 31;
  const int b_loc = bhl >> 4, h = bhl & 15;
  const int b = chunk * 2 + b_loc;
  const int q0 = qt * 64 + wave * 16;
  const bf16* Qh = Qall + (size_t)(b * NHEAD + h) * SEQHD;
  const bf16* Kb = KV + (size_t)(b_loc * NHEAD + h) * BHSTRIDE;
  const bf16* Vtb = Kb + SEQHD;
  bf16* pw = lPw[wave];

  int v2 = posv[b * SEQ + SEQ - 1];
  int nk = (v2 & 0x3FFFFFFF) + (v2 >= 0 ? 1 : 0);
  int NT = ((nk + 63) >> 6) << 6;

  const int srow = t >> 3;                              // 0..31
  const int sswz = (t & 7) ^ (srow & 7);
  const bf16* kSrc = Kb + (size_t)srow * HDIM + sswz * 8;
  const bf16* vSrc = Vtb + (size_t)srow * SEQ + sswz * 8;
  bf16* kDst = lK + wave * 512;
  bf16* vDst = lV + wave * 512;

  bf16x8 qf[2];
#pragma unroll
  for (int kk = 0; kk < 2; ++kk)
    qf[kk] = *(const bf16x8*)(Qh + (size_t)(q0 + c) * HDIM + kk * 32 + quad * 8);

  f32x4 oacc[4] = {};
  float mrun[4], lrun[4];
#pragma unroll
  for (int r = 0; r < 4; ++r) { mrun[r] = -1e30f; lrun[r] = 0.0f; }

#pragma unroll
  for (int i2 = 0; i2 < 2; ++i2) {
    gload_lds16(kSrc + i2 * 32 * HDIM, kDst + i2 * 2048);
    gload_lds16(vSrc + (size_t)i2 * 32 * SEQ, vDst + i2 * 2048);
  }
  __syncthreads();

  for (int kt = 0; kt < NT; kt += 64) {
    f32x4 sacc[4] = {};
#pragma unroll
    for (int kk = 0; kk < 2; ++kk) {
      bf16x8 kf[4];
#pragma unroll
      for (int ni = 0; ni < 4; ++ni) {
        int row = ni * 16 + c;
        kf[ni] = *(const bf16x8*)(lK + row * 64 + (((kk * 4 + quad) ^ (row & 7)) * 8));
      }
#pragma unroll
      for (int ni = 0; ni < 4; ++ni)
        sacc[ni] = __builtin_amdgcn_mfma_f32_16x16x32_bf16(qf[kk], kf[ni], sacc[ni], 0, 0, 0);
    }

    __syncthreads();  // A: lK consumed; V[kt] staging drained
    if (kt + 64 < NT) {
      const bf16* ks = kSrc + (size_t)(kt + 64) * HDIM;
#pragma unroll
      for (int i2 = 0; i2 < 2; ++i2) gload_lds16(ks + i2 * 32 * HDIM, kDst + i2 * 2048);
    }

    float sm[4];
    if (kt + 64 <= nk) {
      sm[0] = sm[1] = sm[2] = sm[3] = 0.0f;
    } else {
#pragma unroll
      for (int ni = 0; ni < 4; ++ni) sm[ni] = (kt + ni * 16 + c < nk) ? 0.0f : -3e38f;
    }

#pragma unroll
    for (int r = 0; r < 4; ++r) {
      float sv[4];
#pragma unroll
      for (int ni = 0; ni < 4; ++ni) sv[ni] = sacc[ni][r] + sm[ni];
      float mx = fmaxf(fmaxf(sv[0], sv[1]), fmaxf(sv[2], sv[3]));
      mx = fmaxf(mx, __shfl_xor(mx, 1));
      mx = fmaxf(mx, __shfl_xor(mx, 2));
      mx = fmaxf(mx, __shfl_xor(mx, 4));
      mx = fmaxf(mx, __shfl_xor(mx, 8));
      float mo = mrun[r];
      float mn = fmaxf(mo, mx);
      float al = __builtin_amdgcn_exp2f(mo - mn);
      mrun[r] = mn;
      float rs = 0.0f, p[4];
#pragma unroll
      for (int ni = 0; ni < 4; ++ni) { p[ni] = __builtin_amdgcn_exp2f(sv[ni] - mn); rs += p[ni]; }
      rs += __shfl_xor(rs, 1);
      rs += __shfl_xor(rs, 2);
      rs += __shfl_xor(rs, 4);
      rs += __shfl_xor(rs, 8);
      lrun[r] = lrun[r] * al + rs;
      int row = quad * 4 + r;
#pragma unroll
      for (int ni = 0; ni < 4; ++ni) {
        oacc[ni][r] *= al;
        int colT = ni * 16 + c;
        pw[row * 64 + (((colT >> 3) ^ (row & 7)) * 8) + (colT & 7)] = (bf16)p[ni];
      }
    }

#pragma unroll
    for (int kk = 0; kk < 2; ++kk) {
      bf16x8 pf, vfr[4];
      pf = *(const bf16x8*)(pw + c * 64 + (((kk * 4 + quad) ^ (c & 7)) * 8));
#pragma unroll
      for (int ni = 0; ni < 4; ++ni) {
        int row = ni * 16 + c;
        vfr[ni] = *(const bf16x8*)(lV + row * 64 + (((kk * 4 + quad) ^ (row & 7)) * 8));
      }
#pragma unroll
      for (int ni = 0; ni < 4; ++ni)
        oacc[ni] = __builtin_amdgcn_mfma_f32_16x16x32_bf16(pf, vfr[ni], oacc[ni], 0, 0, 0);
    }

    __syncthreads();  // B: lV consumed; K[kt+64] staging drained
    if (kt + 64 < NT) {
      const bf16* vs = vSrc + (kt + 64);
#pragma unroll
      for (int i2 = 0; i2 < 2; ++i2) gload_lds16(vs + (size_t)i2 * 32 * SEQ, vDst + i2 * 2048);
    }
  }

#pragma unroll
  for (int r = 0; r < 4; ++r) {
    float lv = lrun[r];
    float inv = lv > 0.0f ? 1.0f / lv : 0.0f;
    size_t tok = (size_t)b * SEQ + q0 + quad * 4 + r;
#pragma unroll
    for (int ni = 0; ni < 4; ++ni)
      O[tok * DMODEL + h * HDIM + ni * 16 + c] = (bf16)(oacc[ni][r] * inv);
  }
}

// ---- output projection: out = O*Wo^T + bo (fp32). O and Wo both bf16,
//      both staged via global_load_lds. ----
__global__ __launch_bounds__(256) void outproj_kernel(
    const bf16* __restrict__ O, const bf16* __restrict__ Wob,
    const float* __restrict__ bo, float* __restrict__ out) {
  __shared__ __align__(16) bf16 lW[64 * 64];
  __shared__ __align__(16) bf16 lXw[4][64 * 64];
  const int t = threadIdx.x, wave = t >> 6, lane = t & 63;
  const int quad = lane >> 4, c = lane & 15;
  const int m0 = blockIdx.x * 256;           // token rows
  const int n0 = blockIdx.y * 64;            // output cols
  bf16* pw = lXw[wave];
  const int sr = lane >> 3, sg = lane & 7;
  const bf16* aS = O + (size_t)(m0 + wave * 64 + sr) * DMODEL + ((sg ^ sr) * 8);
  const bf16* wS = Wob + (size_t)(n0 + wave * 8 + sr) * DMODEL + ((sg ^ sr) * 8);
  f32x4 acc[4][4] = {};
  for (int k0 = 0; k0 < DMODEL; k0 += 64) {
    __syncthreads();
    gload_lds16(wS + k0, lW + wave * 512);
    gload_lds16(wS + 32 * DMODEL + k0, lW + wave * 512 + 2048);
#pragma unroll
    for (int ii = 0; ii < 8; ++ii)
      gload_lds16(aS + k0 + (size_t)ii * 8 * DMODEL, pw + ii * 512);
    __syncthreads();
#pragma unroll
    for (int kk = 0; kk < 2; ++kk) {
      bf16x8 af[4], bfr[4];
#pragma unroll
      for (int mi = 0; mi < 4; ++mi) {
        int row = mi * 16 + c;
        af[mi] = *(const bf16x8*)(pw + row * 64 + (((kk * 4 + quad) ^ (row & 7)) * 8));
      }
#pragma unroll
      for (int ni = 0; ni < 4; ++ni) {
        int row = ni * 16 + c;
        bfr[ni] = *(const bf16x8*)(lW + row * 64 + (((kk * 4 + quad) ^ (row & 7)) * 8));
      }
#pragma unroll
      for (int mi = 0; mi < 4; ++mi)
#pragma unroll
        for (int ni = 0; ni < 4; ++ni)
          acc[mi][ni] = __builtin_amdgcn_mfma_f32_16x16x32_bf16(af[mi], bfr[ni], acc[mi][ni], 0, 0, 0);
    }
  }
#pragma unroll
  for (int ni = 0; ni < 4; ++ni) {
    int gn = n0 + ni * 16 + c;
    float bv_ = bo[gn];
#pragma unroll
    for (int mi = 0; mi < 4; ++mi)
#pragma unroll
      for (int r = 0; r < 4; ++r) {
        int gm = m0 + wave * 64 + mi * 16 + quad * 4 + r;
        out[(size_t)gm * DMODEL + gn] = acc[mi][ni][r] + bv_;
      }
  }
}

extern "C" void kernel_launch(void* const* d_in, const int* in_sizes, int n_in,
                              void* d_out, int out_size, void* d_ws, size_t ws_size,
                              hipStream_t stream) {
  const float* x  = (const float*)d_in[0];
  int*         posv = (int*)d_in[1];                 // mask -> compacted pos (in place)
  const float* Wq = (const float*)d_in[2]; const float* bq = (const float*)d_in[3];
  const float* Wk = (const float*)d_in[4]; const float* bk = (const float*)d_in[5];
  const float* Wv = (const float*)d_in[6]; const float* bv = (const float*)d_in[7];
  const float* Wo = (const float*)d_in[8]; const float* bo = (const float*)d_in[9];
  float* out = (float*)d_out;
  char* outc = (char*)d_out;
  char* xc   = (char*)d_in[0];
  const size_t half = (size_t)NBATCH * SEQ * DMODEL * 2;  // 16,777,216 B
  const size_t qtr  = half / 2;                            // 8,388,608 B

  // Regions (16.78 MB each): R0=d_out.lo R1=d_out.hi R2=x.lo R3=x.hi
  // Timeline (all stream-serial; x fp32 dead after cvt_x):
  //   cvt_x:  x(R2∪R3) -> xbf(R1)
  //   cvt3:   Wq/Wk/Wv -> Wbf3(R3.hi)            [dead after proj1]
  //   proj0:  xbf.lo,Wbf3 -> Qall(R0.lo)+KV(R2)
  //   attn_A: Qall.lo,KV -> O.lo(R3.lo)
  //   proj1:  xbf.hi,Wbf3 -> Qall(R0.hi)+KV(R2)
  //   attn_B: Qall.hi,KV -> O.hi(R3.hi)          [overwrites dead Wbf3]
  //   cvt_wo: Wo -> Wobf(R2)                     [KV dead]
  //   outproj: O(R3),Wobf(R2) -> out(R0∪R1)      [no overlap with reads]
  bf16* Qall = (bf16*)d_out;
  bf16* xbf  = (bf16*)(outc + half);
  bf16* KV   = (bf16*)xc;
  bf16* O    = (bf16*)(xc + half);
  bf16* Wbf3 = (bf16*)(xc + half + qtr);
  bf16* Wobf = (bf16*)xc;

  scan_kernel<<<dim3(NBATCH), 256, 0, stream>>>(posv);
  cvt_kernel<<<dim3(2048), 256, 0, stream>>>(x, xbf);
  cvt3_kernel<<<dim3(256, 3), 256, 0, stream>>>(Wq, Wk, Wv, Wbf3);
  proj_kernel<<<dim3(16, 48), 256, 0, stream>>>(xbf, Wbf3, bq, bk, bv, posv, Qall, KV, 0);
  attn4_kernel<<<dim3(1024), 256, 0, stream>>>(Qall, KV, posv, O, 0);
  proj_kernel<<<dim3(16, 48), 256, 0, stream>>>(xbf + (size_t)2 * SEQ * DMODEL, Wbf3, bq, bk, bv,
                                                posv + 2 * SEQ, Qall, KV, 2);
  attn4_kernel<<<dim3(1024), 256, 0, stream>>>(Qall, KV, posv, O, 1);
  cvt_kernel<<<dim3(256), 256, 0, stream>>>(Wo, Wobf);
  outproj_kernel<<<dim3(32, 16), 256, 0, stream>>>(O, Wobf, bo, out);
}

// Round 7
// 324.382 us; speedup vs baseline: 2.7378x; 1.1133x over previous
//
#include <hip/hip_runtime.h>
#include <stdint.h>

typedef __bf16 bf16;
typedef __bf16 bf16x8 __attribute__((ext_vector_type(8)));
typedef float f32x4 __attribute__((ext_vector_type(4)));

#define SEQ 2048
#define NHEAD 16
#define HDIM 64
#define DMODEL 1024
#define NBATCH 4
// 0.125 * log2(e): softmax runs in exp2 domain
#define ATT_SCALE 0.18033688011112042f
#define SEQHD (SEQ * HDIM)          // 131072
#define BHSTRIDE (2 * SEQHD)        // per-(b,h): K tile then V^T tile

// LDS slot invariant: L[row*64 + ((blk ^ (row&7))*8) + off] = SRC[row][blk*8+off]

__device__ __forceinline__ void gload_lds16(const bf16* g, bf16* l) {
  __builtin_amdgcn_global_load_lds(
      (const __attribute__((address_space(1))) uint32_t*)g,
      (__attribute__((address_space(3))) uint32_t*)l, 16, 0, 0);
}

__device__ __forceinline__ uint32_t pk2(float a, float b) {
  bf16 x = (bf16)a, y = (bf16)b;
  return (uint32_t)__builtin_bit_cast(uint16_t, x) |
         ((uint32_t)__builtin_bit_cast(uint16_t, y) << 16);
}

// ---- fp32 -> bf16 conversion (memory-bound pre-pass), 16 elems/thread ----
__global__ __launch_bounds__(256) void cvt_kernel(const float* __restrict__ src,
                                                  bf16* __restrict__ dst) {
  size_t i = ((size_t)blockIdx.x * 256 + threadIdx.x) * 16;
#pragma unroll
  for (int j = 0; j < 2; ++j) {
    float4 f0 = *(const float4*)(src + i + j * 8);
    float4 f1 = *(const float4*)(src + i + j * 8 + 4);
    bf16x8 v;
    v[0] = (bf16)f0.x; v[1] = (bf16)f0.y; v[2] = (bf16)f0.z; v[3] = (bf16)f0.w;
    v[4] = (bf16)f1.x; v[5] = (bf16)f1.y; v[6] = (bf16)f1.z; v[7] = (bf16)f1.w;
    *(bf16x8*)(dst + i + j * 8) = v;
  }
}

// Wq/Wk/Wv -> packed bf16 [3][1024][1024]
__global__ __launch_bounds__(256) void cvt3_kernel(const float* __restrict__ a,
                                                   const float* __restrict__ b,
                                                   const float* __restrict__ c,
                                                   bf16* __restrict__ dst) {
  const float* s = blockIdx.y == 0 ? a : (blockIdx.y == 1 ? b : c);
  bf16* d = dst + (size_t)blockIdx.y * DMODEL * DMODEL;
  size_t i = ((size_t)blockIdx.x * 256 + threadIdx.x) * 16;
#pragma unroll
  for (int j = 0; j < 2; ++j) {
    float4 f0 = *(const float4*)(s + i + j * 8);
    float4 f1 = *(const float4*)(s + i + j * 8 + 4);
    bf16x8 v;
    v[0] = (bf16)f0.x; v[1] = (bf16)f0.y; v[2] = (bf16)f0.z; v[3] = (bf16)f0.w;
    v[4] = (bf16)f1.x; v[5] = (bf16)f1.y; v[6] = (bf16)f1.z; v[7] = (bf16)f1.w;
    *(bf16x8*)(d + i + j * 8) = v;
  }
}

// ---- mask -> compacted-position scan, IN PLACE, idempotent (see R5) ----
__global__ __launch_bounds__(256) void scan_kernel(int* __restrict__ posv) {
  __shared__ int sums[256];
  const int b = blockIdx.x, t = threadIdx.x;
  int* m = posv + b * SEQ;
  int f[8], cnt = 0;
#pragma unroll
  for (int j = 0; j < 8; ++j) {
    int x = m[t * 8 + j];
    int unm = (x < 0) ? 0 : ((x & 0x40000000) ? 1 : (x == 0 ? 1 : 0));
    f[j] = unm; cnt += unm;
  }
  sums[t] = cnt;
  __syncthreads();
  if (t == 0) {
    int acc = 0;
#pragma unroll 8
    for (int i = 0; i < 256; ++i) { int s = sums[i]; sums[i] = acc; acc += s; }
  }
  __syncthreads();
  int p = sums[t];
#pragma unroll
  for (int j = 0; j < 8; ++j) {
    m[t * 8 + j] = (int)((f[j] ? 0x40000000u : 0x80000000u) | (unsigned)p);
    p += f[j];
  }
}

// ---- merged Q/K/V projection for one 2-batch chunk (4096 tokens). ----
__global__ __launch_bounds__(256) void proj_kernel(
    const bf16* __restrict__ xb, const bf16* __restrict__ Wall,
    const float* __restrict__ bq, const float* __restrict__ bk,
    const float* __restrict__ bv, const int* __restrict__ posv,
    bf16* __restrict__ Qall, bf16* __restrict__ kv, int b_base) {
  __shared__ __align__(16) bf16 lW[64 * 64];
  __shared__ __align__(16) bf16 lXw[4][64 * 64];
  const int t = threadIdx.x, wave = t >> 6, lane = t & 63;
  const int quad = lane >> 4, c = lane & 15;
  const int m0 = blockIdx.x * 256;           // local token rows (0..4095)
  const int nt = blockIdx.y;
  const int sel = nt >> 4, h = nt & 15;      // 0=Q 1=K 2=V
  const bf16* W = Wall + (size_t)sel * DMODEL * DMODEL + (size_t)(h * HDIM) * DMODEL;
  bf16* pw = lXw[wave];
  const int sr = lane >> 3, sg = lane & 7;
  const bf16* aS = xb + (size_t)(m0 + wave * 64 + sr) * DMODEL + ((sg ^ sr) * 8);
  const bf16* wS = W + (size_t)(wave * 8 + sr) * DMODEL + ((sg ^ sr) * 8);
  f32x4 acc[4][4] = {};
  for (int k0 = 0; k0 < DMODEL; k0 += 64) {
    __syncthreads();
    gload_lds16(wS + k0, lW + wave * 512);
    gload_lds16(wS + 32 * DMODEL + k0, lW + wave * 512 + 2048);
#pragma unroll
    for (int ii = 0; ii < 8; ++ii)
      gload_lds16(aS + k0 + (size_t)ii * 8 * DMODEL, pw + ii * 512);
    __syncthreads();
#pragma unroll
    for (int kk = 0; kk < 2; ++kk) {
      bf16x8 af[4], bfr[4];
#pragma unroll
      for (int mi = 0; mi < 4; ++mi) {
        int row = mi * 16 + c;
        af[mi] = *(const bf16x8*)(pw + row * 64 + (((kk * 4 + quad) ^ (row & 7)) * 8));
      }
#pragma unroll
      for (int ni = 0; ni < 4; ++ni) {
        int row = ni * 16 + c;
        bfr[ni] = *(const bf16x8*)(lW + row * 64 + (((kk * 4 + quad) ^ (row & 7)) * 8));
      }
#pragma unroll
      for (int mi = 0; mi < 4; ++mi)
#pragma unroll
        for (int ni = 0; ni < 4; ++ni)
          acc[mi][ni] = __builtin_amdgcn_mfma_f32_16x16x32_bf16(af[mi], bfr[ni], acc[mi][ni], 0, 0, 0);
    }
  }

  if (sel == 0) {
#pragma unroll
    for (int ni = 0; ni < 4; ++ni) {
      int hd = ni * 16 + c;
      float bqv = bq[h * HDIM + hd];
#pragma unroll
      for (int mi = 0; mi < 4; ++mi)
#pragma unroll
        for (int r = 0; r < 4; ++r) {
          int tok = m0 + wave * 64 + mi * 16 + quad * 4 + r;
          int b_loc = tok >> 11, s = tok & 2047;
          Qall[((size_t)((b_base + b_loc) * NHEAD + h) * SEQ + s) * HDIM + hd] =
              (bf16)((acc[mi][ni][r] + bqv) * ATT_SCALE);
        }
    }
  } else {
    const float* bias = (sel == 1 ? bk : bv) + h * HDIM;
    const int isV = (sel == 2);
    const int b_loc0 = m0 >> 11;             // block spans one batch
    int v2 = posv[b_loc0 * SEQ + SEQ - 1];
    int nk = (v2 & 0x3FFFFFFF) + (v2 >= 0 ? 1 : 0);
    bf16* base = kv + (size_t)(b_loc0 * NHEAD + h) * BHSTRIDE;
#pragma unroll
    for (int ni = 0; ni < 4; ++ni) {
      int hd = ni * 16 + c;
      float bv_ = bias[hd];
#pragma unroll
      for (int mi = 0; mi < 4; ++mi)
#pragma unroll
        for (int r = 0; r < 4; ++r) {
          int tok = m0 + wave * 64 + mi * 16 + quad * 4 + r;
          int s = tok & 2047;
          int pv = posv[b_loc0 * SEQ + s];
          int pos = pv & 0x3FFFFFFF;
          int dst = (pv >= 0) ? pos : (nk + (s - pos));
          float val = (pv >= 0) ? (acc[mi][ni][r] + bv_) : 0.0f;
          if (isV) base[SEQHD + (size_t)hd * SEQ + dst] = (bf16)val;
          else     base[(size_t)dst * HDIM + hd] = (bf16)val;
        }
    }
  }
}

// ---- attention over COMPACTED keys, one 2-batch chunk per launch.
//      SWAPPED QK^T: sacc = mfma(K_frag, Q_frag) -> lane holds S^T[k][q=c]:
//      16 P-values per lane, ONE q-row each. Row max/sum = lane-local chain +
//      shfl_xor(16,32). P packed as u32 pairs -> 8 ds_write_b32 (vs 16 b16).
//      Rescale factor broadcast to oacc layout (q=quad*4+r) via 4 shfl.
//      PV path (pf b128 read + mfma(P, V)) unchanged. ----
__global__ __launch_bounds__(256, 4) void attn4_kernel(
    const bf16* __restrict__ Qall, const bf16* __restrict__ KV,
    const int* __restrict__ posv, bf16* __restrict__ O, int chunk) {
  __shared__ __align__(16) bf16 lK[64 * 64];
  __shared__ __align__(16) bf16 lV[64 * 64];
  __shared__ __align__(16) bf16 lPw[4][16 * 64];
  const int t = threadIdx.x, wave = t >> 6, lane = t & 63;
  const int quad = lane >> 4, c = lane & 15;
  const int i = blockIdx.x;                  // 0..1023
  const int xcd = i & 7, slot = i >> 3;      // slot 0..127
  const int bhl = xcd * 4 + (slot >> 5);     // 0..31, 4 bh per XCD
  const int qt = slot & 31;
  const int b_loc = bhl >> 4, h = bhl & 15;
  const int b = chunk * 2 + b_loc;
  const int q0 = qt * 64 + wave * 16;
  const bf16* Qh = Qall + (size_t)(b * NHEAD + h) * SEQHD;
  const bf16* Kb = KV + (size_t)(b_loc * NHEAD + h) * BHSTRIDE;
  const bf16* Vtb = Kb + SEQHD;
  bf16* pw = lPw[wave];

  int v2 = posv[b * SEQ + SEQ - 1];
  int nk = (v2 & 0x3FFFFFFF) + (v2 >= 0 ? 1 : 0);
  int NT = ((nk + 63) >> 6) << 6;

  const int srow = t >> 3;                              // 0..31
  const int sswz = (t & 7) ^ (srow & 7);
  const bf16* kSrc = Kb + (size_t)srow * HDIM + sswz * 8;
  const bf16* vSrc = Vtb + (size_t)srow * SEQ + sswz * 8;
  bf16* kDst = lK + wave * 512;
  bf16* vDst = lV + wave * 512;

  bf16x8 qf[2];
#pragma unroll
  for (int kk = 0; kk < 2; ++kk)
    qf[kk] = *(const bf16x8*)(Qh + (size_t)(q0 + c) * HDIM + kk * 32 + quad * 8);

  f32x4 oacc[4] = {};
  float mrun = -1e30f, lrun = 0.0f;          // softmax state for q-row = q0 + c

  // packed-P store slots (swizzle-consistent with the pf b128 read below):
  // P[k=ni*16+quad*4+2m .. +1][q=c] -> u32 at
  //   c*64 + (((ni*2+(quad>>1)) ^ (c&7))*8) + (quad&1)*4 + 2m
  const int pbase = c * 64 + (quad & 1) * 4;
  const int pswz = c & 7;

#pragma unroll
  for (int i2 = 0; i2 < 2; ++i2) {
    gload_lds16(kSrc + i2 * 32 * HDIM, kDst + i2 * 2048);
    gload_lds16(vSrc + (size_t)i2 * 32 * SEQ, vDst + i2 * 2048);
  }
  __syncthreads();

  for (int kt = 0; kt < NT; kt += 64) {
    // QK^T swapped: identical fragment loads, operands exchanged
    f32x4 sacc[4] = {};
#pragma unroll
    for (int kk = 0; kk < 2; ++kk) {
      bf16x8 kf[4];
#pragma unroll
      for (int ni = 0; ni < 4; ++ni) {
        int row = ni * 16 + c;
        kf[ni] = *(const bf16x8*)(lK + row * 64 + (((kk * 4 + quad) ^ (row & 7)) * 8));
      }
#pragma unroll
      for (int ni = 0; ni < 4; ++ni)
        sacc[ni] = __builtin_amdgcn_mfma_f32_16x16x32_bf16(kf[ni], qf[kk], sacc[ni], 0, 0, 0);
    }

    __syncthreads();  // A: lK consumed; V[kt] staging drained
    if (kt + 64 < NT) {
      const bf16* ks = kSrc + (size_t)(kt + 64) * HDIM;
#pragma unroll
      for (int i2 = 0; i2 < 2; ++i2) gload_lds16(ks + i2 * 32 * HDIM, kDst + i2 * 2048);
    }

    // tail-index masking on lane-local k = kt + ni*16 + quad*4 + r
    if (kt + 64 > nk) {
      int base = kt + quad * 4 - nk;
#pragma unroll
      for (int ni = 0; ni < 4; ++ni)
#pragma unroll
        for (int r = 0; r < 4; ++r)
          if (base + ni * 16 + r >= 0) sacc[ni][r] = -3e38f;
    }

    // row stats for q = c: lane-local 16 + cross-quad xor16/xor32
    float mx = sacc[0][0];
#pragma unroll
    for (int ni = 0; ni < 4; ++ni)
#pragma unroll
      for (int r = 0; r < 4; ++r)
        if (ni | r) mx = fmaxf(mx, sacc[ni][r]);
    mx = fmaxf(mx, __shfl_xor(mx, 16));
    mx = fmaxf(mx, __shfl_xor(mx, 32));
    float mn = fmaxf(mrun, mx);
    float al = __builtin_amdgcn_exp2f(mrun - mn);
    mrun = mn;
    float rs = 0.0f;
#pragma unroll
    for (int ni = 0; ni < 4; ++ni)
#pragma unroll
      for (int r = 0; r < 4; ++r) {
        float e = __builtin_amdgcn_exp2f(sacc[ni][r] - mn);
        sacc[ni][r] = e; rs += e;
      }
    rs += __shfl_xor(rs, 16);
    rs += __shfl_xor(rs, 32);
    lrun = lrun * al + rs;

    // pack P pairs and store 8 u32 to LDS
#pragma unroll
    for (int ni = 0; ni < 4; ++ni) {
      uint32_t u0 = pk2(sacc[ni][0], sacc[ni][1]);
      uint32_t u1 = pk2(sacc[ni][2], sacc[ni][3]);
      int sl = pbase + (((ni * 2 + (quad >> 1)) ^ pswz) * 8);
      *(uint32_t*)(pw + sl) = u0;
      *(uint32_t*)(pw + sl + 2) = u1;
    }

    // broadcast rescale factor to oacc layout (q = quad*4 + r) and rescale
    float al4[4];
#pragma unroll
    for (int r = 0; r < 4; ++r) al4[r] = __shfl(al, quad * 4 + r);
#pragma unroll
    for (int ni = 0; ni < 4; ++ni)
#pragma unroll
      for (int r = 0; r < 4; ++r) oacc[ni][r] *= al4[r];

    // PV from lPw (own wave, packed write above) and lV — unchanged
#pragma unroll
    for (int kk = 0; kk < 2; ++kk) {
      bf16x8 pf, vfr[4];
      pf = *(const bf16x8*)(pw + c * 64 + (((kk * 4 + quad) ^ (c & 7)) * 8));
#pragma unroll
      for (int ni = 0; ni < 4; ++ni) {
        int row = ni * 16 + c;
        vfr[ni] = *(const bf16x8*)(lV + row * 64 + (((kk * 4 + quad) ^ (row & 7)) * 8));
      }
#pragma unroll
      for (int ni = 0; ni < 4; ++ni)
        oacc[ni] = __builtin_amdgcn_mfma_f32_16x16x32_bf16(pf, vfr[ni], oacc[ni], 0, 0, 0);
    }

    __syncthreads();  // B: lV consumed; K[kt+64] staging drained
    if (kt + 64 < NT) {
      const bf16* vs = vSrc + (kt + 64);
#pragma unroll
      for (int i2 = 0; i2 < 2; ++i2) gload_lds16(vs + (size_t)i2 * 32 * SEQ, vDst + i2 * 2048);
    }
  }

  // epilogue: 1/l broadcast from q=c layout to q=quad*4+r layout
  float linv = lrun > 0.0f ? 1.0f / lrun : 0.0f;
  float linv4[4];
#pragma unroll
  for (int r = 0; r < 4; ++r) linv4[r] = __shfl(linv, quad * 4 + r);
#pragma unroll
  for (int r = 0; r < 4; ++r) {
    size_t tok = (size_t)b * SEQ + q0 + quad * 4 + r;
#pragma unroll
    for (int ni = 0; ni < 4; ++ni)
      O[tok * DMODEL + h * HDIM + ni * 16 + c] = (bf16)(oacc[ni][r] * linv4[r]);
  }
}

// ---- output projection: out = O*Wo^T + bo (fp32). ----
__global__ __launch_bounds__(256) void outproj_kernel(
    const bf16* __restrict__ O, const bf16* __restrict__ Wob,
    const float* __restrict__ bo, float* __restrict__ out) {
  __shared__ __align__(16) bf16 lW[64 * 64];
  __shared__ __align__(16) bf16 lXw[4][64 * 64];
  const int t = threadIdx.x, wave = t >> 6, lane = t & 63;
  const int quad = lane >> 4, c = lane & 15;
  const int m0 = blockIdx.x * 256;           // token rows
  const int n0 = blockIdx.y * 64;            // output cols
  bf16* pw = lXw[wave];
  const int sr = lane >> 3, sg = lane & 7;
  const bf16* aS = O + (size_t)(m0 + wave * 64 + sr) * DMODEL + ((sg ^ sr) * 8);
  const bf16* wS = Wob + (size_t)(n0 + wave * 8 + sr) * DMODEL + ((sg ^ sr) * 8);
  f32x4 acc[4][4] = {};
  for (int k0 = 0; k0 < DMODEL; k0 += 64) {
    __syncthreads();
    gload_lds16(wS + k0, lW + wave * 512);
    gload_lds16(wS + 32 * DMODEL + k0, lW + wave * 512 + 2048);
#pragma unroll
    for (int ii = 0; ii < 8; ++ii)
      gload_lds16(aS + k0 + (size_t)ii * 8 * DMODEL, pw + ii * 512);
    __syncthreads();
#pragma unroll
    for (int kk = 0; kk < 2; ++kk) {
      bf16x8 af[4], bfr[4];
#pragma unroll
      for (int mi = 0; mi < 4; ++mi) {
        int row = mi * 16 + c;
        af[mi] = *(const bf16x8*)(pw + row * 64 + (((kk * 4 + quad) ^ (row & 7)) * 8));
      }
#pragma unroll
      for (int ni = 0; ni < 4; ++ni) {
        int row = ni * 16 + c;
        bfr[ni] = *(const bf16x8*)(lW + row * 64 + (((kk * 4 + quad) ^ (row & 7)) * 8));
      }
#pragma unroll
      for (int mi = 0; mi < 4; ++mi)
#pragma unroll
        for (int ni = 0; ni < 4; ++ni)
          acc[mi][ni] = __builtin_amdgcn_mfma_f32_16x16x32_bf16(af[mi], bfr[ni], acc[mi][ni], 0, 0, 0);
    }
  }
#pragma unroll
  for (int ni = 0; ni < 4; ++ni) {
    int gn = n0 + ni * 16 + c;
    float bv_ = bo[gn];
#pragma unroll
    for (int mi = 0; mi < 4; ++mi)
#pragma unroll
      for (int r = 0; r < 4; ++r) {
        int gm = m0 + wave * 64 + mi * 16 + quad * 4 + r;
        out[(size_t)gm * DMODEL + gn] = acc[mi][ni][r] + bv_;
      }
  }
}

extern "C" void kernel_launch(void* const* d_in, const int* in_sizes, int n_in,
                              void* d_out, int out_size, void* d_ws, size_t ws_size,
                              hipStream_t stream) {
  const float* x  = (const float*)d_in[0];
  int*         posv = (int*)d_in[1];                 // mask -> compacted pos (in place)
  const float* Wq = (const float*)d_in[2]; const float* bq = (const float*)d_in[3];
  const float* Wk = (const float*)d_in[4]; const float* bk = (const float*)d_in[5];
  const float* Wv = (const float*)d_in[6]; const float* bv = (const float*)d_in[7];
  const float* Wo = (const float*)d_in[8]; const float* bo = (const float*)d_in[9];
  float* out = (float*)d_out;
  char* outc = (char*)d_out;
  char* xc   = (char*)d_in[0];
  const size_t half = (size_t)NBATCH * SEQ * DMODEL * 2;  // 16,777,216 B
  const size_t qtr  = half / 2;                            // 8,388,608 B

  // Regions (16.78 MB each): R0=d_out.lo R1=d_out.hi R2=x.lo R3=x.hi
  //   cvt_x:  x(R2∪R3) -> xbf(R1)
  //   cvt3:   Wq/Wk/Wv -> Wbf3(R3.hi)            [dead after proj1]
  //   proj0:  xbf.lo,Wbf3 -> Qall(R0.lo)+KV(R2)
  //   attn_A: Qall.lo,KV -> O.lo(R3.lo)
  //   proj1:  xbf.hi,Wbf3 -> Qall(R0.hi)+KV(R2)
  //   attn_B: Qall.hi,KV -> O.hi(R3.hi)          [overwrites dead Wbf3]
  //   cvt_wo: Wo -> Wobf(R2)                     [KV dead]
  //   outproj: O(R3),Wobf(R2) -> out(R0∪R1)
  bf16* Qall = (bf16*)d_out;
  bf16* xbf  = (bf16*)(outc + half);
  bf16* KV   = (bf16*)xc;
  bf16* O    = (bf16*)(xc + half);
  bf16* Wbf3 = (bf16*)(xc + half + qtr);
  bf16* Wobf = (bf16*)xc;

  scan_kernel<<<dim3(NBATCH), 256, 0, stream>>>(posv);
  cvt_kernel<<<dim3(2048), 256, 0, stream>>>(x, xbf);
  cvt3_kernel<<<dim3(256, 3), 256, 0, stream>>>(Wq, Wk, Wv, Wbf3);
  proj_kernel<<<dim3(16, 48), 256, 0, stream>>>(xbf, Wbf3, bq, bk, bv, posv, Qall, KV, 0);
  attn4_kernel<<<dim3(1024), 256, 0, stream>>>(Qall, KV, posv, O, 0);
  proj_kernel<<<dim3(16, 48), 256, 0, stream>>>(xbf + (size_t)2 * SEQ * DMODEL, Wbf3, bq, bk, bv,
                                                posv + 2 * SEQ, Qall, KV, 2);
  attn4_kernel<<<dim3(1024), 256, 0, stream>>>(Qall, KV, posv, O, 1);
  cvt_kernel<<<dim3(256), 256, 0, stream>>>(Wo, Wobf);
  outproj_kernel<<<dim3(32, 16), 256, 0, stream>>>(O, Wobf, bo, out);
}

// Round 9
// 311.748 us; speedup vs baseline: 2.8488x; 1.0405x over previous
//
#include <hip/hip_runtime.h>
#include <stdint.h>

typedef __bf16 bf16;
typedef __bf16 bf16x8 __attribute__((ext_vector_type(8)));
typedef float f32x4 __attribute__((ext_vector_type(4)));

#define SEQ 2048
#define NHEAD 16
#define HDIM 64
#define DMODEL 1024
#define NBATCH 4
// 0.125 * log2(e): softmax runs in exp2 domain
#define ATT_SCALE 0.18033688011112042f
#define SEQHD (SEQ * HDIM)          // 131072
#define BHSTRIDE (2 * SEQHD)        // per-(b,h): K tile then V^T tile

// LDS slot invariant: L[row*64 + ((blk ^ (row&7))*8) + off] = SRC[row][blk*8+off]

__device__ __forceinline__ void gload_lds16(const bf16* g, bf16* l) {
  __builtin_amdgcn_global_load_lds(
      (const __attribute__((address_space(1))) uint32_t*)g,
      (__attribute__((address_space(3))) uint32_t*)l, 16, 0, 0);
}

__device__ __forceinline__ uint32_t pk2(float a, float b) {
  bf16 x = (bf16)a, y = (bf16)b;
  return (uint32_t)__builtin_bit_cast(uint16_t, x) |
         ((uint32_t)__builtin_bit_cast(uint16_t, y) << 16);
}

// ---- fp32 -> bf16 conversion (memory-bound pre-pass), 16 elems/thread ----
__global__ __launch_bounds__(256) void cvt_kernel(const float* __restrict__ src,
                                                  bf16* __restrict__ dst) {
  size_t i = ((size_t)blockIdx.x * 256 + threadIdx.x) * 16;
#pragma unroll
  for (int j = 0; j < 2; ++j) {
    float4 f0 = *(const float4*)(src + i + j * 8);
    float4 f1 = *(const float4*)(src + i + j * 8 + 4);
    bf16x8 v;
    v[0] = (bf16)f0.x; v[1] = (bf16)f0.y; v[2] = (bf16)f0.z; v[3] = (bf16)f0.w;
    v[4] = (bf16)f1.x; v[5] = (bf16)f1.y; v[6] = (bf16)f1.z; v[7] = (bf16)f1.w;
    *(bf16x8*)(dst + i + j * 8) = v;
  }
}

// Wq/Wk/Wv -> packed bf16 [3][1024][1024]
__global__ __launch_bounds__(256) void cvt3_kernel(const float* __restrict__ a,
                                                   const float* __restrict__ b,
                                                   const float* __restrict__ c,
                                                   bf16* __restrict__ dst) {
  const float* s = blockIdx.y == 0 ? a : (blockIdx.y == 1 ? b : c);
  bf16* d = dst + (size_t)blockIdx.y * DMODEL * DMODEL;
  size_t i = ((size_t)blockIdx.x * 256 + threadIdx.x) * 16;
#pragma unroll
  for (int j = 0; j < 2; ++j) {
    float4 f0 = *(const float4*)(s + i + j * 8);
    float4 f1 = *(const float4*)(s + i + j * 8 + 4);
    bf16x8 v;
    v[0] = (bf16)f0.x; v[1] = (bf16)f0.y; v[2] = (bf16)f0.z; v[3] = (bf16)f0.w;
    v[4] = (bf16)f1.x; v[5] = (bf16)f1.y; v[6] = (bf16)f1.z; v[7] = (bf16)f1.w;
    *(bf16x8*)(d + i + j * 8) = v;
  }
}

// ---- mask -> compacted-position scan, IN PLACE, idempotent; also emits the
//      inverse map inv[b][pos] = s (zero-filled for pos >= nk).
//      MUST run after cvt_x: inv lives in the (then-dead) fp32 x region. ----
__global__ __launch_bounds__(256) void scan_kernel(int* __restrict__ posv,
                                                   int* __restrict__ inv) {
  __shared__ int sums[256];
  const int b = blockIdx.x, t = threadIdx.x;
  int* m = posv + b * SEQ;
  int* iv = inv + b * SEQ;
  int f[8], cnt = 0;
#pragma unroll
  for (int j = 0; j < 8; ++j) {
    int x = m[t * 8 + j];
    int unm = (x < 0) ? 0 : ((x & 0x40000000) ? 1 : (x == 0 ? 1 : 0));
    f[j] = unm; cnt += unm;
    iv[t * 8 + j] = 0;                       // memset inv (scatter after barrier)
  }
  sums[t] = cnt;
  __syncthreads();
  if (t == 0) {
    int acc = 0;
#pragma unroll 8
    for (int i = 0; i < 256; ++i) { int s = sums[i]; sums[i] = acc; acc += s; }
  }
  __syncthreads();
  int p = sums[t];
#pragma unroll
  for (int j = 0; j < 8; ++j) {
    m[t * 8 + j] = (int)((f[j] ? 0x40000000u : 0x80000000u) | (unsigned)p);
    if (f[j]) iv[p] = t * 8 + j;
    p += f[j];
  }
}

// ---- Q projection, ALL 4 batches (Q needed for every query token). ----
__global__ __launch_bounds__(256) void qproj_kernel(
    const bf16* __restrict__ xb, const bf16* __restrict__ Wall,
    const float* __restrict__ bq, bf16* __restrict__ Qall) {
  __shared__ __align__(16) bf16 lW[64 * 64];
  __shared__ __align__(16) bf16 lXw[4][64 * 64];
  const int t = threadIdx.x, wave = t >> 6, lane = t & 63;
  const int quad = lane >> 4, c = lane & 15;
  const int m0 = blockIdx.x * 256;           // token rows 0..8191
  const int h = blockIdx.y;
  const bf16* W = Wall + (size_t)(h * HDIM) * DMODEL;
  bf16* pw = lXw[wave];
  const int sr = lane >> 3, sg = lane & 7;
  const bf16* aS = xb + (size_t)(m0 + wave * 64 + sr) * DMODEL + ((sg ^ sr) * 8);
  const bf16* wS = W + (size_t)(wave * 8 + sr) * DMODEL + ((sg ^ sr) * 8);
  f32x4 acc[4][4] = {};
  for (int k0 = 0; k0 < DMODEL; k0 += 64) {
    __syncthreads();
    gload_lds16(wS + k0, lW + wave * 512);
    gload_lds16(wS + 32 * DMODEL + k0, lW + wave * 512 + 2048);
#pragma unroll
    for (int ii = 0; ii < 8; ++ii)
      gload_lds16(aS + k0 + (size_t)ii * 8 * DMODEL, pw + ii * 512);
    __syncthreads();
#pragma unroll
    for (int kk = 0; kk < 2; ++kk) {
      bf16x8 af[4], bfr[4];
#pragma unroll
      for (int mi = 0; mi < 4; ++mi) {
        int row = mi * 16 + c;
        af[mi] = *(const bf16x8*)(pw + row * 64 + (((kk * 4 + quad) ^ (row & 7)) * 8));
      }
#pragma unroll
      for (int ni = 0; ni < 4; ++ni) {
        int row = ni * 16 + c;
        bfr[ni] = *(const bf16x8*)(lW + row * 64 + (((kk * 4 + quad) ^ (row & 7)) * 8));
      }
#pragma unroll
      for (int mi = 0; mi < 4; ++mi)
#pragma unroll
        for (int ni = 0; ni < 4; ++ni)
          acc[mi][ni] = __builtin_amdgcn_mfma_f32_16x16x32_bf16(af[mi], bfr[ni], acc[mi][ni], 0, 0, 0);
    }
  }
#pragma unroll
  for (int ni = 0; ni < 4; ++ni) {
    int hd = ni * 16 + c;
    float bqv = bq[h * HDIM + hd];
#pragma unroll
    for (int mi = 0; mi < 4; ++mi)
#pragma unroll
      for (int r = 0; r < 4; ++r) {
        int tok = m0 + wave * 64 + mi * 16 + quad * 4 + r;
        int b = tok >> 11, s = tok & 2047;
        Qall[((size_t)(b * NHEAD + h) * SEQ + s) * HDIM + hd] =
            (bf16)((acc[mi][ni][r] + bqv) * ATT_SCALE);
      }
  }
}

// ---- K/V projection over COMPACTED rows only (one 2-batch chunk).
//      grid (16, 32): x -> b_loc = x>>3, mb = x&7 (256 compacted rows each;
//      blocks beyond ceil(nk/256) exit). y -> isV = y>>4, h = y&15.
//      A rows gathered via inv[] (global_load_lds source is per-lane);
//      epilogue stores dense at slot = compacted row. Slots >= nk get
//      garbage here and are fixed by zf_kernel before attn reads them. ----
__global__ __launch_bounds__(256) void kvproj_kernel(
    const bf16* __restrict__ xb, const bf16* __restrict__ Wall,
    const float* __restrict__ bk, const float* __restrict__ bv,
    const int* __restrict__ posv, const int* __restrict__ inv,
    bf16* __restrict__ kv) {
  __shared__ __align__(16) bf16 lW[64 * 64];
  __shared__ __align__(16) bf16 lXw[4][64 * 64];
  const int t = threadIdx.x, wave = t >> 6, lane = t & 63;
  const int quad = lane >> 4, c = lane & 15;
  const int bx = blockIdx.x;
  const int b_loc = bx >> 3, mb = bx & 7;
  const int nt = blockIdx.y;
  const int isV = nt >> 4, h = nt & 15;
  int v2 = posv[b_loc * SEQ + SEQ - 1];
  int nk = (v2 & 0x3FFFFFFF) + (v2 >= 0 ? 1 : 0);
  const int c0 = mb * 256;                   // compacted row base
  if (c0 >= nk) return;                      // block-uniform exit (pre-barrier)
  const bf16* W = Wall + (size_t)(1 + isV) * DMODEL * DMODEL + (size_t)(h * HDIM) * DMODEL;
  const float* bias = (isV ? bv : bk) + h * HDIM;
  bf16* pw = lXw[wave];
  const int sr = lane >> 3, sg = lane & 7;
  const int swzc = (sg ^ sr) * 8;
  const bf16* wS = W + (size_t)(wave * 8 + sr) * DMODEL + swzc;
  const int* invb = inv + b_loc * SEQ;
  int grow[8];
#pragma unroll
  for (int ii = 0; ii < 8; ++ii)
    grow[ii] = invb[c0 + wave * 64 + ii * 8 + sr];   // 0 for slots >= nk
  const bf16* xbb = xb + (size_t)b_loc * SEQ * DMODEL + swzc;
  f32x4 acc[4][4] = {};
  for (int k0 = 0; k0 < DMODEL; k0 += 64) {
    __syncthreads();
    gload_lds16(wS + k0, lW + wave * 512);
    gload_lds16(wS + 32 * DMODEL + k0, lW + wave * 512 + 2048);
#pragma unroll
    for (int ii = 0; ii < 8; ++ii)
      gload_lds16(xbb + (size_t)grow[ii] * DMODEL + k0, pw + ii * 512);
    __syncthreads();
#pragma unroll
    for (int kk = 0; kk < 2; ++kk) {
      bf16x8 af[4], bfr[4];
#pragma unroll
      for (int mi = 0; mi < 4; ++mi) {
        int row = mi * 16 + c;
        af[mi] = *(const bf16x8*)(pw + row * 64 + (((kk * 4 + quad) ^ (row & 7)) * 8));
      }
#pragma unroll
      for (int ni = 0; ni < 4; ++ni) {
        int row = ni * 16 + c;
        bfr[ni] = *(const bf16x8*)(lW + row * 64 + (((kk * 4 + quad) ^ (row & 7)) * 8));
      }
#pragma unroll
      for (int mi = 0; mi < 4; ++mi)
#pragma unroll
        for (int ni = 0; ni < 4; ++ni)
          acc[mi][ni] = __builtin_amdgcn_mfma_f32_16x16x32_bf16(af[mi], bfr[ni], acc[mi][ni], 0, 0, 0);
    }
  }
  bf16* base = kv + (size_t)(b_loc * NHEAD + h) * BHSTRIDE;
#pragma unroll
  for (int ni = 0; ni < 4; ++ni) {
    int hd = ni * 16 + c;
    float bv_ = bias[hd];
#pragma unroll
    for (int mi = 0; mi < 4; ++mi)
#pragma unroll
      for (int r = 0; r < 4; ++r) {
        int dst = c0 + wave * 64 + mi * 16 + quad * 4 + r;
        float val = acc[mi][ni][r] + bv_;
        if (isV) base[SEQHD + (size_t)hd * SEQ + dst] = (bf16)val;
        else     base[(size_t)dst * HDIM + hd] = (bf16)val;
      }
  }
}

// ---- zero the K/V pad [nk, NT) so attn's tail tile reads exact zeros ----
__global__ __launch_bounds__(256) void zf_kernel(bf16* __restrict__ kv,
                                                 const int* __restrict__ posv) {
  const int bh = blockIdx.x, t = threadIdx.x;
  const int b_loc = bh >> 4, h = bh & 15;
  int v2 = posv[b_loc * SEQ + SEQ - 1];
  int nk = (v2 & 0x3FFFFFFF) + (v2 >= 0 ? 1 : 0);
  int NT = ((nk + 63) >> 6) << 6;
  int pad = NT - nk;
  if (pad == 0) return;
  bf16* base = kv + (size_t)(b_loc * NHEAD + h) * BHSTRIDE;
  int hd = t & 63;
  for (int rr = t >> 6; rr < pad; rr += 4) {
    base[(size_t)(nk + rr) * HDIM + hd] = (bf16)0.0f;        // K row
    base[SEQHD + (size_t)hd * SEQ + nk + rr] = (bf16)0.0f;   // V^T col
  }
}

// ---- attention over COMPACTED keys (swapped QK^T, see R7) ----
__global__ __launch_bounds__(256, 4) void attn4_kernel(
    const bf16* __restrict__ Qall, const bf16* __restrict__ KV,
    const int* __restrict__ posv, bf16* __restrict__ O, int chunk) {
  __shared__ __align__(16) bf16 lK[64 * 64];
  __shared__ __align__(16) bf16 lV[64 * 64];
  __shared__ __align__(16) bf16 lPw[4][16 * 64];
  const int t = threadIdx.x, wave = t >> 6, lane = t & 63;
  const int quad = lane >> 4, c = lane & 15;
  const int i = blockIdx.x;                  // 0..1023
  const int xcd = i & 7, slot = i >> 3;      // slot 0..127
  const int bhl = xcd * 4 + (slot >> 5);     // 0..31, 4 bh per XCD
  const int qt = slot & 31;
  const int b_loc = bhl >> 4, h = bhl & 15;
  const int b = chunk * 2 + b_loc;
  const int q0 = qt * 64 + wave * 16;
  const bf16* Qh = Qall + (size_t)(b * NHEAD + h) * SEQHD;
  const bf16* Kb = KV + (size_t)(b_loc * NHEAD + h) * BHSTRIDE;
  const bf16* Vtb = Kb + SEQHD;
  bf16* pw = lPw[wave];

  int v2 = posv[b * SEQ + SEQ - 1];
  int nk = (v2 & 0x3FFFFFFF) + (v2 >= 0 ? 1 : 0);
  int NT = ((nk + 63) >> 6) << 6;

  const int srow = t >> 3;                              // 0..31
  const int sswz = (t & 7) ^ (srow & 7);
  const bf16* kSrc = Kb + (size_t)srow * HDIM + sswz * 8;
  const bf16* vSrc = Vtb + (size_t)srow * SEQ + sswz * 8;
  bf16* kDst = lK + wave * 512;
  bf16* vDst = lV + wave * 512;

  bf16x8 qf[2];
#pragma unroll
  for (int kk = 0; kk < 2; ++kk)
    qf[kk] = *(const bf16x8*)(Qh + (size_t)(q0 + c) * HDIM + kk * 32 + quad * 8);

  f32x4 oacc[4] = {};
  float mrun = -1e30f, lrun = 0.0f;          // softmax state for q-row = q0 + c

  const int pbase = c * 64 + (quad & 1) * 4;
  const int pswz = c & 7;

#pragma unroll
  for (int i2 = 0; i2 < 2; ++i2) {
    gload_lds16(kSrc + i2 * 32 * HDIM, kDst + i2 * 2048);
    gload_lds16(vSrc + (size_t)i2 * 32 * SEQ, vDst + i2 * 2048);
  }
  __syncthreads();

  for (int kt = 0; kt < NT; kt += 64) {
    f32x4 sacc[4] = {};
#pragma unroll
    for (int kk = 0; kk < 2; ++kk) {
      bf16x8 kf[4];
#pragma unroll
      for (int ni = 0; ni < 4; ++ni) {
        int row = ni * 16 + c;
        kf[ni] = *(const bf16x8*)(lK + row * 64 + (((kk * 4 + quad) ^ (row & 7)) * 8));
      }
#pragma unroll
      for (int ni = 0; ni < 4; ++ni)
        sacc[ni] = __builtin_amdgcn_mfma_f32_16x16x32_bf16(kf[ni], qf[kk], sacc[ni], 0, 0, 0);
    }

    __syncthreads();  // A: lK consumed; V[kt] staging drained
    if (kt + 64 < NT) {
      const bf16* ks = kSrc + (size_t)(kt + 64) * HDIM;
#pragma unroll
      for (int i2 = 0; i2 < 2; ++i2) gload_lds16(ks + i2 * 32 * HDIM, kDst + i2 * 2048);
    }

    // tail-index masking on lane-local k = kt + ni*16 + quad*4 + r
    if (kt + 64 > nk) {
      int base = kt + quad * 4 - nk;
#pragma unroll
      for (int ni = 0; ni < 4; ++ni)
#pragma unroll
        for (int r = 0; r < 4; ++r)
          if (base + ni * 16 + r >= 0) sacc[ni][r] = -3e38f;
    }

    // row stats for q = c: lane-local 16 + cross-quad xor16/xor32
    float mx = sacc[0][0];
#pragma unroll
    for (int ni = 0; ni < 4; ++ni)
#pragma unroll
      for (int r = 0; r < 4; ++r)
        if (ni | r) mx = fmaxf(mx, sacc[ni][r]);
    mx = fmaxf(mx, __shfl_xor(mx, 16));
    mx = fmaxf(mx, __shfl_xor(mx, 32));
    float mn = fmaxf(mrun, mx);
    float al = __builtin_amdgcn_exp2f(mrun - mn);
    mrun = mn;
    float rs = 0.0f;
#pragma unroll
    for (int ni = 0; ni < 4; ++ni)
#pragma unroll
      for (int r = 0; r < 4; ++r) {
        float e = __builtin_amdgcn_exp2f(sacc[ni][r] - mn);
        sacc[ni][r] = e; rs += e;
      }
    rs += __shfl_xor(rs, 16);
    rs += __shfl_xor(rs, 32);
    lrun = lrun * al + rs;

    // pack P pairs and store 8 u32 to LDS
#pragma unroll
    for (int ni = 0; ni < 4; ++ni) {
      uint32_t u0 = pk2(sacc[ni][0], sacc[ni][1]);
      uint32_t u1 = pk2(sacc[ni][2], sacc[ni][3]);
      int sl = pbase + (((ni * 2 + (quad >> 1)) ^ pswz) * 8);
      *(uint32_t*)(pw + sl) = u0;
      *(uint32_t*)(pw + sl + 2) = u1;
    }

    // broadcast rescale factor to oacc layout (q = quad*4 + r) and rescale
    float al4[4];
#pragma unroll
    for (int r = 0; r < 4; ++r) al4[r] = __shfl(al, quad * 4 + r);
#pragma unroll
    for (int ni = 0; ni < 4; ++ni)
#pragma unroll
      for (int r = 0; r < 4; ++r) oacc[ni][r] *= al4[r];

    // PV from lPw (own wave) and lV
#pragma unroll
    for (int kk = 0; kk < 2; ++kk) {
      bf16x8 pf, vfr[4];
      pf = *(const bf16x8*)(pw + c * 64 + (((kk * 4 + quad) ^ (c & 7)) * 8));
#pragma unroll
      for (int ni = 0; ni < 4; ++ni) {
        int row = ni * 16 + c;
        vfr[ni] = *(const bf16x8*)(lV + row * 64 + (((kk * 4 + quad) ^ (row & 7)) * 8));
      }
#pragma unroll
      for (int ni = 0; ni < 4; ++ni)
        oacc[ni] = __builtin_amdgcn_mfma_f32_16x16x32_bf16(pf, vfr[ni], oacc[ni], 0, 0, 0);
    }

    __syncthreads();  // B: lV consumed; K[kt+64] staging drained
    if (kt + 64 < NT) {
      const bf16* vs = vSrc + (kt + 64);
#pragma unroll
      for (int i2 = 0; i2 < 2; ++i2) gload_lds16(vs + (size_t)i2 * 32 * SEQ, vDst + i2 * 2048);
    }
  }

  // epilogue: 1/l broadcast from q=c layout to q=quad*4+r layout
  float linv = lrun > 0.0f ? 1.0f / lrun : 0.0f;
  float linv4[4];
#pragma unroll
  for (int r = 0; r < 4; ++r) linv4[r] = __shfl(linv, quad * 4 + r);
#pragma unroll
  for (int r = 0; r < 4; ++r) {
    size_t tok = (size_t)b * SEQ + q0 + quad * 4 + r;
#pragma unroll
    for (int ni = 0; ni < 4; ++ni)
      O[tok * DMODEL + h * HDIM + ni * 16 + c] = (bf16)(oacc[ni][r] * linv4[r]);
  }
}

// ---- output projection: out = O*Wo^T + bo (fp32). ----
__global__ __launch_bounds__(256) void outproj_kernel(
    const bf16* __restrict__ O, const bf16* __restrict__ Wob,
    const float* __restrict__ bo, float* __restrict__ out) {
  __shared__ __align__(16) bf16 lW[64 * 64];
  __shared__ __align__(16) bf16 lXw[4][64 * 64];
  const int t = threadIdx.x, wave = t >> 6, lane = t & 63;
  const int quad = lane >> 4, c = lane & 15;
  const int m0 = blockIdx.x * 256;           // token rows
  const int n0 = blockIdx.y * 64;            // output cols
  bf16* pw = lXw[wave];
  const int sr = lane >> 3, sg = lane & 7;
  const bf16* aS = O + (size_t)(m0 + wave * 64 + sr) * DMODEL + ((sg ^ sr) * 8);
  const bf16* wS = Wob + (size_t)(n0 + wave * 8 + sr) * DMODEL + ((sg ^ sr) * 8);
  f32x4 acc[4][4] = {};
  for (int k0 = 0; k0 < DMODEL; k0 += 64) {
    __syncthreads();
    gload_lds16(wS + k0, lW + wave * 512);
    gload_lds16(wS + 32 * DMODEL + k0, lW + wave * 512 + 2048);
#pragma unroll
    for (int ii = 0; ii < 8; ++ii)
      gload_lds16(aS + k0 + (size_t)ii * 8 * DMODEL, pw + ii * 512);
    __syncthreads();
#pragma unroll
    for (int kk = 0; kk < 2; ++kk) {
      bf16x8 af[4], bfr[4];
#pragma unroll
      for (int mi = 0; mi < 4; ++mi) {
        int row = mi * 16 + c;
        af[mi] = *(const bf16x8*)(pw + row * 64 + (((kk * 4 + quad) ^ (row & 7)) * 8));
      }
#pragma unroll
      for (int ni = 0; ni < 4; ++ni) {
        int row = ni * 16 + c;
        bfr[ni] = *(const bf16x8*)(lW + row * 64 + (((kk * 4 + quad) ^ (row & 7)) * 8));
      }
#pragma unroll
      for (int mi = 0; mi < 4; ++mi)
#pragma unroll
        for (int ni = 0; ni < 4; ++ni)
          acc[mi][ni] = __builtin_amdgcn_mfma_f32_16x16x32_bf16(af[mi], bfr[ni], acc[mi][ni], 0, 0, 0);
    }
  }
#pragma unroll
  for (int ni = 0; ni < 4; ++ni) {
    int gn = n0 + ni * 16 + c;
    float bv_ = bo[gn];
#pragma unroll
    for (int mi = 0; mi < 4; ++mi)
#pragma unroll
      for (int r = 0; r < 4; ++r) {
        int gm = m0 + wave * 64 + mi * 16 + quad * 4 + r;
        out[(size_t)gm * DMODEL + gn] = acc[mi][ni][r] + bv_;
      }
  }
}

extern "C" void kernel_launch(void* const* d_in, const int* in_sizes, int n_in,
                              void* d_out, int out_size, void* d_ws, size_t ws_size,
                              hipStream_t stream) {
  const float* x  = (const float*)d_in[0];
  int*         posv = (int*)d_in[1];                 // mask -> compacted pos (in place)
  const float* Wq = (const float*)d_in[2]; const float* bq = (const float*)d_in[3];
  const float* Wk = (const float*)d_in[4]; const float* bk = (const float*)d_in[5];
  const float* Wv = (const float*)d_in[6]; const float* bv = (const float*)d_in[7];
  const float* Wo = (const float*)d_in[8]; const float* bo = (const float*)d_in[9];
  float* out = (float*)d_out;
  char* outc = (char*)d_out;
  char* xc   = (char*)d_in[0];
  const size_t half = (size_t)NBATCH * SEQ * DMODEL * 2;  // 16,777,216 B
  const size_t qtr  = half / 2;                            // 8,388,608 B

  // Regions (16.78 MB each): R0=d_out.lo R1=d_out.hi R2=x.lo R3=x.hi
  //   cvt_x:   x(R2∪R3) -> xbf(R1)               [x fp32 dead after this]
  //   scan:    posv in place; inv -> R3.hi tail (after Wbf3, 32 KB)
  //            *** must run AFTER cvt_x: inv region overlaps fp32 x (R8 bug) ***
  //   cvt3:    Wq/Wk/Wv -> Wbf3(R3.hi)           [dead after kvproj1]
  //   qproj:   xbf,Wbf3 -> Qall(R0)
  //   kvproj0: xbf.lo gather(inv) -> KV(R2); zf0 zeroes pad
  //   attn_A:  Qall.lo,KV -> O.lo(R3.lo)
  //   kvproj1: xbf.hi gather(inv) -> KV(R2); zf1 zeroes pad
  //   attn_B:  Qall.hi,KV -> O.hi(R3.hi)         [overwrites dead Wbf3+inv]
  //   cvt_wo:  Wo -> Wobf(R2)                    [KV dead]
  //   outproj: O(R3),Wobf(R2) -> out(R0∪R1)
  bf16* Qall = (bf16*)d_out;
  bf16* xbf  = (bf16*)(outc + half);
  bf16* KV   = (bf16*)xc;
  bf16* O    = (bf16*)(xc + half);
  bf16* Wbf3 = (bf16*)(xc + half + qtr);
  int*  inv  = (int*)(xc + half + qtr + (size_t)3 * DMODEL * DMODEL * 2);
  bf16* Wobf = (bf16*)xc;

  cvt_kernel<<<dim3(2048), 256, 0, stream>>>(x, xbf);
  scan_kernel<<<dim3(NBATCH), 256, 0, stream>>>(posv, inv);
  cvt3_kernel<<<dim3(256, 3), 256, 0, stream>>>(Wq, Wk, Wv, Wbf3);
  qproj_kernel<<<dim3(32, 16), 256, 0, stream>>>(xbf, Wbf3, bq, Qall);
  kvproj_kernel<<<dim3(16, 32), 256, 0, stream>>>(xbf, Wbf3, bk, bv, posv, inv, KV);
  zf_kernel<<<dim3(32), 256, 0, stream>>>(KV, posv);
  attn4_kernel<<<dim3(1024), 256, 0, stream>>>(Qall, KV, posv, O, 0);
  kvproj_kernel<<<dim3(16, 32), 256, 0, stream>>>(xbf + (size_t)2 * SEQ * DMODEL, Wbf3, bk, bv,
                                                  posv + 2 * SEQ, inv + 2 * SEQ, KV);
  zf_kernel<<<dim3(32), 256, 0, stream>>>(KV, posv + 2 * SEQ);
  attn4_kernel<<<dim3(1024), 256, 0, stream>>>(Qall, KV, posv, O, 1);
  cvt_kernel<<<dim3(256), 256, 0, stream>>>(Wo, Wobf);
  outproj_kernel<<<dim3(32, 16), 256, 0, stream>>>(O, Wobf, bo, out);
}

// Round 10
// 298.083 us; speedup vs baseline: 2.9794x; 1.0458x over previous
//
#include <hip/hip_runtime.h>
#include <stdint.h>

typedef __bf16 bf16;
typedef __bf16 bf16x8 __attribute__((ext_vector_type(8)));
typedef float f32x4 __attribute__((ext_vector_type(4)));

#define SEQ 2048
#define NHEAD 16
#define HDIM 64
#define DMODEL 1024
#define NBATCH 4
// 0.125 * log2(e): softmax runs in exp2 domain
#define ATT_SCALE 0.18033688011112042f
#define SEQHD (SEQ * HDIM)          // 131072
#define BHSTRIDE (2 * SEQHD)        // per-(b,h): K tile then V^T tile

// LDS slot invariant: L[row*64 + ((blk ^ (row&7))*8) + off] = SRC[row][blk*8+off]

__device__ __forceinline__ void gload_lds16(const bf16* g, bf16* l) {
  __builtin_amdgcn_global_load_lds(
      (const __attribute__((address_space(1))) uint32_t*)g,
      (__attribute__((address_space(3))) uint32_t*)l, 16, 0, 0);
}

__device__ __forceinline__ uint32_t pk2(float a, float b) {
  bf16 x = (bf16)a, y = (bf16)b;
  return (uint32_t)__builtin_bit_cast(uint16_t, x) |
         ((uint32_t)__builtin_bit_cast(uint16_t, y) << 16);
}

// ---- fp32 -> bf16 conversion (memory-bound pre-pass), 16 elems/thread ----
__global__ __launch_bounds__(256) void cvt_kernel(const float* __restrict__ src,
                                                  bf16* __restrict__ dst) {
  size_t i = ((size_t)blockIdx.x * 256 + threadIdx.x) * 16;
#pragma unroll
  for (int j = 0; j < 2; ++j) {
    float4 f0 = *(const float4*)(src + i + j * 8);
    float4 f1 = *(const float4*)(src + i + j * 8 + 4);
    bf16x8 v;
    v[0] = (bf16)f0.x; v[1] = (bf16)f0.y; v[2] = (bf16)f0.z; v[3] = (bf16)f0.w;
    v[4] = (bf16)f1.x; v[5] = (bf16)f1.y; v[6] = (bf16)f1.z; v[7] = (bf16)f1.w;
    *(bf16x8*)(dst + i + j * 8) = v;
  }
}

// Wq/Wk/Wv -> packed bf16 [3][1024][1024]
__global__ __launch_bounds__(256) void cvt3_kernel(const float* __restrict__ a,
                                                   const float* __restrict__ b,
                                                   const float* __restrict__ c,
                                                   bf16* __restrict__ dst) {
  const float* s = blockIdx.y == 0 ? a : (blockIdx.y == 1 ? b : c);
  bf16* d = dst + (size_t)blockIdx.y * DMODEL * DMODEL;
  size_t i = ((size_t)blockIdx.x * 256 + threadIdx.x) * 16;
#pragma unroll
  for (int j = 0; j < 2; ++j) {
    float4 f0 = *(const float4*)(s + i + j * 8);
    float4 f1 = *(const float4*)(s + i + j * 8 + 4);
    bf16x8 v;
    v[0] = (bf16)f0.x; v[1] = (bf16)f0.y; v[2] = (bf16)f0.z; v[3] = (bf16)f0.w;
    v[4] = (bf16)f1.x; v[5] = (bf16)f1.y; v[6] = (bf16)f1.z; v[7] = (bf16)f1.w;
    *(bf16x8*)(d + i + j * 8) = v;
  }
}

// ---- mask -> compacted-position scan, IN PLACE, idempotent; also emits the
//      inverse map inv[b][pos] = s (zero-filled for pos >= nk).
//      MUST run after cvt_x: inv lives in the (then-dead) fp32 x region. ----
__global__ __launch_bounds__(256) void scan_kernel(int* __restrict__ posv,
                                                   int* __restrict__ inv) {
  __shared__ int sums[256];
  const int b = blockIdx.x, t = threadIdx.x;
  int* m = posv + b * SEQ;
  int* iv = inv + b * SEQ;
  int f[8], cnt = 0;
#pragma unroll
  for (int j = 0; j < 8; ++j) {
    int x = m[t * 8 + j];
    int unm = (x < 0) ? 0 : ((x & 0x40000000) ? 1 : (x == 0 ? 1 : 0));
    f[j] = unm; cnt += unm;
    iv[t * 8 + j] = 0;                       // memset inv (scatter after barrier)
  }
  sums[t] = cnt;
  __syncthreads();
  if (t == 0) {
    int acc = 0;
#pragma unroll 8
    for (int i = 0; i < 256; ++i) { int s = sums[i]; sums[i] = acc; acc += s; }
  }
  __syncthreads();
  int p = sums[t];
#pragma unroll
  for (int j = 0; j < 8; ++j) {
    m[t * 8 + j] = (int)((f[j] ? 0x40000000u : 0x80000000u) | (unsigned)p);
    if (f[j]) iv[p] = t * 8 + j;
    p += f[j];
  }
}

// ---- Q projection, ALL 4 batches. 128-row M-tiles (R10): 1024 blocks ->
//      4 blocks/CU -> 4 waves/SIMD (was 256-row/512-block/2 waves/SIMD).
//      Wave = 32 rows, acc[2][4] (32 AGPR). ----
__global__ __launch_bounds__(256) void qproj_kernel(
    const bf16* __restrict__ xb, const bf16* __restrict__ Wall,
    const float* __restrict__ bq, bf16* __restrict__ Qall) {
  __shared__ __align__(16) bf16 lW[64 * 64];
  __shared__ __align__(16) bf16 lXw[4][32 * 64];
  const int t = threadIdx.x, wave = t >> 6, lane = t & 63;
  const int quad = lane >> 4, c = lane & 15;
  const int m0 = blockIdx.x * 128;           // token rows 0..8191
  const int h = blockIdx.y;
  const bf16* W = Wall + (size_t)(h * HDIM) * DMODEL;
  bf16* pw = lXw[wave];
  const int sr = lane >> 3, sg = lane & 7;
  const bf16* aS = xb + (size_t)(m0 + wave * 32 + sr) * DMODEL + ((sg ^ sr) * 8);
  const bf16* wS = W + (size_t)(wave * 8 + sr) * DMODEL + ((sg ^ sr) * 8);
  f32x4 acc[2][4] = {};
  for (int k0 = 0; k0 < DMODEL; k0 += 64) {
    __syncthreads();
    gload_lds16(wS + k0, lW + wave * 512);
    gload_lds16(wS + 32 * DMODEL + k0, lW + wave * 512 + 2048);
#pragma unroll
    for (int ii = 0; ii < 4; ++ii)
      gload_lds16(aS + k0 + (size_t)ii * 8 * DMODEL, pw + ii * 512);
    __syncthreads();
#pragma unroll
    for (int kk = 0; kk < 2; ++kk) {
      bf16x8 af[2], bfr[4];
#pragma unroll
      for (int mi = 0; mi < 2; ++mi) {
        int row = mi * 16 + c;
        af[mi] = *(const bf16x8*)(pw + row * 64 + (((kk * 4 + quad) ^ (row & 7)) * 8));
      }
#pragma unroll
      for (int ni = 0; ni < 4; ++ni) {
        int row = ni * 16 + c;
        bfr[ni] = *(const bf16x8*)(lW + row * 64 + (((kk * 4 + quad) ^ (row & 7)) * 8));
      }
#pragma unroll
      for (int mi = 0; mi < 2; ++mi)
#pragma unroll
        for (int ni = 0; ni < 4; ++ni)
          acc[mi][ni] = __builtin_amdgcn_mfma_f32_16x16x32_bf16(af[mi], bfr[ni], acc[mi][ni], 0, 0, 0);
    }
  }
#pragma unroll
  for (int ni = 0; ni < 4; ++ni) {
    int hd = ni * 16 + c;
    float bqv = bq[h * HDIM + hd];
#pragma unroll
    for (int mi = 0; mi < 2; ++mi)
#pragma unroll
      for (int r = 0; r < 4; ++r) {
        int tok = m0 + wave * 32 + mi * 16 + quad * 4 + r;
        int b = tok >> 11, s = tok & 2047;
        Qall[((size_t)(b * NHEAD + h) * SEQ + s) * HDIM + hd] =
            (bf16)((acc[mi][ni][r] + bqv) * ATT_SCALE);
      }
  }
}

// ---- K/V projection over COMPACTED rows, 128-row tiles (R10 occupancy fix:
//      256-row tiles left only 1 block/CU after early-exit).
//      grid (32, 32): x -> b_loc = x>>4, mb = x&15; y -> isV = y>>4, h = y&15. ----
__global__ __launch_bounds__(256) void kvproj_kernel(
    const bf16* __restrict__ xb, const bf16* __restrict__ Wall,
    const float* __restrict__ bk, const float* __restrict__ bv,
    const int* __restrict__ posv, const int* __restrict__ inv,
    bf16* __restrict__ kv) {
  __shared__ __align__(16) bf16 lW[64 * 64];
  __shared__ __align__(16) bf16 lXw[4][32 * 64];
  const int t = threadIdx.x, wave = t >> 6, lane = t & 63;
  const int quad = lane >> 4, c = lane & 15;
  const int bx = blockIdx.x;
  const int b_loc = bx >> 4, mb = bx & 15;
  const int nt = blockIdx.y;
  const int isV = nt >> 4, h = nt & 15;
  int v2 = posv[b_loc * SEQ + SEQ - 1];
  int nk = (v2 & 0x3FFFFFFF) + (v2 >= 0 ? 1 : 0);
  const int c0 = mb * 128;                   // compacted row base
  if (c0 >= nk) return;                      // block-uniform exit (pre-barrier)
  const bf16* W = Wall + (size_t)(1 + isV) * DMODEL * DMODEL + (size_t)(h * HDIM) * DMODEL;
  const float* bias = (isV ? bv : bk) + h * HDIM;
  bf16* pw = lXw[wave];
  const int sr = lane >> 3, sg = lane & 7;
  const int swzc = (sg ^ sr) * 8;
  const bf16* wS = W + (size_t)(wave * 8 + sr) * DMODEL + swzc;
  const int* invb = inv + b_loc * SEQ;
  int grow[4];
#pragma unroll
  for (int ii = 0; ii < 4; ++ii)
    grow[ii] = invb[c0 + wave * 32 + ii * 8 + sr];   // 0 for slots >= nk
  const bf16* xbb = xb + (size_t)b_loc * SEQ * DMODEL + swzc;
  f32x4 acc[2][4] = {};
  for (int k0 = 0; k0 < DMODEL; k0 += 64) {
    __syncthreads();
    gload_lds16(wS + k0, lW + wave * 512);
    gload_lds16(wS + 32 * DMODEL + k0, lW + wave * 512 + 2048);
#pragma unroll
    for (int ii = 0; ii < 4; ++ii)
      gload_lds16(xbb + (size_t)grow[ii] * DMODEL + k0, pw + ii * 512);
    __syncthreads();
#pragma unroll
    for (int kk = 0; kk < 2; ++kk) {
      bf16x8 af[2], bfr[4];
#pragma unroll
      for (int mi = 0; mi < 2; ++mi) {
        int row = mi * 16 + c;
        af[mi] = *(const bf16x8*)(pw + row * 64 + (((kk * 4 + quad) ^ (row & 7)) * 8));
      }
#pragma unroll
      for (int ni = 0; ni < 4; ++ni) {
        int row = ni * 16 + c;
        bfr[ni] = *(const bf16x8*)(lW + row * 64 + (((kk * 4 + quad) ^ (row & 7)) * 8));
      }
#pragma unroll
      for (int mi = 0; mi < 2; ++mi)
#pragma unroll
        for (int ni = 0; ni < 4; ++ni)
          acc[mi][ni] = __builtin_amdgcn_mfma_f32_16x16x32_bf16(af[mi], bfr[ni], acc[mi][ni], 0, 0, 0);
    }
  }
  bf16* base = kv + (size_t)(b_loc * NHEAD + h) * BHSTRIDE;
#pragma unroll
  for (int ni = 0; ni < 4; ++ni) {
    int hd = ni * 16 + c;
    float bv_ = bias[hd];
#pragma unroll
    for (int mi = 0; mi < 2; ++mi)
#pragma unroll
      for (int r = 0; r < 4; ++r) {
        int dst = c0 + wave * 32 + mi * 16 + quad * 4 + r;
        float val = acc[mi][ni][r] + bv_;
        if (isV) base[SEQHD + (size_t)hd * SEQ + dst] = (bf16)val;
        else     base[(size_t)dst * HDIM + hd] = (bf16)val;
      }
  }
}

// ---- zero the K/V pad [nk, NT) so attn's tail tile reads exact zeros ----
__global__ __launch_bounds__(256) void zf_kernel(bf16* __restrict__ kv,
                                                 const int* __restrict__ posv) {
  const int bh = blockIdx.x, t = threadIdx.x;
  const int b_loc = bh >> 4, h = bh & 15;
  int v2 = posv[b_loc * SEQ + SEQ - 1];
  int nk = (v2 & 0x3FFFFFFF) + (v2 >= 0 ? 1 : 0);
  int NT = ((nk + 63) >> 6) << 6;
  int pad = NT - nk;
  if (pad == 0) return;
  bf16* base = kv + (size_t)(b_loc * NHEAD + h) * BHSTRIDE;
  int hd = t & 63;
  for (int rr = t >> 6; rr < pad; rr += 4) {
    base[(size_t)(nk + rr) * HDIM + hd] = (bf16)0.0f;        // K row
    base[SEQHD + (size_t)hd * SEQ + nk + rr] = (bf16)0.0f;   // V^T col
  }
}

// ---- attention over COMPACTED keys (swapped QK^T; R10: b64 P-store,
//      max3 nesting, defer-rescale THR=8) ----
__global__ __launch_bounds__(256, 4) void attn4_kernel(
    const bf16* __restrict__ Qall, const bf16* __restrict__ KV,
    const int* __restrict__ posv, bf16* __restrict__ O, int chunk) {
  __shared__ __align__(16) bf16 lK[64 * 64];
  __shared__ __align__(16) bf16 lV[64 * 64];
  __shared__ __align__(16) bf16 lPw[4][16 * 64];
  const int t = threadIdx.x, wave = t >> 6, lane = t & 63;
  const int quad = lane >> 4, c = lane & 15;
  const int i = blockIdx.x;                  // 0..1023
  const int xcd = i & 7, slot = i >> 3;      // slot 0..127
  const int bhl = xcd * 4 + (slot >> 5);     // 0..31, 4 bh per XCD
  const int qt = slot & 31;
  const int b_loc = bhl >> 4, h = bhl & 15;
  const int b = chunk * 2 + b_loc;
  const int q0 = qt * 64 + wave * 16;
  const bf16* Qh = Qall + (size_t)(b * NHEAD + h) * SEQHD;
  const bf16* Kb = KV + (size_t)(b_loc * NHEAD + h) * BHSTRIDE;
  const bf16* Vtb = Kb + SEQHD;
  bf16* pw = lPw[wave];

  int v2 = posv[b * SEQ + SEQ - 1];
  int nk = (v2 & 0x3FFFFFFF) + (v2 >= 0 ? 1 : 0);
  int NT = ((nk + 63) >> 6) << 6;

  const int srow = t >> 3;                              // 0..31
  const int sswz = (t & 7) ^ (srow & 7);
  const bf16* kSrc = Kb + (size_t)srow * HDIM + sswz * 8;
  const bf16* vSrc = Vtb + (size_t)srow * SEQ + sswz * 8;
  bf16* kDst = lK + wave * 512;
  bf16* vDst = lV + wave * 512;

  bf16x8 qf[2];
#pragma unroll
  for (int kk = 0; kk < 2; ++kk)
    qf[kk] = *(const bf16x8*)(Qh + (size_t)(q0 + c) * HDIM + kk * 32 + quad * 8);

  f32x4 oacc[4] = {};
  float mrun = -1e30f, lrun = 0.0f;          // softmax state for q-row = q0 + c

  const int pbase = c * 64 + (quad & 1) * 4;
  const int pswz = c & 7;

#pragma unroll
  for (int i2 = 0; i2 < 2; ++i2) {
    gload_lds16(kSrc + i2 * 32 * HDIM, kDst + i2 * 2048);
    gload_lds16(vSrc + (size_t)i2 * 32 * SEQ, vDst + i2 * 2048);
  }
  __syncthreads();

  for (int kt = 0; kt < NT; kt += 64) {
    f32x4 sacc[4] = {};
#pragma unroll
    for (int kk = 0; kk < 2; ++kk) {
      bf16x8 kf[4];
#pragma unroll
      for (int ni = 0; ni < 4; ++ni) {
        int row = ni * 16 + c;
        kf[ni] = *(const bf16x8*)(lK + row * 64 + (((kk * 4 + quad) ^ (row & 7)) * 8));
      }
#pragma unroll
      for (int ni = 0; ni < 4; ++ni)
        sacc[ni] = __builtin_amdgcn_mfma_f32_16x16x32_bf16(kf[ni], qf[kk], sacc[ni], 0, 0, 0);
    }

    __syncthreads();  // A: lK consumed; V[kt] staging drained
    if (kt + 64 < NT) {
      const bf16* ks = kSrc + (size_t)(kt + 64) * HDIM;
#pragma unroll
      for (int i2 = 0; i2 < 2; ++i2) gload_lds16(ks + i2 * 32 * HDIM, kDst + i2 * 2048);
    }

    // tail-index masking on lane-local k = kt + ni*16 + quad*4 + r
    if (kt + 64 > nk) {
      int base = kt + quad * 4 - nk;
#pragma unroll
      for (int ni = 0; ni < 4; ++ni)
#pragma unroll
        for (int r = 0; r < 4; ++r)
          if (base + ni * 16 + r >= 0) sacc[ni][r] = -3e38f;
    }

    // row max for q = c: max3-friendly tree + cross-quad xor16/xor32
    float m1 = fmaxf(fmaxf(sacc[0][0], sacc[0][1]), sacc[0][2]);
    float m2 = fmaxf(fmaxf(sacc[0][3], sacc[1][0]), sacc[1][1]);
    float m3 = fmaxf(fmaxf(sacc[1][2], sacc[1][3]), sacc[2][0]);
    float m4 = fmaxf(fmaxf(sacc[2][1], sacc[2][2]), sacc[2][3]);
    float m5 = fmaxf(fmaxf(sacc[3][0], sacc[3][1]), sacc[3][2]);
    float mx = fmaxf(fmaxf(fmaxf(m1, m2), m3), fmaxf(fmaxf(m4, m5), sacc[3][3]));
    mx = fmaxf(mx, __shfl_xor(mx, 16));
    mx = fmaxf(mx, __shfl_xor(mx, 32));

    // defer-rescale (T13, THR=8 in exp2 domain -> P bounded by 256)
    if (!__all(mx - mrun <= 8.0f)) {
      float mn = fmaxf(mrun, mx);
      float al = __builtin_amdgcn_exp2f(mrun - mn);
      mrun = mn;
      lrun *= al;
      float al4[4];
#pragma unroll
      for (int r = 0; r < 4; ++r) al4[r] = __shfl(al, quad * 4 + r);
#pragma unroll
      for (int ni = 0; ni < 4; ++ni)
#pragma unroll
        for (int r = 0; r < 4; ++r) oacc[ni][r] *= al4[r];
    }

    float rs = 0.0f;
#pragma unroll
    for (int ni = 0; ni < 4; ++ni)
#pragma unroll
      for (int r = 0; r < 4; ++r) {
        float e = __builtin_amdgcn_exp2f(sacc[ni][r] - mrun);
        sacc[ni][r] = e; rs += e;
      }
    rs += __shfl_xor(rs, 16);
    rs += __shfl_xor(rs, 32);
    lrun += rs;

    // pack P pairs and store one b64 per ni (R10: was 2x b32, 4-way conflicts)
#pragma unroll
    for (int ni = 0; ni < 4; ++ni) {
      uint2 u;
      u.x = pk2(sacc[ni][0], sacc[ni][1]);
      u.y = pk2(sacc[ni][2], sacc[ni][3]);
      int sl = pbase + (((ni * 2 + (quad >> 1)) ^ pswz) * 8);
      *(uint2*)(pw + sl) = u;
    }

    // PV from lPw (own wave) and lV
#pragma unroll
    for (int kk = 0; kk < 2; ++kk) {
      bf16x8 pf, vfr[4];
      pf = *(const bf16x8*)(pw + c * 64 + (((kk * 4 + quad) ^ (c & 7)) * 8));
#pragma unroll
      for (int ni = 0; ni < 4; ++ni) {
        int row = ni * 16 + c;
        vfr[ni] = *(const bf16x8*)(lV + row * 64 + (((kk * 4 + quad) ^ (row & 7)) * 8));
      }
#pragma unroll
      for (int ni = 0; ni < 4; ++ni)
        oacc[ni] = __builtin_amdgcn_mfma_f32_16x16x32_bf16(pf, vfr[ni], oacc[ni], 0, 0, 0);
    }

    __syncthreads();  // B: lV consumed; K[kt+64] staging drained
    if (kt + 64 < NT) {
      const bf16* vs = vSrc + (kt + 64);
#pragma unroll
      for (int i2 = 0; i2 < 2; ++i2) gload_lds16(vs + (size_t)i2 * 32 * SEQ, vDst + i2 * 2048);
    }
  }

  // epilogue: 1/l broadcast from q=c layout to q=quad*4+r layout
  float linv = lrun > 0.0f ? 1.0f / lrun : 0.0f;
  float linv4[4];
#pragma unroll
  for (int r = 0; r < 4; ++r) linv4[r] = __shfl(linv, quad * 4 + r);
#pragma unroll
  for (int r = 0; r < 4; ++r) {
    size_t tok = (size_t)b * SEQ + q0 + quad * 4 + r;
#pragma unroll
    for (int ni = 0; ni < 4; ++ni)
      O[tok * DMODEL + h * HDIM + ni * 16 + c] = (bf16)(oacc[ni][r] * linv4[r]);
  }
}

// ---- output projection: out = O*Wo^T + bo (fp32). 128-row M-tiles (R10). ----
__global__ __launch_bounds__(256) void outproj_kernel(
    const bf16* __restrict__ O, const bf16* __restrict__ Wob,
    const float* __restrict__ bo, float* __restrict__ out) {
  __shared__ __align__(16) bf16 lW[64 * 64];
  __shared__ __align__(16) bf16 lXw[4][32 * 64];
  const int t = threadIdx.x, wave = t >> 6, lane = t & 63;
  const int quad = lane >> 4, c = lane & 15;
  const int m0 = blockIdx.x * 128;           // token rows
  const int n0 = blockIdx.y * 64;            // output cols
  bf16* pw = lXw[wave];
  const int sr = lane >> 3, sg = lane & 7;
  const bf16* aS = O + (size_t)(m0 + wave * 32 + sr) * DMODEL + ((sg ^ sr) * 8);
  const bf16* wS = Wob + (size_t)(n0 + wave * 8 + sr) * DMODEL + ((sg ^ sr) * 8);
  f32x4 acc[2][4] = {};
  for (int k0 = 0; k0 < DMODEL; k0 += 64) {
    __syncthreads();
    gload_lds16(wS + k0, lW + wave * 512);
    gload_lds16(wS + 32 * DMODEL + k0, lW + wave * 512 + 2048);
#pragma unroll
    for (int ii = 0; ii < 4; ++ii)
      gload_lds16(aS + k0 + (size_t)ii * 8 * DMODEL, pw + ii * 512);
    __syncthreads();
#pragma unroll
    for (int kk = 0; kk < 2; ++kk) {
      bf16x8 af[2], bfr[4];
#pragma unroll
      for (int mi = 0; mi < 2; ++mi) {
        int row = mi * 16 + c;
        af[mi] = *(const bf16x8*)(pw + row * 64 + (((kk * 4 + quad) ^ (row & 7)) * 8));
      }
#pragma unroll
      for (int ni = 0; ni < 4; ++ni) {
        int row = ni * 16 + c;
        bfr[ni] = *(const bf16x8*)(lW + row * 64 + (((kk * 4 + quad) ^ (row & 7)) * 8));
      }
#pragma unroll
      for (int mi = 0; mi < 2; ++mi)
#pragma unroll
        for (int ni = 0; ni < 4; ++ni)
          acc[mi][ni] = __builtin_amdgcn_mfma_f32_16x16x32_bf16(af[mi], bfr[ni], acc[mi][ni], 0, 0, 0);
    }
  }
#pragma unroll
  for (int ni = 0; ni < 4; ++ni) {
    int gn = n0 + ni * 16 + c;
    float bv_ = bo[gn];
#pragma unroll
    for (int mi = 0; mi < 2; ++mi)
#pragma unroll
      for (int r = 0; r < 4; ++r) {
        int gm = m0 + wave * 32 + mi * 16 + quad * 4 + r;
        out[(size_t)gm * DMODEL + gn] = acc[mi][ni][r] + bv_;
      }
  }
}

extern "C" void kernel_launch(void* const* d_in, const int* in_sizes, int n_in,
                              void* d_out, int out_size, void* d_ws, size_t ws_size,
                              hipStream_t stream) {
  const float* x  = (const float*)d_in[0];
  int*         posv = (int*)d_in[1];                 // mask -> compacted pos (in place)
  const float* Wq = (const float*)d_in[2]; const float* bq = (const float*)d_in[3];
  const float* Wk = (const float*)d_in[4]; const float* bk = (const float*)d_in[5];
  const float* Wv = (const float*)d_in[6]; const float* bv = (const float*)d_in[7];
  const float* Wo = (const float*)d_in[8]; const float* bo = (const float*)d_in[9];
  float* out = (float*)d_out;
  char* outc = (char*)d_out;
  char* xc   = (char*)d_in[0];
  const size_t half = (size_t)NBATCH * SEQ * DMODEL * 2;  // 16,777,216 B
  const size_t qtr  = half / 2;                            // 8,388,608 B

  // Regions (16.78 MB each): R0=d_out.lo R1=d_out.hi R2=x.lo R3=x.hi
  //   cvt_x:   x(R2∪R3) -> xbf(R1)               [x fp32 dead after this]
  //   scan:    posv in place; inv -> R3.hi tail (after Wbf3, 32 KB)
  //            *** must run AFTER cvt_x: inv region overlaps fp32 x (R8 bug) ***
  //   cvt3:    Wq/Wk/Wv -> Wbf3(R3.hi)           [dead after kvproj1]
  //   qproj:   xbf,Wbf3 -> Qall(R0)
  //   kvproj0: xbf.lo gather(inv) -> KV(R2); zf0 zeroes pad
  //   attn_A:  Qall.lo,KV -> O.lo(R3.lo)
  //   kvproj1: xbf.hi gather(inv) -> KV(R2); zf1 zeroes pad
  //   attn_B:  Qall.hi,KV -> O.hi(R3.hi)         [overwrites dead Wbf3+inv]
  //   cvt_wo:  Wo -> Wobf(R2)                    [KV dead]
  //   outproj: O(R3),Wobf(R2) -> out(R0∪R1)
  bf16* Qall = (bf16*)d_out;
  bf16* xbf  = (bf16*)(outc + half);
  bf16* KV   = (bf16*)xc;
  bf16* O    = (bf16*)(xc + half);
  bf16* Wbf3 = (bf16*)(xc + half + qtr);
  int*  inv  = (int*)(xc + half + qtr + (size_t)3 * DMODEL * DMODEL * 2);
  bf16* Wobf = (bf16*)xc;

  cvt_kernel<<<dim3(2048), 256, 0, stream>>>(x, xbf);
  scan_kernel<<<dim3(NBATCH), 256, 0, stream>>>(posv, inv);
  cvt3_kernel<<<dim3(256, 3), 256, 0, stream>>>(Wq, Wk, Wv, Wbf3);
  qproj_kernel<<<dim3(64, 16), 256, 0, stream>>>(xbf, Wbf3, bq, Qall);
  kvproj_kernel<<<dim3(32, 32), 256, 0, stream>>>(xbf, Wbf3, bk, bv, posv, inv, KV);
  zf_kernel<<<dim3(32), 256, 0, stream>>>(KV, posv);
  attn4_kernel<<<dim3(1024), 256, 0, stream>>>(Qall, KV, posv, O, 0);
  kvproj_kernel<<<dim3(32, 32), 256, 0, stream>>>(xbf + (size_t)2 * SEQ * DMODEL, Wbf3, bk, bv,
                                                  posv + 2 * SEQ, inv + 2 * SEQ, KV);
  zf_kernel<<<dim3(32), 256, 0, stream>>>(KV, posv + 2 * SEQ);
  attn4_kernel<<<dim3(1024), 256, 0, stream>>>(Qall, KV, posv, O, 1);
  cvt_kernel<<<dim3(256), 256, 0, stream>>>(Wo, Wobf);
  outproj_kernel<<<dim3(64, 16), 256, 0, stream>>>(O, Wobf, bo, out);
}

// Round 11
// 287.821 us; speedup vs baseline: 3.0856x; 1.0357x over previous
//
#include <hip/hip_runtime.h>
#include <stdint.h>

typedef __bf16 bf16;
typedef __bf16 bf16x8 __attribute__((ext_vector_type(8)));
typedef float f32x4 __attribute__((ext_vector_type(4)));

#define SEQ 2048
#define NHEAD 16
#define HDIM 64
#define DMODEL 1024
#define NBATCH 4
// 0.125 * log2(e): softmax runs in exp2 domain
#define ATT_SCALE 0.18033688011112042f
#define SEQHD (SEQ * HDIM)          // 131072
#define BHSTRIDE (2 * SEQHD)        // per-(b,h): K tile then V^T tile

// LDS slot invariant: L[row*64 + ((blk ^ (row&7))*8) + off] = SRC[row][blk*8+off]

__device__ __forceinline__ void gload_lds16(const bf16* g, bf16* l) {
  __builtin_amdgcn_global_load_lds(
      (const __attribute__((address_space(1))) uint32_t*)g,
      (__attribute__((address_space(3))) uint32_t*)l, 16, 0, 0);
}

__device__ __forceinline__ uint32_t pk2(float a, float b) {
  bf16 x = (bf16)a, y = (bf16)b;
  return (uint32_t)__builtin_bit_cast(uint16_t, x) |
         ((uint32_t)__builtin_bit_cast(uint16_t, y) << 16);
}

// ---- fp32 -> bf16 conversion (memory-bound pre-pass), 16 elems/thread ----
__global__ __launch_bounds__(256) void cvt_kernel(const float* __restrict__ src,
                                                  bf16* __restrict__ dst) {
  size_t i = ((size_t)blockIdx.x * 256 + threadIdx.x) * 16;
#pragma unroll
  for (int j = 0; j < 2; ++j) {
    float4 f0 = *(const float4*)(src + i + j * 8);
    float4 f1 = *(const float4*)(src + i + j * 8 + 4);
    bf16x8 v;
    v[0] = (bf16)f0.x; v[1] = (bf16)f0.y; v[2] = (bf16)f0.z; v[3] = (bf16)f0.w;
    v[4] = (bf16)f1.x; v[5] = (bf16)f1.y; v[6] = (bf16)f1.z; v[7] = (bf16)f1.w;
    *(bf16x8*)(dst + i + j * 8) = v;
  }
}

// ---- merged prep: blocks 0..767 convert Wq/Wk/Wv -> Wbf3; blocks 768..771
//      run the mask scan (posv in place, idempotent) + emit inv[b][pos]=s.
//      Writes (Wbf3, inv, posv) are pairwise disjoint; MUST run after cvt_x
//      (both Wbf3 and inv live in the then-dead fp32 x region — R8 lesson). ----
__global__ __launch_bounds__(256) void prep_kernel(
    const float* __restrict__ Wq, const float* __restrict__ Wk,
    const float* __restrict__ Wv, bf16* __restrict__ Wbf3,
    int* __restrict__ posv, int* __restrict__ inv) {
  __shared__ int sums[256];
  const int bx = blockIdx.x, t = threadIdx.x;
  if (bx < 768) {
    const float* s = bx < 256 ? Wq : (bx < 512 ? Wk : Wv);
    bf16* d = Wbf3 + (size_t)(bx >> 8) * DMODEL * DMODEL;
    size_t i = ((size_t)(bx & 255) * 256 + t) * 16;
#pragma unroll
    for (int j = 0; j < 2; ++j) {
      float4 f0 = *(const float4*)(s + i + j * 8);
      float4 f1 = *(const float4*)(s + i + j * 8 + 4);
      bf16x8 v;
      v[0] = (bf16)f0.x; v[1] = (bf16)f0.y; v[2] = (bf16)f0.z; v[3] = (bf16)f0.w;
      v[4] = (bf16)f1.x; v[5] = (bf16)f1.y; v[6] = (bf16)f1.z; v[7] = (bf16)f1.w;
      *(bf16x8*)(d + i + j * 8) = v;
    }
    return;
  }
  const int b = bx - 768;
  int* m = posv + b * SEQ;
  int* iv = inv + b * SEQ;
  int f[8], cnt = 0;
#pragma unroll
  for (int j = 0; j < 8; ++j) {
    int x = m[t * 8 + j];
    int unm = (x < 0) ? 0 : ((x & 0x40000000) ? 1 : (x == 0 ? 1 : 0));
    f[j] = unm; cnt += unm;
    iv[t * 8 + j] = 0;                       // memset inv (scatter after barrier)
  }
  sums[t] = cnt;
  __syncthreads();
  if (t == 0) {
    int acc = 0;
#pragma unroll 8
    for (int i = 0; i < 256; ++i) { int s = sums[i]; sums[i] = acc; acc += s; }
  }
  __syncthreads();
  int p = sums[t];
#pragma unroll
  for (int j = 0; j < 8; ++j) {
    m[t * 8 + j] = (int)((f[j] ? 0x40000000u : 0x80000000u) | (unsigned)p);
    if (f[j]) iv[p] = t * 8 + j;
    p += f[j];
  }
}

// ---- Q projection, ALL 4 batches. 128-row M-tiles: 1024 blocks ->
//      4 blocks/CU -> 4 waves/SIMD. Wave = 32 rows, acc[2][4] (32 AGPR). ----
__global__ __launch_bounds__(256) void qproj_kernel(
    const bf16* __restrict__ xb, const bf16* __restrict__ Wall,
    const float* __restrict__ bq, bf16* __restrict__ Qall) {
  __shared__ __align__(16) bf16 lW[64 * 64];
  __shared__ __align__(16) bf16 lXw[4][32 * 64];
  const int t = threadIdx.x, wave = t >> 6, lane = t & 63;
  const int quad = lane >> 4, c = lane & 15;
  const int m0 = blockIdx.x * 128;           // token rows 0..8191
  const int h = blockIdx.y;
  const bf16* W = Wall + (size_t)(h * HDIM) * DMODEL;
  bf16* pw = lXw[wave];
  const int sr = lane >> 3, sg = lane & 7;
  const bf16* aS = xb + (size_t)(m0 + wave * 32 + sr) * DMODEL + ((sg ^ sr) * 8);
  const bf16* wS = W + (size_t)(wave * 8 + sr) * DMODEL + ((sg ^ sr) * 8);
  f32x4 acc[2][4] = {};
  for (int k0 = 0; k0 < DMODEL; k0 += 64) {
    __syncthreads();
    gload_lds16(wS + k0, lW + wave * 512);
    gload_lds16(wS + 32 * DMODEL + k0, lW + wave * 512 + 2048);
#pragma unroll
    for (int ii = 0; ii < 4; ++ii)
      gload_lds16(aS + k0 + (size_t)ii * 8 * DMODEL, pw + ii * 512);
    __syncthreads();
#pragma unroll
    for (int kk = 0; kk < 2; ++kk) {
      bf16x8 af[2], bfr[4];
#pragma unroll
      for (int mi = 0; mi < 2; ++mi) {
        int row = mi * 16 + c;
        af[mi] = *(const bf16x8*)(pw + row * 64 + (((kk * 4 + quad) ^ (row & 7)) * 8));
      }
#pragma unroll
      for (int ni = 0; ni < 4; ++ni) {
        int row = ni * 16 + c;
        bfr[ni] = *(const bf16x8*)(lW + row * 64 + (((kk * 4 + quad) ^ (row & 7)) * 8));
      }
#pragma unroll
      for (int mi = 0; mi < 2; ++mi)
#pragma unroll
        for (int ni = 0; ni < 4; ++ni)
          acc[mi][ni] = __builtin_amdgcn_mfma_f32_16x16x32_bf16(af[mi], bfr[ni], acc[mi][ni], 0, 0, 0);
    }
  }
#pragma unroll
  for (int ni = 0; ni < 4; ++ni) {
    int hd = ni * 16 + c;
    float bqv = bq[h * HDIM + hd];
#pragma unroll
    for (int mi = 0; mi < 2; ++mi)
#pragma unroll
      for (int r = 0; r < 4; ++r) {
        int tok = m0 + wave * 32 + mi * 16 + quad * 4 + r;
        int b = tok >> 11, s = tok & 2047;
        Qall[((size_t)(b * NHEAD + h) * SEQ + s) * HDIM + hd] =
            (bf16)((acc[mi][ni][r] + bqv) * ATT_SCALE);
      }
  }
}

// ---- K/V projection over COMPACTED rows, 128-row tiles.
//      grid (32, 32): x -> b_loc = x>>4, mb = x&15; y -> isV = y>>4, h = y&15.
//      R11: pad slots [nk, NT) zeroed inline (val=0 for dst>=nk) — zf_kernel
//      retired. Coverage proof: pad ⊂ last surviving block's dst range. ----
__global__ __launch_bounds__(256) void kvproj_kernel(
    const bf16* __restrict__ xb, const bf16* __restrict__ Wall,
    const float* __restrict__ bk, const float* __restrict__ bv,
    const int* __restrict__ posv, const int* __restrict__ inv,
    bf16* __restrict__ kv) {
  __shared__ __align__(16) bf16 lW[64 * 64];
  __shared__ __align__(16) bf16 lXw[4][32 * 64];
  const int t = threadIdx.x, wave = t >> 6, lane = t & 63;
  const int quad = lane >> 4, c = lane & 15;
  const int bx = blockIdx.x;
  const int b_loc = bx >> 4, mb = bx & 15;
  const int nt = blockIdx.y;
  const int isV = nt >> 4, h = nt & 15;
  int v2 = posv[b_loc * SEQ + SEQ - 1];
  int nk = (v2 & 0x3FFFFFFF) + (v2 >= 0 ? 1 : 0);
  const int c0 = mb * 128;                   // compacted row base
  if (c0 >= nk) return;                      // block-uniform exit (pre-barrier)
  const bf16* W = Wall + (size_t)(1 + isV) * DMODEL * DMODEL + (size_t)(h * HDIM) * DMODEL;
  const float* bias = (isV ? bv : bk) + h * HDIM;
  bf16* pw = lXw[wave];
  const int sr = lane >> 3, sg = lane & 7;
  const int swzc = (sg ^ sr) * 8;
  const bf16* wS = W + (size_t)(wave * 8 + sr) * DMODEL + swzc;
  const int* invb = inv + b_loc * SEQ;
  int grow[4];
#pragma unroll
  for (int ii = 0; ii < 4; ++ii)
    grow[ii] = invb[c0 + wave * 32 + ii * 8 + sr];   // 0 for slots >= nk
  const bf16* xbb = xb + (size_t)b_loc * SEQ * DMODEL + swzc;
  f32x4 acc[2][4] = {};
  for (int k0 = 0; k0 < DMODEL; k0 += 64) {
    __syncthreads();
    gload_lds16(wS + k0, lW + wave * 512);
    gload_lds16(wS + 32 * DMODEL + k0, lW + wave * 512 + 2048);
#pragma unroll
    for (int ii = 0; ii < 4; ++ii)
      gload_lds16(xbb + (size_t)grow[ii] * DMODEL + k0, pw + ii * 512);
    __syncthreads();
#pragma unroll
    for (int kk = 0; kk < 2; ++kk) {
      bf16x8 af[2], bfr[4];
#pragma unroll
      for (int mi = 0; mi < 2; ++mi) {
        int row = mi * 16 + c;
        af[mi] = *(const bf16x8*)(pw + row * 64 + (((kk * 4 + quad) ^ (row & 7)) * 8));
      }
#pragma unroll
      for (int ni = 0; ni < 4; ++ni) {
        int row = ni * 16 + c;
        bfr[ni] = *(const bf16x8*)(lW + row * 64 + (((kk * 4 + quad) ^ (row & 7)) * 8));
      }
#pragma unroll
      for (int mi = 0; mi < 2; ++mi)
#pragma unroll
        for (int ni = 0; ni < 4; ++ni)
          acc[mi][ni] = __builtin_amdgcn_mfma_f32_16x16x32_bf16(af[mi], bfr[ni], acc[mi][ni], 0, 0, 0);
    }
  }
  bf16* base = kv + (size_t)(b_loc * NHEAD + h) * BHSTRIDE;
#pragma unroll
  for (int ni = 0; ni < 4; ++ni) {
    int hd = ni * 16 + c;
    float bv_ = bias[hd];
#pragma unroll
    for (int mi = 0; mi < 2; ++mi)
#pragma unroll
      for (int r = 0; r < 4; ++r) {
        int dst = c0 + wave * 32 + mi * 16 + quad * 4 + r;
        float val = (dst < nk) ? (acc[mi][ni][r] + bv_) : 0.0f;  // inline pad zero
        if (isV) base[SEQHD + (size_t)hd * SEQ + dst] = (bf16)val;
        else     base[(size_t)dst * HDIM + hd] = (bf16)val;
      }
  }
}

// ---- attention over COMPACTED keys (swapped QK^T; R11: LDS double-buffer,
//      ONE barrier per kt-iteration, staging issued at loop top so the full
//      iteration's compute hides the load latency). ----
__global__ __launch_bounds__(256, 4) void attn4_kernel(
    const bf16* __restrict__ Qall, const bf16* __restrict__ KV,
    const int* __restrict__ posv, bf16* __restrict__ O, int chunk) {
  __shared__ __align__(16) bf16 lK[2][64 * 64];
  __shared__ __align__(16) bf16 lV[2][64 * 64];
  __shared__ __align__(16) bf16 lPw[4][16 * 64];
  const int t = threadIdx.x, wave = t >> 6, lane = t & 63;
  const int quad = lane >> 4, c = lane & 15;
  const int i = blockIdx.x;                  // 0..1023
  const int xcd = i & 7, slot = i >> 3;      // slot 0..127
  const int bhl = xcd * 4 + (slot >> 5);     // 0..31, 4 bh per XCD
  const int qt = slot & 31;
  const int b_loc = bhl >> 4, h = bhl & 15;
  const int b = chunk * 2 + b_loc;
  const int q0 = qt * 64 + wave * 16;
  const bf16* Qh = Qall + (size_t)(b * NHEAD + h) * SEQHD;
  const bf16* Kb = KV + (size_t)(b_loc * NHEAD + h) * BHSTRIDE;
  const bf16* Vtb = Kb + SEQHD;
  bf16* pw = lPw[wave];

  int v2 = posv[b * SEQ + SEQ - 1];
  int nk = (v2 & 0x3FFFFFFF) + (v2 >= 0 ? 1 : 0);
  int NT = ((nk + 63) >> 6) << 6;

  const int srow = t >> 3;                              // 0..31
  const int sswz = (t & 7) ^ (srow & 7);
  const bf16* kSrc = Kb + (size_t)srow * HDIM + sswz * 8;
  const bf16* vSrc = Vtb + (size_t)srow * SEQ + sswz * 8;
  const int sOff = wave * 512;               // + buf*4096 + i2*2048 (HW adds lane*16B)

  bf16x8 qf[2];
#pragma unroll
  for (int kk = 0; kk < 2; ++kk)
    qf[kk] = *(const bf16x8*)(Qh + (size_t)(q0 + c) * HDIM + kk * 32 + quad * 8);

  f32x4 oacc[4] = {};
  float mrun = -1e30f, lrun = 0.0f;          // softmax state for q-row = q0 + c

  const int pbase = c * 64 + (quad & 1) * 4;
  const int pswz = c & 7;

  // prologue: stage tile 0 into buf 0
#pragma unroll
  for (int i2 = 0; i2 < 2; ++i2) {
    gload_lds16(kSrc + i2 * 32 * HDIM, &lK[0][0] + sOff + i2 * 2048);
    gload_lds16(vSrc + (size_t)i2 * 32 * SEQ, &lV[0][0] + sOff + i2 * 2048);
  }
  __syncthreads();

  int idx = 0;
  for (int kt = 0; kt < NT; kt += 64, idx ^= 1) {
    // stage next tile into buf^1 FIRST — whole iteration hides the latency
    if (kt + 64 < NT) {
      const bf16* ks = kSrc + (size_t)(kt + 64) * HDIM;
      const bf16* vs = vSrc + (kt + 64);
      bf16* kD = &lK[0][0] + (idx ^ 1) * 4096 + sOff;
      bf16* vD = &lV[0][0] + (idx ^ 1) * 4096 + sOff;
#pragma unroll
      for (int i2 = 0; i2 < 2; ++i2) {
        gload_lds16(ks + i2 * 32 * HDIM, kD + i2 * 2048);
        gload_lds16(vs + (size_t)i2 * 32 * SEQ, vD + i2 * 2048);
      }
    }
    const bf16* lKc = &lK[0][0] + idx * 4096;
    const bf16* lVc = &lV[0][0] + idx * 4096;

    // QK^T swapped: lane holds S^T[k][q=c], 16 P-values of ONE q-row
    f32x4 sacc[4] = {};
#pragma unroll
    for (int kk = 0; kk < 2; ++kk) {
      bf16x8 kf[4];
#pragma unroll
      for (int ni = 0; ni < 4; ++ni) {
        int row = ni * 16 + c;
        kf[ni] = *(const bf16x8*)(lKc + row * 64 + (((kk * 4 + quad) ^ (row & 7)) * 8));
      }
#pragma unroll
      for (int ni = 0; ni < 4; ++ni)
        sacc[ni] = __builtin_amdgcn_mfma_f32_16x16x32_bf16(kf[ni], qf[kk], sacc[ni], 0, 0, 0);
    }

    // tail-index masking on lane-local k = kt + ni*16 + quad*4 + r
    if (kt + 64 > nk) {
      int base = kt + quad * 4 - nk;
#pragma unroll
      for (int ni = 0; ni < 4; ++ni)
#pragma unroll
        for (int r = 0; r < 4; ++r)
          if (base + ni * 16 + r >= 0) sacc[ni][r] = -3e38f;
    }

    // row max for q = c: tree + cross-quad xor16/xor32
    float m1 = fmaxf(fmaxf(sacc[0][0], sacc[0][1]), sacc[0][2]);
    float m2 = fmaxf(fmaxf(sacc[0][3], sacc[1][0]), sacc[1][1]);
    float m3 = fmaxf(fmaxf(sacc[1][2], sacc[1][3]), sacc[2][0]);
    float m4 = fmaxf(fmaxf(sacc[2][1], sacc[2][2]), sacc[2][3]);
    float m5 = fmaxf(fmaxf(sacc[3][0], sacc[3][1]), sacc[3][2]);
    float mx = fmaxf(fmaxf(fmaxf(m1, m2), m3), fmaxf(fmaxf(m4, m5), sacc[3][3]));
    mx = fmaxf(mx, __shfl_xor(mx, 16));
    mx = fmaxf(mx, __shfl_xor(mx, 32));

    // defer-rescale (T13, THR=8 in exp2 domain -> P bounded by 256)
    if (!__all(mx - mrun <= 8.0f)) {
      float mn = fmaxf(mrun, mx);
      float al = __builtin_amdgcn_exp2f(mrun - mn);
      mrun = mn;
      lrun *= al;
      float al4[4];
#pragma unroll
      for (int r = 0; r < 4; ++r) al4[r] = __shfl(al, quad * 4 + r);
#pragma unroll
      for (int ni = 0; ni < 4; ++ni)
#pragma unroll
        for (int r = 0; r < 4; ++r) oacc[ni][r] *= al4[r];
    }

    float rs = 0.0f;
#pragma unroll
    for (int ni = 0; ni < 4; ++ni)
#pragma unroll
      for (int r = 0; r < 4; ++r) {
        float e = __builtin_amdgcn_exp2f(sacc[ni][r] - mrun);
        sacc[ni][r] = e; rs += e;
      }
    rs += __shfl_xor(rs, 16);
    rs += __shfl_xor(rs, 32);
    lrun += rs;

    // pack P pairs, one b64 store per ni
#pragma unroll
    for (int ni = 0; ni < 4; ++ni) {
      uint2 u;
      u.x = pk2(sacc[ni][0], sacc[ni][1]);
      u.y = pk2(sacc[ni][2], sacc[ni][3]);
      int sl = pbase + (((ni * 2 + (quad >> 1)) ^ pswz) * 8);
      *(uint2*)(pw + sl) = u;
    }

    // PV from lPw (own wave) and lV[idx]
#pragma unroll
    for (int kk = 0; kk < 2; ++kk) {
      bf16x8 pf, vfr[4];
      pf = *(const bf16x8*)(pw + c * 64 + (((kk * 4 + quad) ^ (c & 7)) * 8));
#pragma unroll
      for (int ni = 0; ni < 4; ++ni) {
        int row = ni * 16 + c;
        vfr[ni] = *(const bf16x8*)(lVc + row * 64 + (((kk * 4 + quad) ^ (row & 7)) * 8));
      }
#pragma unroll
      for (int ni = 0; ni < 4; ++ni)
        oacc[ni] = __builtin_amdgcn_mfma_f32_16x16x32_bf16(pf, vfr[ni], oacc[ni], 0, 0, 0);
    }

    // ONE barrier: drains this iter's staging (vmcnt0) and guarantees all
    // waves finished reading buf[idx] before next iter's staging overwrites it
    __syncthreads();
  }

  // epilogue: 1/l broadcast from q=c layout to q=quad*4+r layout
  float linv = lrun > 0.0f ? 1.0f / lrun : 0.0f;
  float linv4[4];
#pragma unroll
  for (int r = 0; r < 4; ++r) linv4[r] = __shfl(linv, quad * 4 + r);
#pragma unroll
  for (int r = 0; r < 4; ++r) {
    size_t tok = (size_t)b * SEQ + q0 + quad * 4 + r;
#pragma unroll
    for (int ni = 0; ni < 4; ++ni)
      O[tok * DMODEL + h * HDIM + ni * 16 + c] = (bf16)(oacc[ni][r] * linv4[r]);
  }
}

// ---- output projection: out = O*Wo^T + bo (fp32). 128-row M-tiles. ----
__global__ __launch_bounds__(256) void outproj_kernel(
    const bf16* __restrict__ O, const bf16* __restrict__ Wob,
    const float* __restrict__ bo, float* __restrict__ out) {
  __shared__ __align__(16) bf16 lW[64 * 64];
  __shared__ __align__(16) bf16 lXw[4][32 * 64];
  const int t = threadIdx.x, wave = t >> 6, lane = t & 63;
  const int quad = lane >> 4, c = lane & 15;
  const int m0 = blockIdx.x * 128;           // token rows
  const int n0 = blockIdx.y * 64;            // output cols
  bf16* pw = lXw[wave];
  const int sr = lane >> 3, sg = lane & 7;
  const bf16* aS = O + (size_t)(m0 + wave * 32 + sr) * DMODEL + ((sg ^ sr) * 8);
  const bf16* wS = Wob + (size_t)(n0 + wave * 8 + sr) * DMODEL + ((sg ^ sr) * 8);
  f32x4 acc[2][4] = {};
  for (int k0 = 0; k0 < DMODEL; k0 += 64) {
    __syncthreads();
    gload_lds16(wS + k0, lW + wave * 512);
    gload_lds16(wS + 32 * DMODEL + k0, lW + wave * 512 + 2048);
#pragma unroll
    for (int ii = 0; ii < 4; ++ii)
      gload_lds16(aS + k0 + (size_t)ii * 8 * DMODEL, pw + ii * 512);
    __syncthreads();
#pragma unroll
    for (int kk = 0; kk < 2; ++kk) {
      bf16x8 af[2], bfr[4];
#pragma unroll
      for (int mi = 0; mi < 2; ++mi) {
        int row = mi * 16 + c;
        af[mi] = *(const bf16x8*)(pw + row * 64 + (((kk * 4 + quad) ^ (row & 7)) * 8));
      }
#pragma unroll
      for (int ni = 0; ni < 4; ++ni) {
        int row = ni * 16 + c;
        bfr[ni] = *(const bf16x8*)(lW + row * 64 + (((kk * 4 + quad) ^ (row & 7)) * 8));
      }
#pragma unroll
      for (int mi = 0; mi < 2; ++mi)
#pragma unroll
        for (int ni = 0; ni < 4; ++ni)
          acc[mi][ni] = __builtin_amdgcn_mfma_f32_16x16x32_bf16(af[mi], bfr[ni], acc[mi][ni], 0, 0, 0);
    }
  }
#pragma unroll
  for (int ni = 0; ni < 4; ++ni) {
    int gn = n0 + ni * 16 + c;
    float bv_ = bo[gn];
#pragma unroll
    for (int mi = 0; mi < 2; ++mi)
#pragma unroll
      for (int r = 0; r < 4; ++r) {
        int gm = m0 + wave * 32 + mi * 16 + quad * 4 + r;
        out[(size_t)gm * DMODEL + gn] = acc[mi][ni][r] + bv_;
      }
  }
}

extern "C" void kernel_launch(void* const* d_in, const int* in_sizes, int n_in,
                              void* d_out, int out_size, void* d_ws, size_t ws_size,
                              hipStream_t stream) {
  const float* x  = (const float*)d_in[0];
  int*         posv = (int*)d_in[1];                 // mask -> compacted pos (in place)
  const float* Wq = (const float*)d_in[2]; const float* bq = (const float*)d_in[3];
  const float* Wk = (const float*)d_in[4]; const float* bk = (const float*)d_in[5];
  const float* Wv = (const float*)d_in[6]; const float* bv = (const float*)d_in[7];
  const float* Wo = (const float*)d_in[8]; const float* bo = (const float*)d_in[9];
  float* out = (float*)d_out;
  char* outc = (char*)d_out;
  char* xc   = (char*)d_in[0];
  const size_t half = (size_t)NBATCH * SEQ * DMODEL * 2;  // 16,777,216 B
  const size_t qtr  = half / 2;                            // 8,388,608 B

  // Regions (16.78 MB each): R0=d_out.lo R1=d_out.hi R2=x.lo R3=x.hi
  //   cvt_x:   x(R2∪R3) -> xbf(R1)               [x fp32 dead after this]
  //   prep:    Wq/Wk/Wv -> Wbf3(R3.hi); scan posv in place + inv (R3.hi tail)
  //            [after cvt_x: Wbf3 and inv overlap fp32 x — R8 lesson]
  //   qproj:   xbf,Wbf3 -> Qall(R0)
  //   kvproj0: xbf.lo gather(inv) -> KV(R2), pad zeroed inline
  //   attn_A:  Qall.lo,KV -> O.lo(R3.lo)
  //   kvproj1: xbf.hi gather(inv) -> KV(R2), pad zeroed inline
  //   attn_B:  Qall.hi,KV -> O.hi(R3.hi)         [overwrites dead Wbf3+inv]
  //   cvt_wo:  Wo -> Wobf(R2)                    [KV dead]
  //   outproj: O(R3),Wobf(R2) -> out(R0∪R1)
  bf16* Qall = (bf16*)d_out;
  bf16* xbf  = (bf16*)(outc + half);
  bf16* KV   = (bf16*)xc;
  bf16* O    = (bf16*)(xc + half);
  bf16* Wbf3 = (bf16*)(xc + half + qtr);
  int*  inv  = (int*)(xc + half + qtr + (size_t)3 * DMODEL * DMODEL * 2);
  bf16* Wobf = (bf16*)xc;

  cvt_kernel<<<dim3(2048), 256, 0, stream>>>(x, xbf);
  prep_kernel<<<dim3(772), 256, 0, stream>>>(Wq, Wk, Wv, Wbf3, posv, inv);
  qproj_kernel<<<dim3(64, 16), 256, 0, stream>>>(xbf, Wbf3, bq, Qall);
  kvproj_kernel<<<dim3(32, 32), 256, 0, stream>>>(xbf, Wbf3, bk, bv, posv, inv, KV);
  attn4_kernel<<<dim3(1024), 256, 0, stream>>>(Qall, KV, posv, O, 0);
  kvproj_kernel<<<dim3(32, 32), 256, 0, stream>>>(xbf + (size_t)2 * SEQ * DMODEL, Wbf3, bk, bv,
                                                  posv + 2 * SEQ, inv + 2 * SEQ, KV);
  attn4_kernel<<<dim3(1024), 256, 0, stream>>>(Qall, KV, posv, O, 1);
  cvt_kernel<<<dim3(256), 256, 0, stream>>>(Wo, Wobf);
  outproj_kernel<<<dim3(64, 16), 256, 0, stream>>>(O, Wobf, bo, out);
}

// Round 12
// 276.146 us; speedup vs baseline: 3.2161x; 1.0423x over previous
//
#include <hip/hip_runtime.h>
#include <stdint.h>

typedef __bf16 bf16;
typedef __bf16 bf16x8 __attribute__((ext_vector_type(8)));
typedef float f32x4 __attribute__((ext_vector_type(4)));

#define SEQ 2048
#define NHEAD 16
#define HDIM 64
#define DMODEL 1024
#define NBATCH 4
// 0.125 * log2(e): softmax runs in exp2 domain
#define ATT_SCALE 0.18033688011112042f
#define SEQHD (SEQ * HDIM)          // 131072
#define BHSTRIDE (2 * SEQHD)        // per-(b,h): K tile then V^T tile

// LDS slot invariant: L[row*64 + ((blk ^ (row&7))*8) + off] = SRC[row][blk*8+off]

__device__ __forceinline__ void gload_lds16(const bf16* g, bf16* l) {
  __builtin_amdgcn_global_load_lds(
      (const __attribute__((address_space(1))) uint32_t*)g,
      (__attribute__((address_space(3))) uint32_t*)l, 16, 0, 0);
}

__device__ __forceinline__ uint32_t pk2(float a, float b) {
  bf16 x = (bf16)a, y = (bf16)b;
  return (uint32_t)__builtin_bit_cast(uint16_t, x) |
         ((uint32_t)__builtin_bit_cast(uint16_t, y) << 16);
}

// ---- fp32 -> bf16 conversion (memory-bound pre-pass), 16 elems/thread ----
__global__ __launch_bounds__(256) void cvt_kernel(const float* __restrict__ src,
                                                  bf16* __restrict__ dst) {
  size_t i = ((size_t)blockIdx.x * 256 + threadIdx.x) * 16;
#pragma unroll
  for (int j = 0; j < 2; ++j) {
    float4 f0 = *(const float4*)(src + i + j * 8);
    float4 f1 = *(const float4*)(src + i + j * 8 + 4);
    bf16x8 v;
    v[0] = (bf16)f0.x; v[1] = (bf16)f0.y; v[2] = (bf16)f0.z; v[3] = (bf16)f0.w;
    v[4] = (bf16)f1.x; v[5] = (bf16)f1.y; v[6] = (bf16)f1.z; v[7] = (bf16)f1.w;
    *(bf16x8*)(dst + i + j * 8) = v;
  }
}

// ---- merged prep: blocks 0..767 convert Wq/Wk/Wv -> Wbf3; blocks 768..771
//      run the mask scan (posv in place, idempotent) + emit inv[b][pos]=s.
//      MUST run after cvt_x (Wbf3 and inv live in the then-dead fp32 x region). ----
__global__ __launch_bounds__(256) void prep_kernel(
    const float* __restrict__ Wq, const float* __restrict__ Wk,
    const float* __restrict__ Wv, bf16* __restrict__ Wbf3,
    int* __restrict__ posv, int* __restrict__ inv) {
  __shared__ int sums[256];
  const int bx = blockIdx.x, t = threadIdx.x;
  if (bx < 768) {
    const float* s = bx < 256 ? Wq : (bx < 512 ? Wk : Wv);
    bf16* d = Wbf3 + (size_t)(bx >> 8) * DMODEL * DMODEL;
    size_t i = ((size_t)(bx & 255) * 256 + t) * 16;
#pragma unroll
    for (int j = 0; j < 2; ++j) {
      float4 f0 = *(const float4*)(s + i + j * 8);
      float4 f1 = *(const float4*)(s + i + j * 8 + 4);
      bf16x8 v;
      v[0] = (bf16)f0.x; v[1] = (bf16)f0.y; v[2] = (bf16)f0.z; v[3] = (bf16)f0.w;
      v[4] = (bf16)f1.x; v[5] = (bf16)f1.y; v[6] = (bf16)f1.z; v[7] = (bf16)f1.w;
      *(bf16x8*)(d + i + j * 8) = v;
    }
    return;
  }
  const int b = bx - 768;
  int* m = posv + b * SEQ;
  int* iv = inv + b * SEQ;
  int f[8], cnt = 0;
#pragma unroll
  for (int j = 0; j < 8; ++j) {
    int x = m[t * 8 + j];
    int unm = (x < 0) ? 0 : ((x & 0x40000000) ? 1 : (x == 0 ? 1 : 0));
    f[j] = unm; cnt += unm;
    iv[t * 8 + j] = 0;                       // memset inv (scatter after barrier)
  }
  sums[t] = cnt;
  __syncthreads();
  if (t == 0) {
    int acc = 0;
#pragma unroll 8
    for (int i = 0; i < 256; ++i) { int s = sums[i]; sums[i] = acc; acc += s; }
  }
  __syncthreads();
  int p = sums[t];
#pragma unroll
  for (int j = 0; j < 8; ++j) {
    m[t * 8 + j] = (int)((f[j] ? 0x40000000u : 0x80000000u) | (unsigned)p);
    if (f[j]) iv[p] = t * 8 + j;
    p += f[j];
  }
}

// ---- mega launch (R12): qproj(all 4 batches) + kvproj(chunk 0) + cvt of Wo,
//      all independent (read xbf/Wbf3/Wo only), merged so kvproj's early-exit
//      blocks and the tiny cvt backfill CUs while qproj runs.
//      blocks [0,1024): qproj; [1024,2048): kvproj chunk0; [2048,2304): Wo cvt.
//      Wobf lives in d_in[2] (fp32 Wq, dead after prep). ----
__global__ __launch_bounds__(256) void mega_kernel(
    const bf16* __restrict__ xb, const bf16* __restrict__ Wall,
    const float* __restrict__ bq, const float* __restrict__ bk,
    const float* __restrict__ bv, const int* __restrict__ posv,
    const int* __restrict__ inv, bf16* __restrict__ Qall,
    bf16* __restrict__ kv, const float* __restrict__ Wo,
    bf16* __restrict__ Wobf) {
  __shared__ __align__(16) bf16 lW[64 * 64];
  __shared__ __align__(16) bf16 lXw[4][32 * 64];
  const int bx = blockIdx.x;
  const int t = threadIdx.x, wave = t >> 6, lane = t & 63;
  const int quad = lane >> 4, c = lane & 15;
  const int sr = lane >> 3, sg = lane & 7;
  const int swzc = (sg ^ sr) * 8;

  if (bx >= 2048) {                          // ---- Wo fp32 -> bf16 ----
    size_t i = ((size_t)(bx - 2048) * 256 + t) * 16;
#pragma unroll
    for (int j = 0; j < 2; ++j) {
      float4 f0 = *(const float4*)(Wo + i + j * 8);
      float4 f1 = *(const float4*)(Wo + i + j * 8 + 4);
      bf16x8 v;
      v[0] = (bf16)f0.x; v[1] = (bf16)f0.y; v[2] = (bf16)f0.z; v[3] = (bf16)f0.w;
      v[4] = (bf16)f1.x; v[5] = (bf16)f1.y; v[6] = (bf16)f1.z; v[7] = (bf16)f1.w;
      *(bf16x8*)(Wobf + i + j * 8) = v;
    }
    return;
  }

  if (bx < 1024) {                           // ---- qproj ----
    const int m0 = (bx & 63) * 128;          // token rows 0..8191
    const int h = bx >> 6;
    const bf16* W = Wall + (size_t)(h * HDIM) * DMODEL;
    bf16* pw = lXw[wave];
    const bf16* aS = xb + (size_t)(m0 + wave * 32 + sr) * DMODEL + swzc;
    const bf16* wS = W + (size_t)(wave * 8 + sr) * DMODEL + swzc;
    f32x4 acc[2][4] = {};
    for (int k0 = 0; k0 < DMODEL; k0 += 64) {
      __syncthreads();
      gload_lds16(wS + k0, lW + wave * 512);
      gload_lds16(wS + 32 * DMODEL + k0, lW + wave * 512 + 2048);
#pragma unroll
      for (int ii = 0; ii < 4; ++ii)
        gload_lds16(aS + k0 + (size_t)ii * 8 * DMODEL, pw + ii * 512);
      __syncthreads();
#pragma unroll
      for (int kk = 0; kk < 2; ++kk) {
        bf16x8 af[2], bfr[4];
#pragma unroll
        for (int mi = 0; mi < 2; ++mi) {
          int row = mi * 16 + c;
          af[mi] = *(const bf16x8*)(pw + row * 64 + (((kk * 4 + quad) ^ (row & 7)) * 8));
        }
#pragma unroll
        for (int ni = 0; ni < 4; ++ni) {
          int row = ni * 16 + c;
          bfr[ni] = *(const bf16x8*)(lW + row * 64 + (((kk * 4 + quad) ^ (row & 7)) * 8));
        }
#pragma unroll
        for (int mi = 0; mi < 2; ++mi)
#pragma unroll
          for (int ni = 0; ni < 4; ++ni)
            acc[mi][ni] = __builtin_amdgcn_mfma_f32_16x16x32_bf16(af[mi], bfr[ni], acc[mi][ni], 0, 0, 0);
      }
    }
#pragma unroll
    for (int ni = 0; ni < 4; ++ni) {
      int hd = ni * 16 + c;
      float bqv = bq[h * HDIM + hd];
#pragma unroll
      for (int mi = 0; mi < 2; ++mi)
#pragma unroll
        for (int r = 0; r < 4; ++r) {
          int tok = m0 + wave * 32 + mi * 16 + quad * 4 + r;
          int b = tok >> 11, s = tok & 2047;
          Qall[((size_t)(b * NHEAD + h) * SEQ + s) * HDIM + hd] =
              (bf16)((acc[mi][ni][r] + bqv) * ATT_SCALE);
        }
    }
    return;
  }

  // ---- kvproj chunk 0 (batches 0,1), compacted rows, inline pad zero ----
  const int idx = bx - 1024;                 // 0..1023
  const int xi = idx & 31, yi = idx >> 5;
  const int b_loc = xi >> 4, mb = xi & 15;
  const int isV = yi >> 4, h = yi & 15;
  int v2 = posv[b_loc * SEQ + SEQ - 1];
  int nk = (v2 & 0x3FFFFFFF) + (v2 >= 0 ? 1 : 0);
  const int c0 = mb * 128;                   // compacted row base
  if (c0 >= nk) return;                      // block-uniform exit (pre-barrier)
  const bf16* W = Wall + (size_t)(1 + isV) * DMODEL * DMODEL + (size_t)(h * HDIM) * DMODEL;
  const float* bias = (isV ? bv : bk) + h * HDIM;
  bf16* pw = lXw[wave];
  const bf16* wS = W + (size_t)(wave * 8 + sr) * DMODEL + swzc;
  const int* invb = inv + b_loc * SEQ;
  int grow[4];
#pragma unroll
  for (int ii = 0; ii < 4; ++ii)
    grow[ii] = invb[c0 + wave * 32 + ii * 8 + sr];   // 0 for slots >= nk
  const bf16* xbb = xb + (size_t)b_loc * SEQ * DMODEL + swzc;
  f32x4 acc[2][4] = {};
  for (int k0 = 0; k0 < DMODEL; k0 += 64) {
    __syncthreads();
    gload_lds16(wS + k0, lW + wave * 512);
    gload_lds16(wS + 32 * DMODEL + k0, lW + wave * 512 + 2048);
#pragma unroll
    for (int ii = 0; ii < 4; ++ii)
      gload_lds16(xbb + (size_t)grow[ii] * DMODEL + k0, pw + ii * 512);
    __syncthreads();
#pragma unroll
    for (int kk = 0; kk < 2; ++kk) {
      bf16x8 af[2], bfr[4];
#pragma unroll
      for (int mi = 0; mi < 2; ++mi) {
        int row = mi * 16 + c;
        af[mi] = *(const bf16x8*)(pw + row * 64 + (((kk * 4 + quad) ^ (row & 7)) * 8));
      }
#pragma unroll
      for (int ni = 0; ni < 4; ++ni) {
        int row = ni * 16 + c;
        bfr[ni] = *(const bf16x8*)(lW + row * 64 + (((kk * 4 + quad) ^ (row & 7)) * 8));
      }
#pragma unroll
      for (int mi = 0; mi < 2; ++mi)
#pragma unroll
        for (int ni = 0; ni < 4; ++ni)
          acc[mi][ni] = __builtin_amdgcn_mfma_f32_16x16x32_bf16(af[mi], bfr[ni], acc[mi][ni], 0, 0, 0);
    }
  }
  bf16* base = kv + (size_t)(b_loc * NHEAD + h) * BHSTRIDE;
#pragma unroll
  for (int ni = 0; ni < 4; ++ni) {
    int hd = ni * 16 + c;
    float bv_ = bias[hd];
#pragma unroll
    for (int mi = 0; mi < 2; ++mi)
#pragma unroll
      for (int r = 0; r < 4; ++r) {
        int dst = c0 + wave * 32 + mi * 16 + quad * 4 + r;
        float val = (dst < nk) ? (acc[mi][ni][r] + bv_) : 0.0f;  // inline pad zero
        if (isV) base[SEQHD + (size_t)hd * SEQ + dst] = (bf16)val;
        else     base[(size_t)dst * HDIM + hd] = (bf16)val;
      }
  }
}

// ---- K/V projection over COMPACTED rows, 128-row tiles (chunk 1). ----
__global__ __launch_bounds__(256) void kvproj_kernel(
    const bf16* __restrict__ xb, const bf16* __restrict__ Wall,
    const float* __restrict__ bk, const float* __restrict__ bv,
    const int* __restrict__ posv, const int* __restrict__ inv,
    bf16* __restrict__ kv) {
  __shared__ __align__(16) bf16 lW[64 * 64];
  __shared__ __align__(16) bf16 lXw[4][32 * 64];
  const int t = threadIdx.x, wave = t >> 6, lane = t & 63;
  const int quad = lane >> 4, c = lane & 15;
  const int bx = blockIdx.x;
  const int b_loc = bx >> 4, mb = bx & 15;
  const int nt = blockIdx.y;
  const int isV = nt >> 4, h = nt & 15;
  int v2 = posv[b_loc * SEQ + SEQ - 1];
  int nk = (v2 & 0x3FFFFFFF) + (v2 >= 0 ? 1 : 0);
  const int c0 = mb * 128;                   // compacted row base
  if (c0 >= nk) return;                      // block-uniform exit (pre-barrier)
  const bf16* W = Wall + (size_t)(1 + isV) * DMODEL * DMODEL + (size_t)(h * HDIM) * DMODEL;
  const float* bias = (isV ? bv : bk) + h * HDIM;
  bf16* pw = lXw[wave];
  const int sr = lane >> 3, sg = lane & 7;
  const int swzc = (sg ^ sr) * 8;
  const bf16* wS = W + (size_t)(wave * 8 + sr) * DMODEL + swzc;
  const int* invb = inv + b_loc * SEQ;
  int grow[4];
#pragma unroll
  for (int ii = 0; ii < 4; ++ii)
    grow[ii] = invb[c0 + wave * 32 + ii * 8 + sr];   // 0 for slots >= nk
  const bf16* xbb = xb + (size_t)b_loc * SEQ * DMODEL + swzc;
  f32x4 acc[2][4] = {};
  for (int k0 = 0; k0 < DMODEL; k0 += 64) {
    __syncthreads();
    gload_lds16(wS + k0, lW + wave * 512);
    gload_lds16(wS + 32 * DMODEL + k0, lW + wave * 512 + 2048);
#pragma unroll
    for (int ii = 0; ii < 4; ++ii)
      gload_lds16(xbb + (size_t)grow[ii] * DMODEL + k0, pw + ii * 512);
    __syncthreads();
#pragma unroll
    for (int kk = 0; kk < 2; ++kk) {
      bf16x8 af[2], bfr[4];
#pragma unroll
      for (int mi = 0; mi < 2; ++mi) {
        int row = mi * 16 + c;
        af[mi] = *(const bf16x8*)(pw + row * 64 + (((kk * 4 + quad) ^ (row & 7)) * 8));
      }
#pragma unroll
      for (int ni = 0; ni < 4; ++ni) {
        int row = ni * 16 + c;
        bfr[ni] = *(const bf16x8*)(lW + row * 64 + (((kk * 4 + quad) ^ (row & 7)) * 8));
      }
#pragma unroll
      for (int mi = 0; mi < 2; ++mi)
#pragma unroll
        for (int ni = 0; ni < 4; ++ni)
          acc[mi][ni] = __builtin_amdgcn_mfma_f32_16x16x32_bf16(af[mi], bfr[ni], acc[mi][ni], 0, 0, 0);
    }
  }
  bf16* base = kv + (size_t)(b_loc * NHEAD + h) * BHSTRIDE;
#pragma unroll
  for (int ni = 0; ni < 4; ++ni) {
    int hd = ni * 16 + c;
    float bv_ = bias[hd];
#pragma unroll
    for (int mi = 0; mi < 2; ++mi)
#pragma unroll
      for (int r = 0; r < 4; ++r) {
        int dst = c0 + wave * 32 + mi * 16 + quad * 4 + r;
        float val = (dst < nk) ? (acc[mi][ni][r] + bv_) : 0.0f;  // inline pad zero
        if (isV) base[SEQHD + (size_t)hd * SEQ + dst] = (bf16)val;
        else     base[(size_t)dst * HDIM + hd] = (bf16)val;
      }
  }
}

// ---- attention over COMPACTED keys (swapped QK^T; dbuf, 1 barrier/iter;
//      R12: s_setprio(1) around MFMA clusters — T5, attn-positive per m191). ----
__global__ __launch_bounds__(256, 4) void attn4_kernel(
    const bf16* __restrict__ Qall, const bf16* __restrict__ KV,
    const int* __restrict__ posv, bf16* __restrict__ O, int chunk) {
  __shared__ __align__(16) bf16 lK[2][64 * 64];
  __shared__ __align__(16) bf16 lV[2][64 * 64];
  __shared__ __align__(16) bf16 lPw[4][16 * 64];
  const int t = threadIdx.x, wave = t >> 6, lane = t & 63;
  const int quad = lane >> 4, c = lane & 15;
  const int i = blockIdx.x;                  // 0..1023
  const int xcd = i & 7, slot = i >> 3;      // slot 0..127
  const int bhl = xcd * 4 + (slot >> 5);     // 0..31, 4 bh per XCD
  const int qt = slot & 31;
  const int b_loc = bhl >> 4, h = bhl & 15;
  const int b = chunk * 2 + b_loc;
  const int q0 = qt * 64 + wave * 16;
  const bf16* Qh = Qall + (size_t)(b * NHEAD + h) * SEQHD;
  const bf16* Kb = KV + (size_t)(b_loc * NHEAD + h) * BHSTRIDE;
  const bf16* Vtb = Kb + SEQHD;
  bf16* pw = lPw[wave];

  int v2 = posv[b * SEQ + SEQ - 1];
  int nk = (v2 & 0x3FFFFFFF) + (v2 >= 0 ? 1 : 0);
  int NT = ((nk + 63) >> 6) << 6;

  const int srow = t >> 3;                              // 0..31
  const int sswz = (t & 7) ^ (srow & 7);
  const bf16* kSrc = Kb + (size_t)srow * HDIM + sswz * 8;
  const bf16* vSrc = Vtb + (size_t)srow * SEQ + sswz * 8;
  const int sOff = wave * 512;               // + buf*4096 + i2*2048 (HW adds lane*16B)

  bf16x8 qf[2];
#pragma unroll
  for (int kk = 0; kk < 2; ++kk)
    qf[kk] = *(const bf16x8*)(Qh + (size_t)(q0 + c) * HDIM + kk * 32 + quad * 8);

  f32x4 oacc[4] = {};
  float mrun = -1e30f, lrun = 0.0f;          // softmax state for q-row = q0 + c

  const int pbase = c * 64 + (quad & 1) * 4;
  const int pswz = c & 7;

  // prologue: stage tile 0 into buf 0
#pragma unroll
  for (int i2 = 0; i2 < 2; ++i2) {
    gload_lds16(kSrc + i2 * 32 * HDIM, &lK[0][0] + sOff + i2 * 2048);
    gload_lds16(vSrc + (size_t)i2 * 32 * SEQ, &lV[0][0] + sOff + i2 * 2048);
  }
  __syncthreads();

  int idx = 0;
  for (int kt = 0; kt < NT; kt += 64, idx ^= 1) {
    // stage next tile into buf^1 FIRST — whole iteration hides the latency
    if (kt + 64 < NT) {
      const bf16* ks = kSrc + (size_t)(kt + 64) * HDIM;
      const bf16* vs = vSrc + (kt + 64);
      bf16* kD = &lK[0][0] + (idx ^ 1) * 4096 + sOff;
      bf16* vD = &lV[0][0] + (idx ^ 1) * 4096 + sOff;
#pragma unroll
      for (int i2 = 0; i2 < 2; ++i2) {
        gload_lds16(ks + i2 * 32 * HDIM, kD + i2 * 2048);
        gload_lds16(vs + (size_t)i2 * 32 * SEQ, vD + i2 * 2048);
      }
    }
    const bf16* lKc = &lK[0][0] + idx * 4096;
    const bf16* lVc = &lV[0][0] + idx * 4096;

    // QK^T swapped: lane holds S^T[k][q=c], 16 P-values of ONE q-row
    f32x4 sacc[4] = {};
    __builtin_amdgcn_s_setprio(1);
#pragma unroll
    for (int kk = 0; kk < 2; ++kk) {
      bf16x8 kf[4];
#pragma unroll
      for (int ni = 0; ni < 4; ++ni) {
        int row = ni * 16 + c;
        kf[ni] = *(const bf16x8*)(lKc + row * 64 + (((kk * 4 + quad) ^ (row & 7)) * 8));
      }
#pragma unroll
      for (int ni = 0; ni < 4; ++ni)
        sacc[ni] = __builtin_amdgcn_mfma_f32_16x16x32_bf16(kf[ni], qf[kk], sacc[ni], 0, 0, 0);
    }
    __builtin_amdgcn_s_setprio(0);

    // tail-index masking on lane-local k = kt + ni*16 + quad*4 + r
    if (kt + 64 > nk) {
      int base = kt + quad * 4 - nk;
#pragma unroll
      for (int ni = 0; ni < 4; ++ni)
#pragma unroll
        for (int r = 0; r < 4; ++r)
          if (base + ni * 16 + r >= 0) sacc[ni][r] = -3e38f;
    }

    // row max for q = c: tree + cross-quad xor16/xor32
    float m1 = fmaxf(fmaxf(sacc[0][0], sacc[0][1]), sacc[0][2]);
    float m2 = fmaxf(fmaxf(sacc[0][3], sacc[1][0]), sacc[1][1]);
    float m3 = fmaxf(fmaxf(sacc[1][2], sacc[1][3]), sacc[2][0]);
    float m4 = fmaxf(fmaxf(sacc[2][1], sacc[2][2]), sacc[2][3]);
    float m5 = fmaxf(fmaxf(sacc[3][0], sacc[3][1]), sacc[3][2]);
    float mx = fmaxf(fmaxf(fmaxf(m1, m2), m3), fmaxf(fmaxf(m4, m5), sacc[3][3]));
    mx = fmaxf(mx, __shfl_xor(mx, 16));
    mx = fmaxf(mx, __shfl_xor(mx, 32));

    // defer-rescale (T13, THR=8 in exp2 domain -> P bounded by 256)
    if (!__all(mx - mrun <= 8.0f)) {
      float mn = fmaxf(mrun, mx);
      float al = __builtin_amdgcn_exp2f(mrun - mn);
      mrun = mn;
      lrun *= al;
      float al4[4];
#pragma unroll
      for (int r = 0; r < 4; ++r) al4[r] = __shfl(al, quad * 4 + r);
#pragma unroll
      for (int ni = 0; ni < 4; ++ni)
#pragma unroll
        for (int r = 0; r < 4; ++r) oacc[ni][r] *= al4[r];
    }

    float rs = 0.0f;
#pragma unroll
    for (int ni = 0; ni < 4; ++ni)
#pragma unroll
      for (int r = 0; r < 4; ++r) {
        float e = __builtin_amdgcn_exp2f(sacc[ni][r] - mrun);
        sacc[ni][r] = e; rs += e;
      }
    rs += __shfl_xor(rs, 16);
    rs += __shfl_xor(rs, 32);
    lrun += rs;

    // pack P pairs, one b64 store per ni
#pragma unroll
    for (int ni = 0; ni < 4; ++ni) {
      uint2 u;
      u.x = pk2(sacc[ni][0], sacc[ni][1]);
      u.y = pk2(sacc[ni][2], sacc[ni][3]);
      int sl = pbase + (((ni * 2 + (quad >> 1)) ^ pswz) * 8);
      *(uint2*)(pw + sl) = u;
    }

    // PV from lPw (own wave) and lV[idx]
    __builtin_amdgcn_s_setprio(1);
#pragma unroll
    for (int kk = 0; kk < 2; ++kk) {
      bf16x8 pf, vfr[4];
      pf = *(const bf16x8*)(pw + c * 64 + (((kk * 4 + quad) ^ (c & 7)) * 8));
#pragma unroll
      for (int ni = 0; ni < 4; ++ni) {
        int row = ni * 16 + c;
        vfr[ni] = *(const bf16x8*)(lVc + row * 64 + (((kk * 4 + quad) ^ (row & 7)) * 8));
      }
#pragma unroll
      for (int ni = 0; ni < 4; ++ni)
        oacc[ni] = __builtin_amdgcn_mfma_f32_16x16x32_bf16(pf, vfr[ni], oacc[ni], 0, 0, 0);
    }
    __builtin_amdgcn_s_setprio(0);

    // ONE barrier: drains this iter's staging (vmcnt0) and guarantees all
    // waves finished reading buf[idx] before next iter's staging overwrites it
    __syncthreads();
  }

  // epilogue: 1/l broadcast from q=c layout to q=quad*4+r layout
  float linv = lrun > 0.0f ? 1.0f / lrun : 0.0f;
  float linv4[4];
#pragma unroll
  for (int r = 0; r < 4; ++r) linv4[r] = __shfl(linv, quad * 4 + r);
#pragma unroll
  for (int r = 0; r < 4; ++r) {
    size_t tok = (size_t)b * SEQ + q0 + quad * 4 + r;
#pragma unroll
    for (int ni = 0; ni < 4; ++ni)
      O[tok * DMODEL + h * HDIM + ni * 16 + c] = (bf16)(oacc[ni][r] * linv4[r]);
  }
}

// ---- output projection: out = O*Wo^T + bo (fp32). 128-row M-tiles. ----
__global__ __launch_bounds__(256) void outproj_kernel(
    const bf16* __restrict__ O, const bf16* __restrict__ Wob,
    const float* __restrict__ bo, float* __restrict__ out) {
  __shared__ __align__(16) bf16 lW[64 * 64];
  __shared__ __align__(16) bf16 lXw[4][32 * 64];
  const int t = threadIdx.x, wave = t >> 6, lane = t & 63;
  const int quad = lane >> 4, c = lane & 15;
  const int m0 = blockIdx.x * 128;           // token rows
  const int n0 = blockIdx.y * 64;            // output cols
  bf16* pw = lXw[wave];
  const int sr = lane >> 3, sg = lane & 7;
  const bf16* aS = O + (size_t)(m0 + wave * 32 + sr) * DMODEL + ((sg ^ sr) * 8);
  const bf16* wS = Wob + (size_t)(n0 + wave * 8 + sr) * DMODEL + ((sg ^ sr) * 8);
  f32x4 acc[2][4] = {};
  for (int k0 = 0; k0 < DMODEL; k0 += 64) {
    __syncthreads();
    gload_lds16(wS + k0, lW + wave * 512);
    gload_lds16(wS + 32 * DMODEL + k0, lW + wave * 512 + 2048);
#pragma unroll
    for (int ii = 0; ii < 4; ++ii)
      gload_lds16(aS + k0 + (size_t)ii * 8 * DMODEL, pw + ii * 512);
    __syncthreads();
#pragma unroll
    for (int kk = 0; kk < 2; ++kk) {
      bf16x8 af[2], bfr[4];
#pragma unroll
      for (int mi = 0; mi < 2; ++mi) {
        int row = mi * 16 + c;
        af[mi] = *(const bf16x8*)(pw + row * 64 + (((kk * 4 + quad) ^ (row & 7)) * 8));
      }
#pragma unroll
      for (int ni = 0; ni < 4; ++ni) {
        int row = ni * 16 + c;
        bfr[ni] = *(const bf16x8*)(lW + row * 64 + (((kk * 4 + quad) ^ (row & 7)) * 8));
      }
#pragma unroll
      for (int mi = 0; mi < 2; ++mi)
#pragma unroll
        for (int ni = 0; ni < 4; ++ni)
          acc[mi][ni] = __builtin_amdgcn_mfma_f32_16x16x32_bf16(af[mi], bfr[ni], acc[mi][ni], 0, 0, 0);
    }
  }
#pragma unroll
  for (int ni = 0; ni < 4; ++ni) {
    int gn = n0 + ni * 16 + c;
    float bv_ = bo[gn];
#pragma unroll
    for (int mi = 0; mi < 2; ++mi)
#pragma unroll
      for (int r = 0; r < 4; ++r) {
        int gm = m0 + wave * 32 + mi * 16 + quad * 4 + r;
        out[(size_t)gm * DMODEL + gn] = acc[mi][ni][r] + bv_;
      }
  }
}

extern "C" void kernel_launch(void* const* d_in, const int* in_sizes, int n_in,
                              void* d_out, int out_size, void* d_ws, size_t ws_size,
                              hipStream_t stream) {
  const float* x  = (const float*)d_in[0];
  int*         posv = (int*)d_in[1];                 // mask -> compacted pos (in place)
  const float* Wq = (const float*)d_in[2]; const float* bq = (const float*)d_in[3];
  const float* Wk = (const float*)d_in[4]; const float* bk = (const float*)d_in[5];
  const float* Wv = (const float*)d_in[6]; const float* bv = (const float*)d_in[7];
  const float* Wo = (const float*)d_in[8]; const float* bo = (const float*)d_in[9];
  float* out = (float*)d_out;
  char* outc = (char*)d_out;
  char* xc   = (char*)d_in[0];
  const size_t half = (size_t)NBATCH * SEQ * DMODEL * 2;  // 16,777,216 B
  const size_t qtr  = half / 2;                            // 8,388,608 B

  // Regions (16.78 MB each): R0=d_out.lo R1=d_out.hi R2=x.lo R3=x.hi
  //   cvt_x:   x(R2∪R3) -> xbf(R1)               [x fp32 dead after this]
  //   prep:    Wq/Wk/Wv -> Wbf3(R3.hi); scan posv in place + inv (R3.hi tail)
  //            [after cvt_x: Wbf3 and inv overlap fp32 x — R8 lesson]
  //   mega:    qproj -> Qall(R0); kvproj0 -> KV(R2); Wo -> Wobf(d_in[2], dead
  //            fp32 Wq — only prep read it)
  //   attn_A:  Qall.lo,KV -> O.lo(R3.lo)
  //   kvproj1: xbf.hi gather(inv) -> KV(R2)
  //   attn_B:  Qall.hi,KV -> O.hi(R3.hi)         [overwrites dead Wbf3+inv]
  //   outproj: O(R3),Wobf(d_in[2]) -> out(R0∪R1)
  bf16* Qall = (bf16*)d_out;
  bf16* xbf  = (bf16*)(outc + half);
  bf16* KV   = (bf16*)xc;
  bf16* O    = (bf16*)(xc + half);
  bf16* Wbf3 = (bf16*)(xc + half + qtr);
  int*  inv  = (int*)(xc + half + qtr + (size_t)3 * DMODEL * DMODEL * 2);
  bf16* Wobf = (bf16*)d_in[2];

  cvt_kernel<<<dim3(2048), 256, 0, stream>>>(x, xbf);
  prep_kernel<<<dim3(772), 256, 0, stream>>>(Wq, Wk, Wv, Wbf3, posv, inv);
  mega_kernel<<<dim3(2304), 256, 0, stream>>>(xbf, Wbf3, bq, bk, bv, posv, inv,
                                              Qall, KV, Wo, Wobf);
  attn4_kernel<<<dim3(1024), 256, 0, stream>>>(Qall, KV, posv, O, 0);
  kvproj_kernel<<<dim3(32, 32), 256, 0, stream>>>(xbf + (size_t)2 * SEQ * DMODEL, Wbf3, bk, bv,
                                                  posv + 2 * SEQ, inv + 2 * SEQ, KV);
  attn4_kernel<<<dim3(1024), 256, 0, stream>>>(Qall, KV, posv, O, 1);
  outproj_kernel<<<dim3(64, 16), 256, 0, stream>>>(O, Wobf, bo, out);
}